// Round 8
// baseline (1279.632 us; speedup 1.0000x reference)
//
#include <hip/hip_runtime.h>
#include <math.h>

#define NB 16
#define TT 256
#define JJ 17
#define CC 512
#define HH 8
#define HD 64
#define MROWS (NB*TT*JJ)        // 69632
#define QTILE 16384             // elems per (b,h,j) tile (u32-packed planes)
#define NTILES (NB*HH*JJ)       // 2176
#define NQKV 35651584           // elements per plane (MROWS*512)

#define FP 68            // LDS pitch for 64-wide freq matrices
#define FHALF 4352       // 64*68
#define W0 0.0245436926061702596f   // 2*pi/256

typedef __attribute__((ext_vector_type(8))) short bf16x8;
typedef __attribute__((ext_vector_type(4))) float f32x4;

__device__ __forceinline__ unsigned short f2bf(float f) {
    unsigned int u = __float_as_uint(f);
    unsigned int r = u + 0x7FFFu + ((u >> 16) & 1u);
    return (unsigned short)(r >> 16);
}
__device__ __forceinline__ float bf2f(unsigned short s) {
    return __uint_as_float(((unsigned int)s) << 16);
}
// 8 packed u32 -> bf16x8 of the hi halves
__device__ __forceinline__ bf16x8 ld8hi(const unsigned int* p) {
    uint4 a = *(const uint4*)p;
    uint4 b = *(const uint4*)(p + 4);
    bf16x8 r;
    r[0] = (short)a.x; r[1] = (short)a.y; r[2] = (short)a.z; r[3] = (short)a.w;
    r[4] = (short)b.x; r[5] = (short)b.y; r[6] = (short)b.z; r[7] = (short)b.w;
    return r;
}

#define GLD16(gp, lp) __builtin_amdgcn_global_load_lds( \
    (__attribute__((address_space(1))) void*)(gp), \
    (__attribute__((address_space(3))) void*)(lp), 16, 0, 0)

// ---------------- f32 -> (hi, lo) bf16 split --------------------------------
__global__ __launch_bounds__(256) void split_k(
    const float* __restrict__ s, unsigned short* __restrict__ hi,
    unsigned short* __restrict__ lo, int n8)
{
    for (int i = blockIdx.x*256 + threadIdx.x; i < n8; i += gridDim.x*256) {
        float4 a = ((const float4*)s)[i*2];
        float4 b = ((const float4*)s)[i*2+1];
        float xx[8] = {a.x,a.y,a.z,a.w,b.x,b.y,b.z,b.w};
        bf16x8 h, l;
        #pragma unroll
        for (int e = 0; e < 8; ++e) {
            unsigned short hb = f2bf(xx[e]);
            h[e] = (short)hb;
            l[e] = (short)f2bf(xx[e] - bf2f(hb));
        }
        ((bf16x8*)hi)[i] = h;
        ((bf16x8*)lo)[i] = l;
    }
}

// ---------------- twiddle matrix W[128][256]: rows 0-63 cos, 64-127 -sin ----
__global__ __launch_bounds__(256) void winit_k(
    unsigned short* __restrict__ Whi, unsigned short* __restrict__ Wlo)
{
    const int r = blockIdx.x;
    const int t = threadIdx.x;
    int idx = ((r & 63) * t) & 255;
    float sv, cv;
    sincosf(W0 * (float)idx, &sv, &cv);
    float val = (r < 64) ? cv : -sv;
    unsigned short h = f2bf(val);
    Whi[r*256 + t] = h;
    Wlo[r*256 + t] = f2bf(val - bf2f(h));
}

// ---------------- GEMM 1 (split bf16 MFMA, BK=32): qkv = x @ w_qkv^T --------
// Output: packed u32 planes (hi | lo<<16). XCD-chunked 1D grid (6528 blocks).
// LDS both-sides swizzle: col ^= ((row>>1)&3)<<3 on source and frag read.
__global__ __launch_bounds__(256) void gemm_qkv_k(
    const unsigned short* __restrict__ Ahi, const unsigned short* __restrict__ Alo,
    const unsigned short* __restrict__ Bhi, const unsigned short* __restrict__ Blo,
    unsigned int* __restrict__ q32, unsigned int* __restrict__ k32,
    unsigned int* __restrict__ v32)
{
    __shared__ unsigned short Ah[128*32], Al[128*32];
    __shared__ unsigned short Bh[128*32], Bl[128*32];
    const int tid = threadIdx.x;
    const int lane = tid & 63, wv = tid >> 6;
    const int lo = lane & 15, hi = lane >> 4;
    const int wr = wv >> 1, wc = wv & 1;
    const int bid = blockIdx.x;
    const int wrk = (bid & 7) * 816 + (bid >> 3);   // 6528 = 8*816, bijective
    const int col0 = (wrk % 12) * 128;
    const int row0 = (wrk / 12) * 128;

    f32x4 acc[4][4];
    #pragma unroll
    for (int rb = 0; rb < 4; ++rb)
        #pragma unroll
        for (int cb = 0; cb < 4; ++cb) acc[rb][cb] = (f32x4){0.f,0.f,0.f,0.f};

    for (int k0 = 0; k0 < 512; k0 += 32) {
        #pragma unroll
        for (int c = 0; c < 2; ++c) {
            int e = c*2048 + tid*8;
            int r = e >> 5, cc = e & 31;
            int ccs = cc ^ (((r >> 1) & 3) << 3);
            size_t offA = (size_t)(row0 + r)*512 + k0 + ccs;
            size_t offB = (size_t)(col0 + r)*512 + k0 + ccs;
            int ldsb = c*4096 + wv*1024;
            GLD16(Ahi + offA, (char*)Ah + ldsb);
            GLD16(Alo + offA, (char*)Al + ldsb);
            GLD16(Bhi + offB, (char*)Bh + ldsb);
            GLD16(Blo + offB, (char*)Bl + ldsb);
        }
        __syncthreads();
        bf16x8 ah[4], al[4], bh[4], bl[4];
        #pragma unroll
        for (int rb = 0; rb < 4; ++rb) {
            int row = wr*64 + rb*16 + lo;
            int colS = (hi*8) ^ (((row >> 1) & 3) << 3);
            ah[rb] = *(const bf16x8*)&Ah[row*32 + colS];
            al[rb] = *(const bf16x8*)&Al[row*32 + colS];
        }
        #pragma unroll
        for (int cb = 0; cb < 4; ++cb) {
            int row = wc*64 + cb*16 + lo;
            int colS = (hi*8) ^ (((row >> 1) & 3) << 3);
            bh[cb] = *(const bf16x8*)&Bh[row*32 + colS];
            bl[cb] = *(const bf16x8*)&Bl[row*32 + colS];
        }
        #pragma unroll
        for (int rb = 0; rb < 4; ++rb)
            #pragma unroll
            for (int cb = 0; cb < 4; ++cb) {
                acc[rb][cb] = __builtin_amdgcn_mfma_f32_16x16x32_bf16(
                    ah[rb], bh[cb], acc[rb][cb], 0, 0, 0);
                acc[rb][cb] = __builtin_amdgcn_mfma_f32_16x16x32_bf16(
                    ah[rb], bl[cb], acc[rb][cb], 0, 0, 0);
                acc[rb][cb] = __builtin_amdgcn_mfma_f32_16x16x32_bf16(
                    al[rb], bh[cb], acc[rb][cb], 0, 0, 0);
            }
        __syncthreads();
    }

    // scatter packed u32: n = g*512 + h*64 + d -> plane[(bb*8+h)*17+j][t][d]
    #pragma unroll
    for (int cb = 0; cb < 4; ++cb) {
        int n0 = col0 + wc*64 + cb*16;
        int g = n0 >> 9;
        unsigned int* dst0 = (g == 0) ? q32 : (g == 1) ? k32 : v32;
        int h = (n0 >> 6) & 7;
        int d = (n0 & 63) + lo;
        #pragma unroll
        for (int rb = 0; rb < 4; ++rb) {
            #pragma unroll
            for (int r = 0; r < 4; ++r) {
                int m = row0 + wr*64 + rb*16 + hi*4 + r;
                int bb = m / (TT*JJ);
                int rem = m - bb*(TT*JJ);
                int t = rem / JJ;
                int j = rem - t*JJ;
                size_t off = ((((size_t)bb*HH + h)*JJ + j)*TT + t)*HD + d;
                float val = acc[rb][cb][r];
                unsigned short hb = f2bf(val);
                unsigned short lb = f2bf(val - bf2f(hb));
                dst0[off] = (unsigned int)hb | ((unsigned int)lb << 16);
            }
        }
    }
}

// ---------------- GEMM 2 (split bf16 MFMA, BK=32): out = y @ w_proj^T + b ---
__global__ __launch_bounds__(256) void gemm_proj_k(
    const unsigned short* __restrict__ Ahi, const unsigned short* __restrict__ Alo,
    const unsigned short* __restrict__ Bhi, const unsigned short* __restrict__ Blo,
    const float* __restrict__ bias, float* __restrict__ out)
{
    __shared__ unsigned short Ah[128*32], Al[128*32];
    __shared__ unsigned short Bh[128*32], Bl[128*32];
    const int tid = threadIdx.x;
    const int lane = tid & 63, wv = tid >> 6;
    const int lo = lane & 15, hi = lane >> 4;
    const int wr = wv >> 1, wc = wv & 1;
    const int bid = blockIdx.x;
    const int wrk = (bid & 7) * 272 + (bid >> 3);   // 2176 = 8*272, bijective
    const int col0 = (wrk % 4) * 128;
    const int row0 = (wrk / 4) * 128;

    f32x4 acc[4][4];
    #pragma unroll
    for (int rb = 0; rb < 4; ++rb)
        #pragma unroll
        for (int cb = 0; cb < 4; ++cb) acc[rb][cb] = (f32x4){0.f,0.f,0.f,0.f};

    for (int k0 = 0; k0 < 512; k0 += 32) {
        #pragma unroll
        for (int c = 0; c < 2; ++c) {
            int e = c*2048 + tid*8;
            int r = e >> 5, cc = e & 31;
            int ccs = cc ^ (((r >> 1) & 3) << 3);
            size_t offA = (size_t)(row0 + r)*512 + k0 + ccs;
            size_t offB = (size_t)(col0 + r)*512 + k0 + ccs;
            int ldsb = c*4096 + wv*1024;
            GLD16(Ahi + offA, (char*)Ah + ldsb);
            GLD16(Alo + offA, (char*)Al + ldsb);
            GLD16(Bhi + offB, (char*)Bh + ldsb);
            GLD16(Blo + offB, (char*)Bl + ldsb);
        }
        __syncthreads();
        bf16x8 ah[4], al[4], bh[4], bl[4];
        #pragma unroll
        for (int rb = 0; rb < 4; ++rb) {
            int row = wr*64 + rb*16 + lo;
            int colS = (hi*8) ^ (((row >> 1) & 3) << 3);
            ah[rb] = *(const bf16x8*)&Ah[row*32 + colS];
            al[rb] = *(const bf16x8*)&Al[row*32 + colS];
        }
        #pragma unroll
        for (int cb = 0; cb < 4; ++cb) {
            int row = wc*64 + cb*16 + lo;
            int colS = (hi*8) ^ (((row >> 1) & 3) << 3);
            bh[cb] = *(const bf16x8*)&Bh[row*32 + colS];
            bl[cb] = *(const bf16x8*)&Bl[row*32 + colS];
        }
        #pragma unroll
        for (int rb = 0; rb < 4; ++rb)
            #pragma unroll
            for (int cb = 0; cb < 4; ++cb) {
                acc[rb][cb] = __builtin_amdgcn_mfma_f32_16x16x32_bf16(
                    ah[rb], bh[cb], acc[rb][cb], 0, 0, 0);
                acc[rb][cb] = __builtin_amdgcn_mfma_f32_16x16x32_bf16(
                    ah[rb], bl[cb], acc[rb][cb], 0, 0, 0);
                acc[rb][cb] = __builtin_amdgcn_mfma_f32_16x16x32_bf16(
                    al[rb], bh[cb], acc[rb][cb], 0, 0, 0);
            }
        __syncthreads();
    }

    #pragma unroll
    for (int cb = 0; cb < 4; ++cb) {
        int n = col0 + wc*64 + cb*16 + lo;
        float bv = bias[n];
        #pragma unroll
        for (int rb = 0; rb < 4; ++rb) {
            #pragma unroll
            for (int r = 0; r < 4; ++r) {
                int m = row0 + wr*64 + rb*16 + hi*4 + r;
                out[(size_t)m*512 + n] = acc[rb][cb][r] + bv;
            }
        }
    }
}

// ---------------- time attention via bf16 MFMA (packed u32 plane inputs) ----
#define VTP 264
#define PPW 40

__global__ __launch_bounds__(256, 2) void attn_time_k(
    const unsigned int* __restrict__ q, const unsigned int* __restrict__ k,
    const unsigned int* __restrict__ v, const float* __restrict__ fg,
    float* __restrict__ y)
{
    __shared__ unsigned short VT[64 * VTP];
    __shared__ unsigned short PL[4 * 64 * PPW];

    const int bid = blockIdx.x;
    const int b = bid / (HH*JJ);
    const int h = (bid / JJ) % HH;
    const int j = bid % JJ;
    const size_t base = (size_t)bid * QTILE;

    const int tid = threadIdx.x;
    const int w = tid >> 6;
    const int lane = tid & 63;
    const int lo = lane & 15;
    const int hi = lane >> 4;

    {
        const unsigned int* vp = v + base + (size_t)tid * HD;
        #pragma unroll
        for (int d0 = 0; d0 < 64; d0 += 4) {
            uint4 vv = *(const uint4*)(vp + d0);
            VT[(d0+0)*VTP + tid] = (unsigned short)vv.x;
            VT[(d0+1)*VTP + tid] = (unsigned short)vv.y;
            VT[(d0+2)*VTP + tid] = (unsigned short)vv.z;
            VT[(d0+3)*VTP + tid] = (unsigned short)vv.w;
        }
    }
    __syncthreads();

    bf16x8 qf[4][2];
    #pragma unroll
    for (int rb = 0; rb < 4; ++rb)
        #pragma unroll
        for (int dc = 0; dc < 2; ++dc)
            qf[rb][dc] = ld8hi(q + base + (size_t)(w*64 + rb*16 + lo)*HD + dc*32 + hi*8);

    f32x4 o[4][4];
    #pragma unroll
    for (int rb = 0; rb < 4; ++rb)
        #pragma unroll
        for (int cd = 0; cd < 4; ++cd) o[rb][cd] = (f32x4){0.f,0.f,0.f,0.f};
    float rs[4][4];
    #pragma unroll
    for (int rb = 0; rb < 4; ++rb)
        #pragma unroll
        for (int r = 0; r < 4; ++r) rs[rb][r] = 0.f;

    unsigned short* Pw = PL + w * 64 * PPW;

    for (int st = 0; st < 8; ++st) {
        const int s0 = st * 32;
        bf16x8 kf[2][2];
        #pragma unroll
        for (int cb = 0; cb < 2; ++cb)
            #pragma unroll
            for (int dc = 0; dc < 2; ++dc)
                kf[cb][dc] = ld8hi(k + base + (size_t)(s0 + cb*16 + lo)*HD + dc*32 + hi*8);

        #pragma unroll
        for (int rb = 0; rb < 4; ++rb) {
            #pragma unroll
            for (int cb = 0; cb < 2; ++cb) {
                f32x4 acc = (f32x4){0.f,0.f,0.f,0.f};
                acc = __builtin_amdgcn_mfma_f32_16x16x32_bf16(qf[rb][0], kf[cb][0], acc, 0, 0, 0);
                acc = __builtin_amdgcn_mfma_f32_16x16x32_bf16(qf[rb][1], kf[cb][1], acc, 0, 0, 0);
                #pragma unroll
                for (int r = 0; r < 4; ++r) {
                    float p = __expf(acc[r] * 0.125f);
                    rs[rb][r] += p;
                    Pw[(rb*16 + hi*4 + r)*PPW + cb*16 + lo] = f2bf(p);
                }
            }
        }

        bf16x8 pa[4];
        #pragma unroll
        for (int rb = 0; rb < 4; ++rb)
            pa[rb] = *(const bf16x8*)&Pw[(rb*16 + lo)*PPW + hi*8];
        bf16x8 bv[4];
        #pragma unroll
        for (int cd = 0; cd < 4; ++cd)
            bv[cd] = *(const bf16x8*)&VT[(cd*16 + lo)*VTP + s0 + hi*8];
        #pragma unroll
        for (int rb = 0; rb < 4; ++rb)
            #pragma unroll
            for (int cd = 0; cd < 4; ++cd)
                o[rb][cd] = __builtin_amdgcn_mfma_f32_16x16x32_bf16(pa[rb], bv[cd], o[rb][cd], 0, 0, 0);
    }

    #pragma unroll
    for (int off = 1; off < 16; off <<= 1)
        #pragma unroll
        for (int rb = 0; rb < 4; ++rb)
            #pragma unroll
            for (int r = 0; r < 4; ++r)
                rs[rb][r] += __shfl_xor(rs[rb][r], off, 64);

    const float gate = 1.f / (1.f + __expf(-fg[0]));
    const float wt = 1.f - gate;
    #pragma unroll
    for (int rb = 0; rb < 4; ++rb) {
        #pragma unroll
        for (int r = 0; r < 4; ++r) {
            const int t = w*64 + rb*16 + hi*4 + r;
            const float sc = wt / rs[rb][r];
            float* yp = y + (((size_t)b*TT + t)*JJ + j)*CC + h*HD;
            #pragma unroll
            for (int cd = 0; cd < 4; ++cd)
                yp[cd*16 + lo] = o[rb][cd][r] * sc;
        }
    }
}

// ---------------- F1: DFT as split-bf16 MFMA GEMM (packed u32 input) --------
// C[128][64] = W[128][256] @ X[256][64]; rows 0-63 re, 64-127 im.
// Writes f32 re/im in place over the first half of the tile slot.
#define XP 280   // u16 pitch

__global__ __launch_bounds__(256) void dft_k(
    unsigned int* __restrict__ planes, const unsigned short* __restrict__ Whi,
    const unsigned short* __restrict__ Wlo)
{
    __shared__ unsigned short Xh[64*XP];
    __shared__ unsigned short Xl[64*XP];
    unsigned int* src = planes + (size_t)blockIdx.y*NQKV + (size_t)blockIdx.x*QTILE;
    float* obuf = (float*)src;
    const int tid = threadIdx.x;
    const int w = tid >> 6;
    const int lane = tid & 63;
    const int qd = (tid >> 4) & 3;
    const int rr = tid & 15;
    const int lo = lane & 15, hi = lane >> 4;

    // stage: uint4 loads (packed hi|lo), 4x4 shfl transpose, unpack to planes
    #pragma unroll
    for (int p = 0; p < 16; ++p) {
        const int t = p*16 + 4*w + qd;
        uint4 x4 = *(const uint4*)&src[t*64 + 4*rr];
        unsigned int a0 = x4.x, a1 = x4.y, a2 = x4.z, a3 = x4.w;
        unsigned int t01 = (unsigned)__shfl_xor((int)((qd&1) ? a0 : a1), 16, 64);
        unsigned int t23 = (unsigned)__shfl_xor((int)((qd&1) ? a2 : a3), 16, 64);
        if (qd&1) { a0 = t01; a2 = t23; } else { a1 = t01; a3 = t23; }
        unsigned int u01 = (unsigned)__shfl_xor((int)((qd&2) ? a0 : a2), 32, 64);
        unsigned int u23 = (unsigned)__shfl_xor((int)((qd&2) ? a1 : a3), 32, 64);
        if (qd&2) { a0 = u01; a1 = u23; } else { a2 = u01; a3 = u23; }
        const int dd = 4*rr + qd;
        const int tb = p*16 + 4*w;
        ushort4 hv, lv;
        hv.x = (unsigned short)a0; lv.x = (unsigned short)(a0 >> 16);
        hv.y = (unsigned short)a1; lv.y = (unsigned short)(a1 >> 16);
        hv.z = (unsigned short)a2; lv.z = (unsigned short)(a2 >> 16);
        hv.w = (unsigned short)a3; lv.w = (unsigned short)(a3 >> 16);
        *(ushort4*)&Xh[dd*XP + tb] = hv;
        *(ushort4*)&Xl[dd*XP + tb] = lv;
    }
    __syncthreads();

    f32x4 acc[2][4];
    #pragma unroll
    for (int rb = 0; rb < 2; ++rb)
        #pragma unroll
        for (int cd = 0; cd < 4; ++cd) acc[rb][cd] = (f32x4){0.f,0.f,0.f,0.f};

    for (int ks = 0; ks < 8; ++ks) {
        const int k0 = ks*32;
        bf16x8 ah[2], al[2];
        #pragma unroll
        for (int rb = 0; rb < 2; ++rb) {
            int r = w*32 + rb*16 + lo;
            ah[rb] = *(const bf16x8*)&Whi[r*256 + k0 + hi*8];
            al[rb] = *(const bf16x8*)&Wlo[r*256 + k0 + hi*8];
        }
        bf16x8 bh[4], bl[4];
        #pragma unroll
        for (int cd = 0; cd < 4; ++cd) {
            int d = cd*16 + lo;
            bh[cd] = *(const bf16x8*)&Xh[d*XP + k0 + hi*8];
            bl[cd] = *(const bf16x8*)&Xl[d*XP + k0 + hi*8];
        }
        #pragma unroll
        for (int rb = 0; rb < 2; ++rb)
            #pragma unroll
            for (int cd = 0; cd < 4; ++cd) {
                acc[rb][cd] = __builtin_amdgcn_mfma_f32_16x16x32_bf16(
                    ah[rb], bh[cd], acc[rb][cd], 0, 0, 0);
                acc[rb][cd] = __builtin_amdgcn_mfma_f32_16x16x32_bf16(
                    ah[rb], bl[cd], acc[rb][cd], 0, 0, 0);
                acc[rb][cd] = __builtin_amdgcn_mfma_f32_16x16x32_bf16(
                    al[rb], bh[cd], acc[rb][cd], 0, 0, 0);
            }
    }

    #pragma unroll
    for (int rb = 0; rb < 2; ++rb) {
        #pragma unroll
        for (int r = 0; r < 4; ++r) {
            int row = w*32 + rb*16 + hi*4 + r;
            float* dst = (row < 64) ? (obuf + row*64) : (obuf + 4096 + (row-64)*64);
            #pragma unroll
            for (int cd = 0; cd < 4; ++cd)
                dst[cd*16 + lo] = acc[rb][cd][r];
        }
    }
}

// ---------------- F2: af = scale*qf kf^H, dual softmax, xf = af vf ----------
// Freq tiles live at stride QTILE f32 within each plane slot.
__global__ __launch_bounds__(256) void afxf_k(
    float* __restrict__ qfv, const float* __restrict__ kfv,
    const float* __restrict__ vfv)
{
    extern __shared__ float lds[];
    float* A = lds;
    float* B = lds + 2*FHALF;

    const int tid = threadIdx.x;
    float* qf = qfv + (size_t)blockIdx.x * QTILE;
    const float* kf = kfv + (size_t)blockIdx.x * QTILE;
    const float* vf = vfv + (size_t)blockIdx.x * QTILE;

    #pragma unroll
    for (int p = 0; p < 8; ++p) {
        int idx = p*256 + tid;
        int part = idx >> 10;
        int rem = idx & 1023;
        int row = rem >> 4;
        int col = (rem & 15) * 4;
        *(float4*)(A + part*FHALF + row*FP + col) = *(const float4*)(qf + (size_t)idx*4);
        *(float4*)(B + part*FHALF + row*FP + col) = *(const float4*)(kf + (size_t)idx*4);
    }
    __syncthreads();

    const int fy = tid >> 4;
    const int gl = tid & 15;

    float cR[4][4], cI[4][4];
    #pragma unroll
    for (int i = 0; i < 4; ++i)
        #pragma unroll
        for (int gi = 0; gi < 4; ++gi) { cR[i][gi] = 0.f; cI[i][gi] = 0.f; }

    for (int d4 = 0; d4 < 16; ++d4) {
        float4 qr[4], qi[4], kr[4], ki[4];
        #pragma unroll
        for (int i = 0; i < 4; ++i) {
            int f = fy + 16*i;
            qr[i] = *(const float4*)(A + f*FP + d4*4);
            qi[i] = *(const float4*)(A + FHALF + f*FP + d4*4);
            int g = gl + 16*i;
            kr[i] = *(const float4*)(B + g*FP + d4*4);
            ki[i] = *(const float4*)(B + FHALF + g*FP + d4*4);
        }
        #pragma unroll
        for (int i = 0; i < 4; ++i)
            #pragma unroll
            for (int gi = 0; gi < 4; ++gi) {
                float r = cR[i][gi], m = cI[i][gi];
                r = fmaf(qr[i].x, kr[gi].x, r); r = fmaf(qi[i].x, ki[gi].x, r);
                r = fmaf(qr[i].y, kr[gi].y, r); r = fmaf(qi[i].y, ki[gi].y, r);
                r = fmaf(qr[i].z, kr[gi].z, r); r = fmaf(qi[i].z, ki[gi].z, r);
                r = fmaf(qr[i].w, kr[gi].w, r); r = fmaf(qi[i].w, ki[gi].w, r);
                m = fmaf(qi[i].x, kr[gi].x, m); m = fmaf(-qr[i].x, ki[gi].x, m);
                m = fmaf(qi[i].y, kr[gi].y, m); m = fmaf(-qr[i].y, ki[gi].y, m);
                m = fmaf(qi[i].z, kr[gi].z, m); m = fmaf(-qr[i].z, ki[gi].z, m);
                m = fmaf(qi[i].w, kr[gi].w, m); m = fmaf(-qr[i].w, ki[gi].w, m);
                cR[i][gi] = r; cI[i][gi] = m;
            }
    }
    __syncthreads();

    #pragma unroll
    for (int i = 0; i < 4; ++i)
        #pragma unroll
        for (int gi = 0; gi < 4; ++gi) {
            A[(fy + 16*i)*FP + gl + 16*gi]         = 0.125f * cR[i][gi];
            A[FHALF + (fy + 16*i)*FP + gl + 16*gi] = 0.125f * cI[i][gi];
        }
    #pragma unroll
    for (int p = 0; p < 8; ++p) {
        int idx = p*256 + tid;
        int part = idx >> 10;
        int rem = idx & 1023;
        int row = rem >> 4;
        int col = (rem & 15) * 4;
        *(float4*)(B + part*FHALF + row*FP + col) = *(const float4*)(vf + (size_t)idx*4);
    }
    __syncthreads();

    if (tid < 128) {
        float* row = A + (tid >> 6)*FHALF + (tid & 63)*FP;
        float mx = row[0];
        for (int g2 = 1; g2 < 64; ++g2) mx = fmaxf(mx, row[g2]);
        float sum = 0.f;
        for (int g2 = 0; g2 < 64; ++g2) { float e = __expf(row[g2]-mx); row[g2] = e; sum += e; }
        float inv = 1.f / sum;
        for (int g2 = 0; g2 < 64; ++g2) row[g2] *= inv;
    }
    __syncthreads();

    float xR[4][4], xI[4][4];
    #pragma unroll
    for (int i = 0; i < 4; ++i)
        #pragma unroll
        for (int cmp = 0; cmp < 4; ++cmp) { xR[i][cmp] = 0.f; xI[i][cmp] = 0.f; }

    for (int g2 = 0; g2 < 64; ++g2) {
        float4 vr = *(const float4*)(B + g2*FP + gl*4);
        float4 vi = *(const float4*)(B + FHALF + g2*FP + gl*4);
        #pragma unroll
        for (int i = 0; i < 4; ++i) {
            float sr = A[(fy + 16*i)*FP + g2];
            float si = A[FHALF + (fy + 16*i)*FP + g2];
            xR[i][0] = fmaf(sr, vr.x, fmaf(-si, vi.x, xR[i][0]));
            xI[i][0] = fmaf(sr, vi.x, fmaf( si, vr.x, xI[i][0]));
            xR[i][1] = fmaf(sr, vr.y, fmaf(-si, vi.y, xR[i][1]));
            xI[i][1] = fmaf(sr, vi.y, fmaf( si, vr.y, xI[i][1]));
            xR[i][2] = fmaf(sr, vr.z, fmaf(-si, vi.z, xR[i][2]));
            xI[i][2] = fmaf(sr, vi.z, fmaf( si, vr.z, xI[i][2]));
            xR[i][3] = fmaf(sr, vr.w, fmaf(-si, vi.w, xR[i][3]));
            xI[i][3] = fmaf(sr, vi.w, fmaf( si, vr.w, xI[i][3]));
        }
    }
    #pragma unroll
    for (int i = 0; i < 4; ++i) {
        int f = fy + 16*i;
        *(float4*)(qf + f*64 + gl*4)        = make_float4(xR[i][0],xR[i][1],xR[i][2],xR[i][3]);
        *(float4*)(qf + 4096 + f*64 + gl*4) = make_float4(xI[i][0],xI[i][1],xI[i][2],xI[i][3]);
    }
}

// ---------------- F3: zero-padded irfft (n=256) + gated accumulate into y ---
__global__ __launch_bounds__(256) void irfft_k(
    const float* __restrict__ qfv, const float* __restrict__ fg,
    float* __restrict__ y)
{
    __shared__ float xs[2*FHALF];
    const int tid = threadIdx.x;
    const int tile = blockIdx.x;
    const int b = tile / (HH*JJ);
    const int h = (tile / JJ) % HH;
    const int j = tile % JJ;
    const float* xf = qfv + (size_t)tile * QTILE;

    #pragma unroll
    for (int p = 0; p < 8; ++p) {
        int idx = p*256 + tid;
        int part = idx >> 10;
        int rem = idx & 1023;
        int row = rem >> 4;
        int col = (rem & 15) * 4;
        *(float4*)(xs + part*FHALF + row*FP + col) = *(const float4*)(xf + (size_t)idx*4);
    }
    __syncthreads();
    if (tid < 16) {
        float4* p = ((float4*)xs) + tid;
        float4 vv = *p;
        vv.x *= 0.5f; vv.y *= 0.5f; vv.z *= 0.5f; vv.w *= 0.5f;
        *p = vv;
    }
    __syncthreads();

    const int d0 = (tid & 7) * 8;
    const int ty = tid >> 3;

    float acc[8][8];
    #pragma unroll
    for (int ti = 0; ti < 8; ++ti)
        #pragma unroll
        for (int i = 0; i < 8; ++i) acc[ti][i] = 0.f;

    float cst[8], sst[8], c[8], s[8];
    #pragma unroll
    for (int ti = 0; ti < 8; ++ti) {
        sincosf(W0 * (float)(ty + 32*ti), &sst[ti], &cst[ti]);
        c[ti] = 1.f; s[ti] = 0.f;
    }

    for (int f = 0; f < 64; ++f) {
        float4 r0 = *(const float4*)(xs + f*FP + d0);
        float4 r1 = *(const float4*)(xs + f*FP + d0 + 4);
        float4 i0 = *(const float4*)(xs + FHALF + f*FP + d0);
        float4 i1 = *(const float4*)(xs + FHALF + f*FP + d0 + 4);
        #pragma unroll
        for (int ti = 0; ti < 8; ++ti) {
            float cc = c[ti], ss = s[ti];
            acc[ti][0] = fmaf(r0.x, cc, fmaf(-i0.x, ss, acc[ti][0]));
            acc[ti][1] = fmaf(r0.y, cc, fmaf(-i0.y, ss, acc[ti][1]));
            acc[ti][2] = fmaf(r0.z, cc, fmaf(-i0.z, ss, acc[ti][2]));
            acc[ti][3] = fmaf(r0.w, cc, fmaf(-i0.w, ss, acc[ti][3]));
            acc[ti][4] = fmaf(r1.x, cc, fmaf(-i1.x, ss, acc[ti][4]));
            acc[ti][5] = fmaf(r1.y, cc, fmaf(-i1.y, ss, acc[ti][5]));
            acc[ti][6] = fmaf(r1.z, cc, fmaf(-i1.z, ss, acc[ti][6]));
            acc[ti][7] = fmaf(r1.w, cc, fmaf(-i1.w, ss, acc[ti][7]));
            float nc = fmaf(cc, cst[ti], -(ss * sst[ti]));
            float ns = fmaf(cc, sst[ti],   ss * cst[ti]);
            c[ti] = nc; s[ti] = ns;
        }
    }

    const float gate = 1.f / (1.f + __expf(-fg[0]));
    const float sc = gate * (2.f / 256.f);
    #pragma unroll
    for (int ti = 0; ti < 8; ++ti) {
        int t = ty + 32*ti;
        float* yp = y + (((size_t)b*TT + t)*JJ + j)*CC + h*HD + d0;
        float4 c0 = *(float4*)yp;
        float4 c1 = *(float4*)(yp + 4);
        c0.x = fmaf(sc, acc[ti][0], c0.x); c0.y = fmaf(sc, acc[ti][1], c0.y);
        c0.z = fmaf(sc, acc[ti][2], c0.z); c0.w = fmaf(sc, acc[ti][3], c0.w);
        c1.x = fmaf(sc, acc[ti][4], c1.x); c1.y = fmaf(sc, acc[ti][5], c1.y);
        c1.z = fmaf(sc, acc[ti][6], c1.z); c1.w = fmaf(sc, acc[ti][7], c1.w);
        *(float4*)yp = c0;
        *(float4*)(yp + 4) = c1;
    }
}

// ---------------------------------------------------------------------------
// Workspace (4 x 142.6MB slots, time-multiplexed):
//  [0]: q32 packed -> qf(f32, stride QTILE) -> y_hi/y_lo (split->proj)
//  [1]: k32 packed -> kf(f32)              -> wp_hi/wp_lo
//  [2]: v32 packed -> vf(f32)
//  [3]: x_hi/x_lo (split->gemm)            -> y f32 (attn->split)
//  d_out: wq_hi/wq_lo + W_hi/W_lo staging (dead before proj writes)
extern "C" void kernel_launch(void* const* d_in, const int* in_sizes, int n_in,
                              void* d_out, int out_size, void* d_ws, size_t ws_size,
                              hipStream_t stream) {
    const float* x      = (const float*)d_in[0];
    const float* w_qkv  = (const float*)d_in[1];
    const float* w_proj = (const float*)d_in[2];
    const float* b_proj = (const float*)d_in[3];
    const float* fg     = (const float*)d_in[4];
    float* out = (float*)d_out;

    char* wsb = (char*)d_ws;
    const size_t SLOT = (size_t)NQKV * 4;  // 142,606,336 B
    unsigned int* q32 = (unsigned int*)(wsb + 0*SLOT);
    unsigned int* k32 = (unsigned int*)(wsb + 1*SLOT);
    unsigned int* v32 = (unsigned int*)(wsb + 2*SLOT);
    unsigned short* xhi = (unsigned short*)(wsb + 3*SLOT);
    unsigned short* xlo = xhi + NQKV;
    float* y = (float*)(wsb + 3*SLOT);     // x planes dead after gemm_qkv

    unsigned short* yhi = (unsigned short*)q32;   // q slot dead after irfft
    unsigned short* ylo = yhi + NQKV;
    unsigned short* wphi = (unsigned short*)k32;  // k slot dead after afxf
    unsigned short* wplo = wphi + 512*512;
    unsigned short* wqhi = (unsigned short*)d_out;
    unsigned short* wqlo = wqhi + 1536*512;
    unsigned short* Whi  = wqlo + 1536*512;
    unsigned short* Wlo  = Whi + 128*256;

    (void)hipFuncSetAttribute((const void*)afxf_k,
                              hipFuncAttributeMaxDynamicSharedMemorySize, 4*FHALF*4);

    split_k<<<2048, 256, 0, stream>>>(x, xhi, xlo, NQKV/8);
    split_k<<<384, 256, 0, stream>>>(w_qkv, wqhi, wqlo, 1536*512/8);
    winit_k<<<128, 256, 0, stream>>>(Whi, Wlo);

    gemm_qkv_k<<<6528, 256, 0, stream>>>(xhi, xlo, wqhi, wqlo, q32, k32, v32);
    attn_time_k<<<NTILES, 256, 0, stream>>>(q32, k32, v32, fg, y);
    dft_k<<<dim3(NTILES, 3), 256, 0, stream>>>(q32, Whi, Wlo);
    afxf_k<<<NTILES, 256, 4*FHALF*4, stream>>>(
        (float*)q32, (const float*)k32, (const float*)v32);
    irfft_k<<<NTILES, 256, 0, stream>>>((const float*)q32, fg, y);

    split_k<<<2048, 256, 0, stream>>>(y, yhi, ylo, NQKV/8);
    split_k<<<128, 256, 0, stream>>>(w_proj, wphi, wplo, 512*512/8);
    gemm_proj_k<<<2176, 256, 0, stream>>>(yhi, ylo, wphi, wplo, b_proj, out);
}

// Round 9
// 1001.590 us; speedup vs baseline: 1.2776x; 1.2776x over previous
//
#include <hip/hip_runtime.h>
#include <hip/hip_fp16.h>
#include <math.h>

#define NB 16
#define TT 256
#define JJ 17
#define CC 512
#define HH 8
#define HD 64
#define MROWS (NB*TT*JJ)        // 69632
#define QTILE 16384             // elems per (b,h,j) tile (u32-packed planes)
#define NTILES (NB*HH*JJ)       // 2176
#define NQKV 35651584           // elements per plane (MROWS*512)

#define FP 68            // LDS pitch for 64-wide freq matrices
#define FHALF 4352       // 64*68
#define W0 0.0245436926061702596f   // 2*pi/256

typedef __attribute__((ext_vector_type(8))) short i16x8;
typedef __attribute__((ext_vector_type(8))) _Float16 f16x8;
typedef __attribute__((ext_vector_type(4))) float f32x4;

__device__ __forceinline__ unsigned short f2h(float f) {
    return (unsigned short)__half_as_ushort(__float2half(f));
}
__device__ __forceinline__ float h2f(unsigned short u) {
    return __half2float(__ushort_as_half(u));
}
// 8 packed u32 -> f16x8 of the low halves (f16 hi part)
__device__ __forceinline__ f16x8 ld8hi(const unsigned int* p) {
    uint4 a = *(const uint4*)p;
    uint4 b = *(const uint4*)(p + 4);
    i16x8 r;
    r[0] = (short)a.x; r[1] = (short)a.y; r[2] = (short)a.z; r[3] = (short)a.w;
    r[4] = (short)b.x; r[5] = (short)b.y; r[6] = (short)b.z; r[7] = (short)b.w;
    f16x8 h;
    __builtin_memcpy(&h, &r, 16);
    return h;
}

#define GLD16(gp, lp) __builtin_amdgcn_global_load_lds( \
    (__attribute__((address_space(1))) void*)(gp), \
    (__attribute__((address_space(3))) void*)(lp), 16, 0, 0)

// ---------------- f32 -> f16 conversion (8-wide) ----------------------------
__global__ __launch_bounds__(256) void conv16_k(
    const float* __restrict__ s, unsigned short* __restrict__ d, int n8)
{
    for (int i = blockIdx.x*256 + threadIdx.x; i < n8; i += gridDim.x*256) {
        float4 a = ((const float4*)s)[i*2];
        float4 b = ((const float4*)s)[i*2+1];
        i16x8 h;
        h[0] = (short)f2h(a.x); h[1] = (short)f2h(a.y);
        h[2] = (short)f2h(a.z); h[3] = (short)f2h(a.w);
        h[4] = (short)f2h(b.x); h[5] = (short)f2h(b.y);
        h[6] = (short)f2h(b.z); h[7] = (short)f2h(b.w);
        ((i16x8*)d)[i] = h;
    }
}

// ---------------- twiddle matrix W[128][256] (split f16): cos / -sin --------
__global__ __launch_bounds__(256) void winit_k(
    unsigned short* __restrict__ Whi, unsigned short* __restrict__ Wlo)
{
    const int r = blockIdx.x;
    const int t = threadIdx.x;
    int idx = ((r & 63) * t) & 255;
    float sv, cv;
    sincosf(W0 * (float)idx, &sv, &cv);
    float val = (r < 64) ? cv : -sv;
    unsigned short h = f2h(val);
    Whi[r*256 + t] = h;
    Wlo[r*256 + t] = f2h(val - h2f(h));
}

// ---------------- GEMM 1 (f16 MFMA, BK=64): qkv = x @ w_qkv^T ---------------
// Output: packed u32 planes (f16hi | f16lo<<16). XCD-chunked 1D grid.
// LDS both-sides swizzle: col ^= ((row&7)<<3) on source and frag read.
__global__ __launch_bounds__(256) void gemm_qkv_k(
    const unsigned short* __restrict__ A, const unsigned short* __restrict__ B,
    unsigned int* __restrict__ q32, unsigned int* __restrict__ k32,
    unsigned int* __restrict__ v32)
{
    __shared__ unsigned short Ah[128*64];
    __shared__ unsigned short Bh[128*64];
    const int tid = threadIdx.x;
    const int lane = tid & 63, wv = tid >> 6;
    const int lo = lane & 15, hi = lane >> 4;
    const int wr = wv >> 1, wc = wv & 1;
    const int bid = blockIdx.x;
    const int wrk = (bid & 7) * 816 + (bid >> 3);   // 6528 = 8*816, bijective
    const int col0 = (wrk % 12) * 128;
    const int row0 = (wrk / 12) * 128;

    f32x4 acc[4][4];
    #pragma unroll
    for (int rb = 0; rb < 4; ++rb)
        #pragma unroll
        for (int cb = 0; cb < 4; ++cb) acc[rb][cb] = (f32x4){0.f,0.f,0.f,0.f};

    for (int k0 = 0; k0 < 512; k0 += 64) {
        #pragma unroll
        for (int c = 0; c < 4; ++c) {
            int e = c*2048 + tid*8;
            int r = e >> 6, cc = e & 63;
            int ccs = cc ^ ((r & 7) << 3);
            size_t offA = (size_t)(row0 + r)*512 + k0 + ccs;
            size_t offB = (size_t)(col0 + r)*512 + k0 + ccs;
            int ldsb = c*4096 + tid*16 - tid*16 + c*0;   // linear: addr = e*2
            GLD16(A + offA, (char*)Ah + c*4096 + (tid & 255)*16);
            GLD16(B + offB, (char*)Bh + c*4096 + (tid & 255)*16);
            (void)ldsb;
        }
        __syncthreads();
        #pragma unroll
        for (int ks = 0; ks < 2; ++ks) {
            f16x8 af[4], bf[4];
            #pragma unroll
            for (int rb = 0; rb < 4; ++rb) {
                int row = wr*64 + rb*16 + lo;
                int col = (ks*32 + hi*8) ^ ((row & 7) << 3);
                af[rb] = *(const f16x8*)&Ah[row*64 + col];
            }
            #pragma unroll
            for (int cb = 0; cb < 4; ++cb) {
                int row = wc*64 + cb*16 + lo;
                int col = (ks*32 + hi*8) ^ ((row & 7) << 3);
                bf[cb] = *(const f16x8*)&Bh[row*64 + col];
            }
            #pragma unroll
            for (int rb = 0; rb < 4; ++rb)
                #pragma unroll
                for (int cb = 0; cb < 4; ++cb)
                    acc[rb][cb] = __builtin_amdgcn_mfma_f32_16x16x32_f16(
                        af[rb], bf[cb], acc[rb][cb], 0, 0, 0);
        }
        __syncthreads();
    }

    // scatter packed u32: n = g*512 + h*64 + d -> plane[(bb*8+h)*17+j][t][d]
    #pragma unroll
    for (int cb = 0; cb < 4; ++cb) {
        int n0 = col0 + wc*64 + cb*16;
        int g = n0 >> 9;
        unsigned int* dst0 = (g == 0) ? q32 : (g == 1) ? k32 : v32;
        int h = (n0 >> 6) & 7;
        int d = (n0 & 63) + lo;
        #pragma unroll
        for (int rb = 0; rb < 4; ++rb) {
            #pragma unroll
            for (int r = 0; r < 4; ++r) {
                int m = row0 + wr*64 + rb*16 + hi*4 + r;
                int bb = m / (TT*JJ);
                int rem = m - bb*(TT*JJ);
                int t = rem / JJ;
                int j = rem - t*JJ;
                size_t off = ((((size_t)bb*HH + h)*JJ + j)*TT + t)*HD + d;
                float val = acc[rb][cb][r];
                unsigned short hb = f2h(val);
                unsigned short lb = f2h(val - h2f(hb));
                dst0[off] = (unsigned int)hb | ((unsigned int)lb << 16);
            }
        }
    }
}

// ---------------- GEMM 2 (f16 MFMA, BK=64): out = y @ w_proj^T + b ----------
__global__ __launch_bounds__(256) void gemm_proj_k(
    const unsigned short* __restrict__ A, const unsigned short* __restrict__ B,
    const float* __restrict__ bias, float* __restrict__ out)
{
    __shared__ unsigned short Ah[128*64];
    __shared__ unsigned short Bh[128*64];
    const int tid = threadIdx.x;
    const int lane = tid & 63, wv = tid >> 6;
    const int lo = lane & 15, hi = lane >> 4;
    const int wr = wv >> 1, wc = wv & 1;
    const int bid = blockIdx.x;
    const int wrk = (bid & 7) * 272 + (bid >> 3);   // 2176 = 8*272, bijective
    const int col0 = (wrk % 4) * 128;
    const int row0 = (wrk / 4) * 128;

    f32x4 acc[4][4];
    #pragma unroll
    for (int rb = 0; rb < 4; ++rb)
        #pragma unroll
        for (int cb = 0; cb < 4; ++cb) acc[rb][cb] = (f32x4){0.f,0.f,0.f,0.f};

    for (int k0 = 0; k0 < 512; k0 += 64) {
        #pragma unroll
        for (int c = 0; c < 4; ++c) {
            int e = c*2048 + tid*8;
            int r = e >> 6, cc = e & 63;
            int ccs = cc ^ ((r & 7) << 3);
            size_t offA = (size_t)(row0 + r)*512 + k0 + ccs;
            size_t offB = (size_t)(col0 + r)*512 + k0 + ccs;
            GLD16(A + offA, (char*)Ah + c*4096 + (tid & 255)*16);
            GLD16(B + offB, (char*)Bh + c*4096 + (tid & 255)*16);
        }
        __syncthreads();
        #pragma unroll
        for (int ks = 0; ks < 2; ++ks) {
            f16x8 af[4], bf[4];
            #pragma unroll
            for (int rb = 0; rb < 4; ++rb) {
                int row = wr*64 + rb*16 + lo;
                int col = (ks*32 + hi*8) ^ ((row & 7) << 3);
                af[rb] = *(const f16x8*)&Ah[row*64 + col];
            }
            #pragma unroll
            for (int cb = 0; cb < 4; ++cb) {
                int row = wc*64 + cb*16 + lo;
                int col = (ks*32 + hi*8) ^ ((row & 7) << 3);
                bf[cb] = *(const f16x8*)&Bh[row*64 + col];
            }
            #pragma unroll
            for (int rb = 0; rb < 4; ++rb)
                #pragma unroll
                for (int cb = 0; cb < 4; ++cb)
                    acc[rb][cb] = __builtin_amdgcn_mfma_f32_16x16x32_f16(
                        af[rb], bf[cb], acc[rb][cb], 0, 0, 0);
        }
        __syncthreads();
    }

    #pragma unroll
    for (int cb = 0; cb < 4; ++cb) {
        int n = col0 + wc*64 + cb*16 + lo;
        float bv = bias[n];
        #pragma unroll
        for (int rb = 0; rb < 4; ++rb) {
            #pragma unroll
            for (int r = 0; r < 4; ++r) {
                int m = row0 + wr*64 + rb*16 + hi*4 + r;
                out[(size_t)m*512 + n] = acc[rb][cb][r] + bv;
            }
        }
    }
}

// ---------------- time attention via f16 MFMA (packed u32 plane inputs) -----
#define VTP 264
#define PPW 40

__global__ __launch_bounds__(256, 2) void attn_time_k(
    const unsigned int* __restrict__ q, const unsigned int* __restrict__ k,
    const unsigned int* __restrict__ v, const float* __restrict__ fg,
    float* __restrict__ y)
{
    __shared__ unsigned short VT[64 * VTP];
    __shared__ unsigned short PL[4 * 64 * PPW];

    const int bid = blockIdx.x;
    const int b = bid / (HH*JJ);
    const int h = (bid / JJ) % HH;
    const int j = bid % JJ;
    const size_t base = (size_t)bid * QTILE;

    const int tid = threadIdx.x;
    const int w = tid >> 6;
    const int lane = tid & 63;
    const int lo = lane & 15;
    const int hi = lane >> 4;

    {
        const unsigned int* vp = v + base + (size_t)tid * HD;
        #pragma unroll
        for (int d0 = 0; d0 < 64; d0 += 4) {
            uint4 vv = *(const uint4*)(vp + d0);
            VT[(d0+0)*VTP + tid] = (unsigned short)vv.x;
            VT[(d0+1)*VTP + tid] = (unsigned short)vv.y;
            VT[(d0+2)*VTP + tid] = (unsigned short)vv.z;
            VT[(d0+3)*VTP + tid] = (unsigned short)vv.w;
        }
    }
    __syncthreads();

    f16x8 qf[4][2];
    #pragma unroll
    for (int rb = 0; rb < 4; ++rb)
        #pragma unroll
        for (int dc = 0; dc < 2; ++dc)
            qf[rb][dc] = ld8hi(q + base + (size_t)(w*64 + rb*16 + lo)*HD + dc*32 + hi*8);

    f32x4 o[4][4];
    #pragma unroll
    for (int rb = 0; rb < 4; ++rb)
        #pragma unroll
        for (int cd = 0; cd < 4; ++cd) o[rb][cd] = (f32x4){0.f,0.f,0.f,0.f};
    float rs[4][4];
    #pragma unroll
    for (int rb = 0; rb < 4; ++rb)
        #pragma unroll
        for (int r = 0; r < 4; ++r) rs[rb][r] = 0.f;

    unsigned short* Pw = PL + w * 64 * PPW;

    for (int st = 0; st < 8; ++st) {
        const int s0 = st * 32;
        f16x8 kf[2][2];
        #pragma unroll
        for (int cb = 0; cb < 2; ++cb)
            #pragma unroll
            for (int dc = 0; dc < 2; ++dc)
                kf[cb][dc] = ld8hi(k + base + (size_t)(s0 + cb*16 + lo)*HD + dc*32 + hi*8);

        #pragma unroll
        for (int rb = 0; rb < 4; ++rb) {
            #pragma unroll
            for (int cb = 0; cb < 2; ++cb) {
                f32x4 acc = (f32x4){0.f,0.f,0.f,0.f};
                acc = __builtin_amdgcn_mfma_f32_16x16x32_f16(qf[rb][0], kf[cb][0], acc, 0, 0, 0);
                acc = __builtin_amdgcn_mfma_f32_16x16x32_f16(qf[rb][1], kf[cb][1], acc, 0, 0, 0);
                #pragma unroll
                for (int r = 0; r < 4; ++r) {
                    float p = __expf(acc[r] * 0.125f);
                    rs[rb][r] += p;
                    Pw[(rb*16 + hi*4 + r)*PPW + cb*16 + lo] = f2h(p);
                }
            }
        }

        f16x8 pa[4];
        #pragma unroll
        for (int rb = 0; rb < 4; ++rb)
            pa[rb] = *(const f16x8*)&Pw[(rb*16 + lo)*PPW + hi*8];
        f16x8 bv[4];
        #pragma unroll
        for (int cd = 0; cd < 4; ++cd)
            bv[cd] = *(const f16x8*)&VT[(cd*16 + lo)*VTP + s0 + hi*8];
        #pragma unroll
        for (int rb = 0; rb < 4; ++rb)
            #pragma unroll
            for (int cd = 0; cd < 4; ++cd)
                o[rb][cd] = __builtin_amdgcn_mfma_f32_16x16x32_f16(pa[rb], bv[cd], o[rb][cd], 0, 0, 0);
    }

    #pragma unroll
    for (int off = 1; off < 16; off <<= 1)
        #pragma unroll
        for (int rb = 0; rb < 4; ++rb)
            #pragma unroll
            for (int r = 0; r < 4; ++r)
                rs[rb][r] += __shfl_xor(rs[rb][r], off, 64);

    const float gate = 1.f / (1.f + __expf(-fg[0]));
    const float wt = 1.f - gate;
    #pragma unroll
    for (int rb = 0; rb < 4; ++rb) {
        #pragma unroll
        for (int r = 0; r < 4; ++r) {
            const int t = w*64 + rb*16 + hi*4 + r;
            const float sc = wt / rs[rb][r];
            float* yp = y + (((size_t)b*TT + t)*JJ + j)*CC + h*HD;
            #pragma unroll
            for (int cd = 0; cd < 4; ++cd)
                yp[cd*16 + lo] = o[rb][cd][r] * sc;
        }
    }
}

// ---------------- F1: DFT as split-f16 MFMA GEMM (packed u32 input) ---------
// C[128][64] = W[128][256] @ X[256][64]; rows 0-63 re, 64-127 im.
// X packed f16 hi/lo; W split f16. 3 products: Wh*Xh + Wh*Xl + Wl*Xh.
#define XP 280   // u16 pitch

__global__ __launch_bounds__(256) void dft_k(
    unsigned int* __restrict__ planes, const unsigned short* __restrict__ Whi,
    const unsigned short* __restrict__ Wlo)
{
    __shared__ unsigned short Xh[64*XP];
    __shared__ unsigned short Xl[64*XP];
    unsigned int* src = planes + (size_t)blockIdx.y*NQKV + (size_t)blockIdx.x*QTILE;
    float* obuf = (float*)src;
    const int tid = threadIdx.x;
    const int w = tid >> 6;
    const int lane = tid & 63;
    const int qd = (tid >> 4) & 3;
    const int rr = tid & 15;
    const int lo = lane & 15, hi = lane >> 4;

    #pragma unroll
    for (int p = 0; p < 16; ++p) {
        const int t = p*16 + 4*w + qd;
        uint4 x4 = *(const uint4*)&src[t*64 + 4*rr];
        unsigned int a0 = x4.x, a1 = x4.y, a2 = x4.z, a3 = x4.w;
        unsigned int t01 = (unsigned)__shfl_xor((int)((qd&1) ? a0 : a1), 16, 64);
        unsigned int t23 = (unsigned)__shfl_xor((int)((qd&1) ? a2 : a3), 16, 64);
        if (qd&1) { a0 = t01; a2 = t23; } else { a1 = t01; a3 = t23; }
        unsigned int u01 = (unsigned)__shfl_xor((int)((qd&2) ? a0 : a2), 32, 64);
        unsigned int u23 = (unsigned)__shfl_xor((int)((qd&2) ? a1 : a3), 32, 64);
        if (qd&2) { a0 = u01; a1 = u23; } else { a2 = u01; a3 = u23; }
        const int dd = 4*rr + qd;
        const int tb = p*16 + 4*w;
        ushort4 hv, lv;
        hv.x = (unsigned short)a0; lv.x = (unsigned short)(a0 >> 16);
        hv.y = (unsigned short)a1; lv.y = (unsigned short)(a1 >> 16);
        hv.z = (unsigned short)a2; lv.z = (unsigned short)(a2 >> 16);
        hv.w = (unsigned short)a3; lv.w = (unsigned short)(a3 >> 16);
        *(ushort4*)&Xh[dd*XP + tb] = hv;
        *(ushort4*)&Xl[dd*XP + tb] = lv;
    }
    __syncthreads();

    f32x4 acc[2][4];
    #pragma unroll
    for (int rb = 0; rb < 2; ++rb)
        #pragma unroll
        for (int cd = 0; cd < 4; ++cd) acc[rb][cd] = (f32x4){0.f,0.f,0.f,0.f};

    for (int ks = 0; ks < 8; ++ks) {
        const int k0 = ks*32;
        f16x8 ah[2], al[2];
        #pragma unroll
        for (int rb = 0; rb < 2; ++rb) {
            int r = w*32 + rb*16 + lo;
            ah[rb] = *(const f16x8*)&Whi[r*256 + k0 + hi*8];
            al[rb] = *(const f16x8*)&Wlo[r*256 + k0 + hi*8];
        }
        f16x8 bh[4], bl[4];
        #pragma unroll
        for (int cd = 0; cd < 4; ++cd) {
            int d = cd*16 + lo;
            bh[cd] = *(const f16x8*)&Xh[d*XP + k0 + hi*8];
            bl[cd] = *(const f16x8*)&Xl[d*XP + k0 + hi*8];
        }
        #pragma unroll
        for (int rb = 0; rb < 2; ++rb)
            #pragma unroll
            for (int cd = 0; cd < 4; ++cd) {
                acc[rb][cd] = __builtin_amdgcn_mfma_f32_16x16x32_f16(
                    ah[rb], bh[cd], acc[rb][cd], 0, 0, 0);
                acc[rb][cd] = __builtin_amdgcn_mfma_f32_16x16x32_f16(
                    ah[rb], bl[cd], acc[rb][cd], 0, 0, 0);
                acc[rb][cd] = __builtin_amdgcn_mfma_f32_16x16x32_f16(
                    al[rb], bh[cd], acc[rb][cd], 0, 0, 0);
            }
    }

    #pragma unroll
    for (int rb = 0; rb < 2; ++rb) {
        #pragma unroll
        for (int r = 0; r < 4; ++r) {
            int row = w*32 + rb*16 + hi*4 + r;
            float* dst = (row < 64) ? (obuf + row*64) : (obuf + 4096 + (row-64)*64);
            #pragma unroll
            for (int cd = 0; cd < 4; ++cd)
                dst[cd*16 + lo] = acc[rb][cd][r];
        }
    }
}

// ---------------- F2: af = scale*qf kf^H, dual softmax, xf = af vf ----------
__global__ __launch_bounds__(256) void afxf_k(
    float* __restrict__ qfv, const float* __restrict__ kfv,
    const float* __restrict__ vfv)
{
    extern __shared__ float lds[];
    float* A = lds;
    float* B = lds + 2*FHALF;

    const int tid = threadIdx.x;
    float* qf = qfv + (size_t)blockIdx.x * QTILE;
    const float* kf = kfv + (size_t)blockIdx.x * QTILE;
    const float* vf = vfv + (size_t)blockIdx.x * QTILE;

    #pragma unroll
    for (int p = 0; p < 8; ++p) {
        int idx = p*256 + tid;
        int part = idx >> 10;
        int rem = idx & 1023;
        int row = rem >> 4;
        int col = (rem & 15) * 4;
        *(float4*)(A + part*FHALF + row*FP + col) = *(const float4*)(qf + (size_t)idx*4);
        *(float4*)(B + part*FHALF + row*FP + col) = *(const float4*)(kf + (size_t)idx*4);
    }
    __syncthreads();

    const int fy = tid >> 4;
    const int gl = tid & 15;

    float cR[4][4], cI[4][4];
    #pragma unroll
    for (int i = 0; i < 4; ++i)
        #pragma unroll
        for (int gi = 0; gi < 4; ++gi) { cR[i][gi] = 0.f; cI[i][gi] = 0.f; }

    for (int d4 = 0; d4 < 16; ++d4) {
        float4 qr[4], qi[4], kr[4], ki[4];
        #pragma unroll
        for (int i = 0; i < 4; ++i) {
            int f = fy + 16*i;
            qr[i] = *(const float4*)(A + f*FP + d4*4);
            qi[i] = *(const float4*)(A + FHALF + f*FP + d4*4);
            int g = gl + 16*i;
            kr[i] = *(const float4*)(B + g*FP + d4*4);
            ki[i] = *(const float4*)(B + FHALF + g*FP + d4*4);
        }
        #pragma unroll
        for (int i = 0; i < 4; ++i)
            #pragma unroll
            for (int gi = 0; gi < 4; ++gi) {
                float r = cR[i][gi], m = cI[i][gi];
                r = fmaf(qr[i].x, kr[gi].x, r); r = fmaf(qi[i].x, ki[gi].x, r);
                r = fmaf(qr[i].y, kr[gi].y, r); r = fmaf(qi[i].y, ki[gi].y, r);
                r = fmaf(qr[i].z, kr[gi].z, r); r = fmaf(qi[i].z, ki[gi].z, r);
                r = fmaf(qr[i].w, kr[gi].w, r); r = fmaf(qi[i].w, ki[gi].w, r);
                m = fmaf(qi[i].x, kr[gi].x, m); m = fmaf(-qr[i].x, ki[gi].x, m);
                m = fmaf(qi[i].y, kr[gi].y, m); m = fmaf(-qr[i].y, ki[gi].y, m);
                m = fmaf(qi[i].z, kr[gi].z, m); m = fmaf(-qr[i].z, ki[gi].z, m);
                m = fmaf(qi[i].w, kr[gi].w, m); m = fmaf(-qr[i].w, ki[gi].w, m);
                cR[i][gi] = r; cI[i][gi] = m;
            }
    }
    __syncthreads();

    #pragma unroll
    for (int i = 0; i < 4; ++i)
        #pragma unroll
        for (int gi = 0; gi < 4; ++gi) {
            A[(fy + 16*i)*FP + gl + 16*gi]         = 0.125f * cR[i][gi];
            A[FHALF + (fy + 16*i)*FP + gl + 16*gi] = 0.125f * cI[i][gi];
        }
    #pragma unroll
    for (int p = 0; p < 8; ++p) {
        int idx = p*256 + tid;
        int part = idx >> 10;
        int rem = idx & 1023;
        int row = rem >> 4;
        int col = (rem & 15) * 4;
        *(float4*)(B + part*FHALF + row*FP + col) = *(const float4*)(vf + (size_t)idx*4);
    }
    __syncthreads();

    if (tid < 128) {
        float* row = A + (tid >> 6)*FHALF + (tid & 63)*FP;
        float mx = row[0];
        for (int g2 = 1; g2 < 64; ++g2) mx = fmaxf(mx, row[g2]);
        float sum = 0.f;
        for (int g2 = 0; g2 < 64; ++g2) { float e = __expf(row[g2]-mx); row[g2] = e; sum += e; }
        float inv = 1.f / sum;
        for (int g2 = 0; g2 < 64; ++g2) row[g2] *= inv;
    }
    __syncthreads();

    float xR[4][4], xI[4][4];
    #pragma unroll
    for (int i = 0; i < 4; ++i)
        #pragma unroll
        for (int cmp = 0; cmp < 4; ++cmp) { xR[i][cmp] = 0.f; xI[i][cmp] = 0.f; }

    for (int g2 = 0; g2 < 64; ++g2) {
        float4 vr = *(const float4*)(B + g2*FP + gl*4);
        float4 vi = *(const float4*)(B + FHALF + g2*FP + gl*4);
        #pragma unroll
        for (int i = 0; i < 4; ++i) {
            float sr = A[(fy + 16*i)*FP + g2];
            float si = A[FHALF + (fy + 16*i)*FP + g2];
            xR[i][0] = fmaf(sr, vr.x, fmaf(-si, vi.x, xR[i][0]));
            xI[i][0] = fmaf(sr, vi.x, fmaf( si, vr.x, xI[i][0]));
            xR[i][1] = fmaf(sr, vr.y, fmaf(-si, vi.y, xR[i][1]));
            xI[i][1] = fmaf(sr, vi.y, fmaf( si, vr.y, xI[i][1]));
            xR[i][2] = fmaf(sr, vr.z, fmaf(-si, vi.z, xR[i][2]));
            xI[i][2] = fmaf(sr, vi.z, fmaf( si, vr.z, xI[i][2]));
            xR[i][3] = fmaf(sr, vr.w, fmaf(-si, vi.w, xR[i][3]));
            xI[i][3] = fmaf(sr, vi.w, fmaf( si, vr.w, xI[i][3]));
        }
    }
    #pragma unroll
    for (int i = 0; i < 4; ++i) {
        int f = fy + 16*i;
        *(float4*)(qf + f*64 + gl*4)        = make_float4(xR[i][0],xR[i][1],xR[i][2],xR[i][3]);
        *(float4*)(qf + 4096 + f*64 + gl*4) = make_float4(xI[i][0],xI[i][1],xI[i][2],xI[i][3]);
    }
}

// ---------------- F3: zero-padded irfft (n=256) + gated accumulate into y ---
__global__ __launch_bounds__(256) void irfft_k(
    const float* __restrict__ qfv, const float* __restrict__ fg,
    float* __restrict__ y)
{
    __shared__ float xs[2*FHALF];
    const int tid = threadIdx.x;
    const int tile = blockIdx.x;
    const int b = tile / (HH*JJ);
    const int h = (tile / JJ) % HH;
    const int j = tile % JJ;
    const float* xf = qfv + (size_t)tile * QTILE;

    #pragma unroll
    for (int p = 0; p < 8; ++p) {
        int idx = p*256 + tid;
        int part = idx >> 10;
        int rem = idx & 1023;
        int row = rem >> 4;
        int col = (rem & 15) * 4;
        *(float4*)(xs + part*FHALF + row*FP + col) = *(const float4*)(xf + (size_t)idx*4);
    }
    __syncthreads();
    if (tid < 16) {
        float4* p = ((float4*)xs) + tid;
        float4 vv = *p;
        vv.x *= 0.5f; vv.y *= 0.5f; vv.z *= 0.5f; vv.w *= 0.5f;
        *p = vv;
    }
    __syncthreads();

    const int d0 = (tid & 7) * 8;
    const int ty = tid >> 3;

    float acc[8][8];
    #pragma unroll
    for (int ti = 0; ti < 8; ++ti)
        #pragma unroll
        for (int i = 0; i < 8; ++i) acc[ti][i] = 0.f;

    float cst[8], sst[8], c[8], s[8];
    #pragma unroll
    for (int ti = 0; ti < 8; ++ti) {
        sincosf(W0 * (float)(ty + 32*ti), &sst[ti], &cst[ti]);
        c[ti] = 1.f; s[ti] = 0.f;
    }

    for (int f = 0; f < 64; ++f) {
        float4 r0 = *(const float4*)(xs + f*FP + d0);
        float4 r1 = *(const float4*)(xs + f*FP + d0 + 4);
        float4 i0 = *(const float4*)(xs + FHALF + f*FP + d0);
        float4 i1 = *(const float4*)(xs + FHALF + f*FP + d0 + 4);
        #pragma unroll
        for (int ti = 0; ti < 8; ++ti) {
            float cc = c[ti], ss = s[ti];
            acc[ti][0] = fmaf(r0.x, cc, fmaf(-i0.x, ss, acc[ti][0]));
            acc[ti][1] = fmaf(r0.y, cc, fmaf(-i0.y, ss, acc[ti][1]));
            acc[ti][2] = fmaf(r0.z, cc, fmaf(-i0.z, ss, acc[ti][2]));
            acc[ti][3] = fmaf(r0.w, cc, fmaf(-i0.w, ss, acc[ti][3]));
            acc[ti][4] = fmaf(r1.x, cc, fmaf(-i1.x, ss, acc[ti][4]));
            acc[ti][5] = fmaf(r1.y, cc, fmaf(-i1.y, ss, acc[ti][5]));
            acc[ti][6] = fmaf(r1.z, cc, fmaf(-i1.z, ss, acc[ti][6]));
            acc[ti][7] = fmaf(r1.w, cc, fmaf(-i1.w, ss, acc[ti][7]));
            float nc = fmaf(cc, cst[ti], -(ss * sst[ti]));
            float ns = fmaf(cc, sst[ti],   ss * cst[ti]);
            c[ti] = nc; s[ti] = ns;
        }
    }

    const float gate = 1.f / (1.f + __expf(-fg[0]));
    const float sc = gate * (2.f / 256.f);
    #pragma unroll
    for (int ti = 0; ti < 8; ++ti) {
        int t = ty + 32*ti;
        float* yp = y + (((size_t)b*TT + t)*JJ + j)*CC + h*HD + d0;
        float4 c0 = *(float4*)yp;
        float4 c1 = *(float4*)(yp + 4);
        c0.x = fmaf(sc, acc[ti][0], c0.x); c0.y = fmaf(sc, acc[ti][1], c0.y);
        c0.z = fmaf(sc, acc[ti][2], c0.z); c0.w = fmaf(sc, acc[ti][3], c0.w);
        c1.x = fmaf(sc, acc[ti][4], c1.x); c1.y = fmaf(sc, acc[ti][5], c1.y);
        c1.z = fmaf(sc, acc[ti][6], c1.z); c1.w = fmaf(sc, acc[ti][7], c1.w);
        *(float4*)yp = c0;
        *(float4*)(yp + 4) = c1;
    }
}

// ---------------------------------------------------------------------------
// Workspace (4 x 142.6MB slots, time-multiplexed):
//  [0]: q32 packed f16 -> qf(f32) -> yh (conv->proj)
//  [1]: k32 packed f16 -> kf(f32) -> wph
//  [2]: v32 packed f16 -> vf(f32)
//  [3]: xh f16 (conv->gemm) -> y f32 (attn->conv)
//  d_out: wqh + W_hi/W_lo staging (dead before proj writes)
extern "C" void kernel_launch(void* const* d_in, const int* in_sizes, int n_in,
                              void* d_out, int out_size, void* d_ws, size_t ws_size,
                              hipStream_t stream) {
    const float* x      = (const float*)d_in[0];
    const float* w_qkv  = (const float*)d_in[1];
    const float* w_proj = (const float*)d_in[2];
    const float* b_proj = (const float*)d_in[3];
    const float* fg     = (const float*)d_in[4];
    float* out = (float*)d_out;

    char* wsb = (char*)d_ws;
    const size_t SLOT = (size_t)NQKV * 4;  // 142,606,336 B
    unsigned int* q32 = (unsigned int*)(wsb + 0*SLOT);
    unsigned int* k32 = (unsigned int*)(wsb + 1*SLOT);
    unsigned int* v32 = (unsigned int*)(wsb + 2*SLOT);
    unsigned short* xh = (unsigned short*)(wsb + 3*SLOT);
    float* y = (float*)(wsb + 3*SLOT);     // overwrites xh after gemm_qkv

    unsigned short* yh  = (unsigned short*)q32;   // q slot dead after irfft
    unsigned short* wph = (unsigned short*)k32;   // k slot dead after afxf
    unsigned short* wqh = (unsigned short*)d_out;
    unsigned short* Whi = wqh + 1536*512;
    unsigned short* Wlo = Whi + 128*256;

    (void)hipFuncSetAttribute((const void*)afxf_k,
                              hipFuncAttributeMaxDynamicSharedMemorySize, 4*FHALF*4);

    conv16_k<<<2048, 256, 0, stream>>>(x, xh, NQKV/8);
    conv16_k<<<384, 256, 0, stream>>>(w_qkv, wqh, 1536*512/8);
    winit_k<<<128, 256, 0, stream>>>(Whi, Wlo);

    gemm_qkv_k<<<6528, 256, 0, stream>>>(xh, wqh, q32, k32, v32);
    attn_time_k<<<NTILES, 256, 0, stream>>>(q32, k32, v32, fg, y);
    dft_k<<<dim3(NTILES, 3), 256, 0, stream>>>(q32, Whi, Wlo);
    afxf_k<<<NTILES, 256, 4*FHALF*4, stream>>>(
        (float*)q32, (const float*)k32, (const float*)v32);
    irfft_k<<<NTILES, 256, 0, stream>>>((const float*)q32, fg, y);

    conv16_k<<<2048, 256, 0, stream>>>(y, yh, NQKV/8);
    conv16_k<<<128, 256, 0, stream>>>(w_proj, wph, 512*512/8);
    gemm_proj_k<<<2176, 256, 0, stream>>>(yh, wph, b_proj, out);
}

// Round 10
// 807.944 us; speedup vs baseline: 1.5838x; 1.2397x over previous
//
#include <hip/hip_runtime.h>
#include <hip/hip_fp16.h>
#include <math.h>

#define NB 16
#define TT 256
#define JJ 17
#define CC 512
#define HH 8
#define HD 64
#define MROWS (NB*TT*JJ)        // 69632
#define QTILE 16384             // u16 elems per (b,h,j) tile
#define FSTRIDE 8192            // f32 elems per freq tile (re+im), in-place
#define NTILES (NB*HH*JJ)       // 2176
#define NQKV 35651584           // elements per plane (MROWS*512)

#define FP 68            // LDS pitch for 64-wide freq matrices
#define FHALF 4352       // 64*68
#define W0 0.0245436926061702596f   // 2*pi/256

typedef __attribute__((ext_vector_type(8))) short i16x8;
typedef __attribute__((ext_vector_type(8))) _Float16 f16x8;
typedef __attribute__((ext_vector_type(4))) float f32x4;

__device__ __forceinline__ unsigned short f2h(float f) {
    return (unsigned short)__half_as_ushort(__float2half(f));
}
__device__ __forceinline__ float h2f(unsigned short u) {
    return __half2float(__ushort_as_half(u));
}

#define GLD16(gp, lp) __builtin_amdgcn_global_load_lds( \
    (__attribute__((address_space(1))) void*)(gp), \
    (__attribute__((address_space(3))) void*)(lp), 16, 0, 0)

// ---------------- f32 -> f16 conversion (8-wide) ----------------------------
__global__ __launch_bounds__(256) void conv16_k(
    const float* __restrict__ s, unsigned short* __restrict__ d, int n8)
{
    for (int i = blockIdx.x*256 + threadIdx.x; i < n8; i += gridDim.x*256) {
        float4 a = ((const float4*)s)[i*2];
        float4 b = ((const float4*)s)[i*2+1];
        i16x8 h;
        h[0] = (short)f2h(a.x); h[1] = (short)f2h(a.y);
        h[2] = (short)f2h(a.z); h[3] = (short)f2h(a.w);
        h[4] = (short)f2h(b.x); h[5] = (short)f2h(b.y);
        h[6] = (short)f2h(b.z); h[7] = (short)f2h(b.w);
        ((i16x8*)d)[i] = h;
    }
}

// ---------------- twiddle matrix W[128][256] (split f16): cos / -sin --------
__global__ __launch_bounds__(256) void winit_k(
    unsigned short* __restrict__ Whi, unsigned short* __restrict__ Wlo)
{
    const int r = blockIdx.x;
    const int t = threadIdx.x;
    int idx = ((r & 63) * t) & 255;
    float sv, cv;
    sincosf(W0 * (float)idx, &sv, &cv);
    float val = (r < 64) ? cv : -sv;
    unsigned short h = f2h(val);
    Whi[r*256 + t] = h;
    Wlo[r*256 + t] = f2h(val - h2f(h));
}

// ---------------- GEMM 1 (f16 MFMA, BK=64): qkv = x @ w_qkv^T ---------------
// Output: f16 planes. XCD-chunked 1D grid; both-sides XOR LDS swizzle.
__global__ __launch_bounds__(256) void gemm_qkv_k(
    const unsigned short* __restrict__ A, const unsigned short* __restrict__ B,
    unsigned short* __restrict__ qp, unsigned short* __restrict__ kp,
    unsigned short* __restrict__ vp)
{
    __shared__ unsigned short Ah[128*64];
    __shared__ unsigned short Bh[128*64];
    const int tid = threadIdx.x;
    const int lane = tid & 63, wv = tid >> 6;
    const int lo = lane & 15, hi = lane >> 4;
    const int wr = wv >> 1, wc = wv & 1;
    const int bid = blockIdx.x;
    const int wrk = (bid & 7) * 816 + (bid >> 3);   // 6528 = 8*816, bijective
    const int col0 = (wrk % 12) * 128;
    const int row0 = (wrk / 12) * 128;

    f32x4 acc[4][4];
    #pragma unroll
    for (int rb = 0; rb < 4; ++rb)
        #pragma unroll
        for (int cb = 0; cb < 4; ++cb) acc[rb][cb] = (f32x4){0.f,0.f,0.f,0.f};

    for (int k0 = 0; k0 < 512; k0 += 64) {
        #pragma unroll
        for (int c = 0; c < 4; ++c) {
            int e = c*2048 + tid*8;
            int r = e >> 6, cc = e & 63;
            int ccs = cc ^ ((r & 7) << 3);
            size_t offA = (size_t)(row0 + r)*512 + k0 + ccs;
            size_t offB = (size_t)(col0 + r)*512 + k0 + ccs;
            GLD16(A + offA, (char*)Ah + c*4096 + tid*16);
            GLD16(B + offB, (char*)Bh + c*4096 + tid*16);
        }
        __syncthreads();
        #pragma unroll
        for (int ks = 0; ks < 2; ++ks) {
            f16x8 af[4], bf[4];
            #pragma unroll
            for (int rb = 0; rb < 4; ++rb) {
                int row = wr*64 + rb*16 + lo;
                int col = (ks*32 + hi*8) ^ ((row & 7) << 3);
                af[rb] = *(const f16x8*)&Ah[row*64 + col];
            }
            #pragma unroll
            for (int cb = 0; cb < 4; ++cb) {
                int row = wc*64 + cb*16 + lo;
                int col = (ks*32 + hi*8) ^ ((row & 7) << 3);
                bf[cb] = *(const f16x8*)&Bh[row*64 + col];
            }
            #pragma unroll
            for (int rb = 0; rb < 4; ++rb)
                #pragma unroll
                for (int cb = 0; cb < 4; ++cb)
                    acc[rb][cb] = __builtin_amdgcn_mfma_f32_16x16x32_f16(
                        af[rb], bf[cb], acc[rb][cb], 0, 0, 0);
        }
        __syncthreads();
    }

    // scatter f16: n = g*512 + h*64 + d -> plane[(bb*8+h)*17+j][t][d]
    #pragma unroll
    for (int cb = 0; cb < 4; ++cb) {
        int n0 = col0 + wc*64 + cb*16;
        int g = n0 >> 9;
        unsigned short* dst0 = (g == 0) ? qp : (g == 1) ? kp : vp;
        int h = (n0 >> 6) & 7;
        int d = (n0 & 63) + lo;
        #pragma unroll
        for (int rb = 0; rb < 4; ++rb) {
            #pragma unroll
            for (int r = 0; r < 4; ++r) {
                int m = row0 + wr*64 + rb*16 + hi*4 + r;
                int bb = m / (TT*JJ);
                int rem = m - bb*(TT*JJ);
                int t = rem / JJ;
                int j = rem - t*JJ;
                size_t off = ((((size_t)bb*HH + h)*JJ + j)*TT + t)*HD + d;
                dst0[off] = f2h(acc[rb][cb][r]);
            }
        }
    }
}

// ---------------- GEMM 2 (f16 MFMA, BK=64): out = y @ w_proj^T + b ----------
__global__ __launch_bounds__(256) void gemm_proj_k(
    const unsigned short* __restrict__ A, const unsigned short* __restrict__ B,
    const float* __restrict__ bias, float* __restrict__ out)
{
    __shared__ unsigned short Ah[128*64];
    __shared__ unsigned short Bh[128*64];
    const int tid = threadIdx.x;
    const int lane = tid & 63, wv = tid >> 6;
    const int lo = lane & 15, hi = lane >> 4;
    const int wr = wv >> 1, wc = wv & 1;
    const int bid = blockIdx.x;
    const int wrk = (bid & 7) * 272 + (bid >> 3);   // 2176 = 8*272, bijective
    const int col0 = (wrk % 4) * 128;
    const int row0 = (wrk / 4) * 128;

    f32x4 acc[4][4];
    #pragma unroll
    for (int rb = 0; rb < 4; ++rb)
        #pragma unroll
        for (int cb = 0; cb < 4; ++cb) acc[rb][cb] = (f32x4){0.f,0.f,0.f,0.f};

    for (int k0 = 0; k0 < 512; k0 += 64) {
        #pragma unroll
        for (int c = 0; c < 4; ++c) {
            int e = c*2048 + tid*8;
            int r = e >> 6, cc = e & 63;
            int ccs = cc ^ ((r & 7) << 3);
            size_t offA = (size_t)(row0 + r)*512 + k0 + ccs;
            size_t offB = (size_t)(col0 + r)*512 + k0 + ccs;
            GLD16(A + offA, (char*)Ah + c*4096 + tid*16);
            GLD16(B + offB, (char*)Bh + c*4096 + tid*16);
        }
        __syncthreads();
        #pragma unroll
        for (int ks = 0; ks < 2; ++ks) {
            f16x8 af[4], bf[4];
            #pragma unroll
            for (int rb = 0; rb < 4; ++rb) {
                int row = wr*64 + rb*16 + lo;
                int col = (ks*32 + hi*8) ^ ((row & 7) << 3);
                af[rb] = *(const f16x8*)&Ah[row*64 + col];
            }
            #pragma unroll
            for (int cb = 0; cb < 4; ++cb) {
                int row = wc*64 + cb*16 + lo;
                int col = (ks*32 + hi*8) ^ ((row & 7) << 3);
                bf[cb] = *(const f16x8*)&Bh[row*64 + col];
            }
            #pragma unroll
            for (int rb = 0; rb < 4; ++rb)
                #pragma unroll
                for (int cb = 0; cb < 4; ++cb)
                    acc[rb][cb] = __builtin_amdgcn_mfma_f32_16x16x32_f16(
                        af[rb], bf[cb], acc[rb][cb], 0, 0, 0);
        }
        __syncthreads();
    }

    #pragma unroll
    for (int cb = 0; cb < 4; ++cb) {
        int n = col0 + wc*64 + cb*16 + lo;
        float bv = bias[n];
        #pragma unroll
        for (int rb = 0; rb < 4; ++rb) {
            #pragma unroll
            for (int r = 0; r < 4; ++r) {
                int m = row0 + wr*64 + rb*16 + hi*4 + r;
                out[(size_t)m*512 + n] = acc[rb][cb][r] + bv;
            }
        }
    }
}

// ---------------- time attention via f16 MFMA (f16 plane inputs) ------------
#define VTP 264
#define PPW 40

__global__ __launch_bounds__(256, 2) void attn_time_k(
    const unsigned short* __restrict__ q, const unsigned short* __restrict__ k,
    const unsigned short* __restrict__ v, const float* __restrict__ fg,
    unsigned short* __restrict__ y)
{
    __shared__ unsigned short VT[64 * VTP];
    __shared__ unsigned short PL[4 * 64 * PPW];

    const int bid = blockIdx.x;
    const int b = bid / (HH*JJ);
    const int h = (bid / JJ) % HH;
    const int j = bid % JJ;
    const size_t base = (size_t)bid * QTILE;

    const int tid = threadIdx.x;
    const int w = tid >> 6;
    const int lane = tid & 63;
    const int lo = lane & 15;
    const int hi = lane >> 4;

    {
        const unsigned short* vptr = v + base + (size_t)tid * HD;
        #pragma unroll
        for (int d0 = 0; d0 < 64; d0 += 8) {
            i16x8 vv = *(const i16x8*)(vptr + d0);
            #pragma unroll
            for (int e = 0; e < 8; ++e)
                VT[(d0+e)*VTP + tid] = (unsigned short)vv[e];
        }
    }
    __syncthreads();

    f16x8 qf[4][2];
    #pragma unroll
    for (int rb = 0; rb < 4; ++rb)
        #pragma unroll
        for (int dc = 0; dc < 2; ++dc)
            qf[rb][dc] = *(const f16x8*)(q + base + (size_t)(w*64 + rb*16 + lo)*HD + dc*32 + hi*8);

    f32x4 o[4][4];
    #pragma unroll
    for (int rb = 0; rb < 4; ++rb)
        #pragma unroll
        for (int cd = 0; cd < 4; ++cd) o[rb][cd] = (f32x4){0.f,0.f,0.f,0.f};
    float rs[4][4];
    #pragma unroll
    for (int rb = 0; rb < 4; ++rb)
        #pragma unroll
        for (int r = 0; r < 4; ++r) rs[rb][r] = 0.f;

    unsigned short* Pw = PL + w * 64 * PPW;

    for (int st = 0; st < 8; ++st) {
        const int s0 = st * 32;
        f16x8 kf[2][2];
        #pragma unroll
        for (int cb = 0; cb < 2; ++cb)
            #pragma unroll
            for (int dc = 0; dc < 2; ++dc)
                kf[cb][dc] = *(const f16x8*)(k + base + (size_t)(s0 + cb*16 + lo)*HD + dc*32 + hi*8);

        #pragma unroll
        for (int rb = 0; rb < 4; ++rb) {
            #pragma unroll
            for (int cb = 0; cb < 2; ++cb) {
                f32x4 acc = (f32x4){0.f,0.f,0.f,0.f};
                acc = __builtin_amdgcn_mfma_f32_16x16x32_f16(qf[rb][0], kf[cb][0], acc, 0, 0, 0);
                acc = __builtin_amdgcn_mfma_f32_16x16x32_f16(qf[rb][1], kf[cb][1], acc, 0, 0, 0);
                #pragma unroll
                for (int r = 0; r < 4; ++r) {
                    float p = __expf(acc[r] * 0.125f);
                    rs[rb][r] += p;
                    Pw[(rb*16 + hi*4 + r)*PPW + cb*16 + lo] = f2h(p);
                }
            }
        }

        f16x8 pa[4];
        #pragma unroll
        for (int rb = 0; rb < 4; ++rb)
            pa[rb] = *(const f16x8*)&Pw[(rb*16 + lo)*PPW + hi*8];
        f16x8 bv[4];
        #pragma unroll
        for (int cd = 0; cd < 4; ++cd)
            bv[cd] = *(const f16x8*)&VT[(cd*16 + lo)*VTP + s0 + hi*8];
        #pragma unroll
        for (int rb = 0; rb < 4; ++rb)
            #pragma unroll
            for (int cd = 0; cd < 4; ++cd)
                o[rb][cd] = __builtin_amdgcn_mfma_f32_16x16x32_f16(pa[rb], bv[cd], o[rb][cd], 0, 0, 0);
    }

    #pragma unroll
    for (int off = 1; off < 16; off <<= 1)
        #pragma unroll
        for (int rb = 0; rb < 4; ++rb)
            #pragma unroll
            for (int r = 0; r < 4; ++r)
                rs[rb][r] += __shfl_xor(rs[rb][r], off, 64);

    const float gate = 1.f / (1.f + __expf(-fg[0]));
    const float wt = 1.f - gate;
    #pragma unroll
    for (int rb = 0; rb < 4; ++rb) {
        #pragma unroll
        for (int r = 0; r < 4; ++r) {
            const int t = w*64 + rb*16 + hi*4 + r;
            const float sc = wt / rs[rb][r];
            unsigned short* yp = y + (((size_t)b*TT + t)*JJ + j)*CC + h*HD;
            #pragma unroll
            for (int cd = 0; cd < 4; ++cd)
                yp[cd*16 + lo] = f2h(o[rb][cd][r] * sc);
        }
    }
}

// ---------------- F1: DFT as MFMA GEMM (f16 input, split-f16 W, 2 products) -
// C[128][64] = W[128][256] @ X[256][64]; rows 0-63 re, 64-127 im.
// Writes f32 re/im in place over the f16 tile (32KB = 32KB).
#define XP 280   // u16 pitch

__global__ __launch_bounds__(256) void dft_k(
    unsigned short* __restrict__ planes, const unsigned short* __restrict__ Whi,
    const unsigned short* __restrict__ Wlo)
{
    __shared__ unsigned short Xh[64*XP];
    unsigned short* src = planes + (size_t)blockIdx.y*NQKV + (size_t)blockIdx.x*QTILE;
    float* obuf = (float*)src;
    const int tid = threadIdx.x;
    const int w = tid >> 6;
    const int lane = tid & 63;
    const int qd = (tid >> 4) & 3;
    const int rr = tid & 15;
    const int lo = lane & 15, hi = lane >> 4;

    // stage: ushort4 loads, 4x4 shfl transpose (u16 in u32 containers)
    #pragma unroll
    for (int p = 0; p < 16; ++p) {
        const int t = p*16 + 4*w + qd;
        ushort4 x4 = *(const ushort4*)&src[t*64 + 4*rr];
        unsigned int a0 = x4.x, a1 = x4.y, a2 = x4.z, a3 = x4.w;
        unsigned int t01 = (unsigned)__shfl_xor((int)((qd&1) ? a0 : a1), 16, 64);
        unsigned int t23 = (unsigned)__shfl_xor((int)((qd&1) ? a2 : a3), 16, 64);
        if (qd&1) { a0 = t01; a2 = t23; } else { a1 = t01; a3 = t23; }
        unsigned int u01 = (unsigned)__shfl_xor((int)((qd&2) ? a0 : a2), 32, 64);
        unsigned int u23 = (unsigned)__shfl_xor((int)((qd&2) ? a1 : a3), 32, 64);
        if (qd&2) { a0 = u01; a1 = u23; } else { a2 = u01; a3 = u23; }
        const int dd = 4*rr + qd;
        const int tb = p*16 + 4*w;
        ushort4 hv;
        hv.x = (unsigned short)a0; hv.y = (unsigned short)a1;
        hv.z = (unsigned short)a2; hv.w = (unsigned short)a3;
        *(ushort4*)&Xh[dd*XP + tb] = hv;
    }
    __syncthreads();

    f32x4 acc[2][4];
    #pragma unroll
    for (int rb = 0; rb < 2; ++rb)
        #pragma unroll
        for (int cd = 0; cd < 4; ++cd) acc[rb][cd] = (f32x4){0.f,0.f,0.f,0.f};

    for (int ks = 0; ks < 8; ++ks) {
        const int k0 = ks*32;
        f16x8 ah[2], al[2];
        #pragma unroll
        for (int rb = 0; rb < 2; ++rb) {
            int r = w*32 + rb*16 + lo;
            ah[rb] = *(const f16x8*)&Whi[r*256 + k0 + hi*8];
            al[rb] = *(const f16x8*)&Wlo[r*256 + k0 + hi*8];
        }
        f16x8 bh[4];
        #pragma unroll
        for (int cd = 0; cd < 4; ++cd) {
            int d = cd*16 + lo;
            bh[cd] = *(const f16x8*)&Xh[d*XP + k0 + hi*8];
        }
        #pragma unroll
        for (int rb = 0; rb < 2; ++rb)
            #pragma unroll
            for (int cd = 0; cd < 4; ++cd) {
                acc[rb][cd] = __builtin_amdgcn_mfma_f32_16x16x32_f16(
                    ah[rb], bh[cd], acc[rb][cd], 0, 0, 0);
                acc[rb][cd] = __builtin_amdgcn_mfma_f32_16x16x32_f16(
                    al[rb], bh[cd], acc[rb][cd], 0, 0, 0);
            }
    }

    #pragma unroll
    for (int rb = 0; rb < 2; ++rb) {
        #pragma unroll
        for (int r = 0; r < 4; ++r) {
            int row = w*32 + rb*16 + hi*4 + r;
            float* dst = (row < 64) ? (obuf + row*64) : (obuf + 4096 + (row-64)*64);
            #pragma unroll
            for (int cd = 0; cd < 4; ++cd)
                dst[cd*16 + lo] = acc[rb][cd][r];
        }
    }
}

// ---------------- F2: af = scale*qf kf^H, dual softmax, xf = af vf ----------
__global__ __launch_bounds__(256) void afxf_k(
    float* __restrict__ qfv, const float* __restrict__ kfv,
    const float* __restrict__ vfv)
{
    extern __shared__ float lds[];
    float* A = lds;
    float* B = lds + 2*FHALF;

    const int tid = threadIdx.x;
    float* qf = qfv + (size_t)blockIdx.x * FSTRIDE;
    const float* kf = kfv + (size_t)blockIdx.x * FSTRIDE;
    const float* vf = vfv + (size_t)blockIdx.x * FSTRIDE;

    #pragma unroll
    for (int p = 0; p < 8; ++p) {
        int idx = p*256 + tid;
        int part = idx >> 10;
        int rem = idx & 1023;
        int row = rem >> 4;
        int col = (rem & 15) * 4;
        *(float4*)(A + part*FHALF + row*FP + col) = *(const float4*)(qf + (size_t)idx*4);
        *(float4*)(B + part*FHALF + row*FP + col) = *(const float4*)(kf + (size_t)idx*4);
    }
    __syncthreads();

    const int fy = tid >> 4;
    const int gl = tid & 15;

    float cR[4][4], cI[4][4];
    #pragma unroll
    for (int i = 0; i < 4; ++i)
        #pragma unroll
        for (int gi = 0; gi < 4; ++gi) { cR[i][gi] = 0.f; cI[i][gi] = 0.f; }

    for (int d4 = 0; d4 < 16; ++d4) {
        float4 qr[4], qi[4], kr[4], ki[4];
        #pragma unroll
        for (int i = 0; i < 4; ++i) {
            int f = fy + 16*i;
            qr[i] = *(const float4*)(A + f*FP + d4*4);
            qi[i] = *(const float4*)(A + FHALF + f*FP + d4*4);
            int g = gl + 16*i;
            kr[i] = *(const float4*)(B + g*FP + d4*4);
            ki[i] = *(const float4*)(B + FHALF + g*FP + d4*4);
        }
        #pragma unroll
        for (int i = 0; i < 4; ++i)
            #pragma unroll
            for (int gi = 0; gi < 4; ++gi) {
                float r = cR[i][gi], m = cI[i][gi];
                r = fmaf(qr[i].x, kr[gi].x, r); r = fmaf(qi[i].x, ki[gi].x, r);
                r = fmaf(qr[i].y, kr[gi].y, r); r = fmaf(qi[i].y, ki[gi].y, r);
                r = fmaf(qr[i].z, kr[gi].z, r); r = fmaf(qi[i].z, ki[gi].z, r);
                r = fmaf(qr[i].w, kr[gi].w, r); r = fmaf(qi[i].w, ki[gi].w, r);
                m = fmaf(qi[i].x, kr[gi].x, m); m = fmaf(-qr[i].x, ki[gi].x, m);
                m = fmaf(qi[i].y, kr[gi].y, m); m = fmaf(-qr[i].y, ki[gi].y, m);
                m = fmaf(qi[i].z, kr[gi].z, m); m = fmaf(-qr[i].z, ki[gi].z, m);
                m = fmaf(qi[i].w, kr[gi].w, m); m = fmaf(-qr[i].w, ki[gi].w, m);
                cR[i][gi] = r; cI[i][gi] = m;
            }
    }
    __syncthreads();

    #pragma unroll
    for (int i = 0; i < 4; ++i)
        #pragma unroll
        for (int gi = 0; gi < 4; ++gi) {
            A[(fy + 16*i)*FP + gl + 16*gi]         = 0.125f * cR[i][gi];
            A[FHALF + (fy + 16*i)*FP + gl + 16*gi] = 0.125f * cI[i][gi];
        }
    #pragma unroll
    for (int p = 0; p < 8; ++p) {
        int idx = p*256 + tid;
        int part = idx >> 10;
        int rem = idx & 1023;
        int row = rem >> 4;
        int col = (rem & 15) * 4;
        *(float4*)(B + part*FHALF + row*FP + col) = *(const float4*)(vf + (size_t)idx*4);
    }
    __syncthreads();

    if (tid < 128) {
        float* row = A + (tid >> 6)*FHALF + (tid & 63)*FP;
        float mx = row[0];
        for (int g2 = 1; g2 < 64; ++g2) mx = fmaxf(mx, row[g2]);
        float sum = 0.f;
        for (int g2 = 0; g2 < 64; ++g2) { float e = __expf(row[g2]-mx); row[g2] = e; sum += e; }
        float inv = 1.f / sum;
        for (int g2 = 0; g2 < 64; ++g2) row[g2] *= inv;
    }
    __syncthreads();

    float xR[4][4], xI[4][4];
    #pragma unroll
    for (int i = 0; i < 4; ++i)
        #pragma unroll
        for (int cmp = 0; cmp < 4; ++cmp) { xR[i][cmp] = 0.f; xI[i][cmp] = 0.f; }

    for (int g2 = 0; g2 < 64; ++g2) {
        float4 vr = *(const float4*)(B + g2*FP + gl*4);
        float4 vi = *(const float4*)(B + FHALF + g2*FP + gl*4);
        #pragma unroll
        for (int i = 0; i < 4; ++i) {
            float sr = A[(fy + 16*i)*FP + g2];
            float si = A[FHALF + (fy + 16*i)*FP + g2];
            xR[i][0] = fmaf(sr, vr.x, fmaf(-si, vi.x, xR[i][0]));
            xI[i][0] = fmaf(sr, vi.x, fmaf( si, vr.x, xI[i][0]));
            xR[i][1] = fmaf(sr, vr.y, fmaf(-si, vi.y, xR[i][1]));
            xI[i][1] = fmaf(sr, vi.y, fmaf( si, vr.y, xI[i][1]));
            xR[i][2] = fmaf(sr, vr.z, fmaf(-si, vi.z, xR[i][2]));
            xI[i][2] = fmaf(sr, vi.z, fmaf( si, vr.z, xI[i][2]));
            xR[i][3] = fmaf(sr, vr.w, fmaf(-si, vi.w, xR[i][3]));
            xI[i][3] = fmaf(sr, vi.w, fmaf( si, vr.w, xI[i][3]));
        }
    }
    #pragma unroll
    for (int i = 0; i < 4; ++i) {
        int f = fy + 16*i;
        *(float4*)(qf + f*64 + gl*4)        = make_float4(xR[i][0],xR[i][1],xR[i][2],xR[i][3]);
        *(float4*)(qf + 4096 + f*64 + gl*4) = make_float4(xI[i][0],xI[i][1],xI[i][2],xI[i][3]);
    }
}

// ---------------- F3: zero-padded irfft (n=256) + gated f16 RMW into y ------
__global__ __launch_bounds__(256) void irfft_k(
    const float* __restrict__ qfv, const float* __restrict__ fg,
    unsigned short* __restrict__ y)
{
    __shared__ float xs[2*FHALF];
    const int tid = threadIdx.x;
    const int tile = blockIdx.x;
    const int b = tile / (HH*JJ);
    const int h = (tile / JJ) % HH;
    const int j = tile % JJ;
    const float* xf = qfv + (size_t)tile * FSTRIDE;

    #pragma unroll
    for (int p = 0; p < 8; ++p) {
        int idx = p*256 + tid;
        int part = idx >> 10;
        int rem = idx & 1023;
        int row = rem >> 4;
        int col = (rem & 15) * 4;
        *(float4*)(xs + part*FHALF + row*FP + col) = *(const float4*)(xf + (size_t)idx*4);
    }
    __syncthreads();
    if (tid < 16) {
        float4* p = ((float4*)xs) + tid;
        float4 vv = *p;
        vv.x *= 0.5f; vv.y *= 0.5f; vv.z *= 0.5f; vv.w *= 0.5f;
        *p = vv;
    }
    __syncthreads();

    const int d0 = (tid & 7) * 8;
    const int ty = tid >> 3;

    float acc[8][8];
    #pragma unroll
    for (int ti = 0; ti < 8; ++ti)
        #pragma unroll
        for (int i = 0; i < 8; ++i) acc[ti][i] = 0.f;

    float cst[8], sst[8], c[8], s[8];
    #pragma unroll
    for (int ti = 0; ti < 8; ++ti) {
        sincosf(W0 * (float)(ty + 32*ti), &sst[ti], &cst[ti]);
        c[ti] = 1.f; s[ti] = 0.f;
    }

    for (int f = 0; f < 64; ++f) {
        float4 r0 = *(const float4*)(xs + f*FP + d0);
        float4 r1 = *(const float4*)(xs + f*FP + d0 + 4);
        float4 i0 = *(const float4*)(xs + FHALF + f*FP + d0);
        float4 i1 = *(const float4*)(xs + FHALF + f*FP + d0 + 4);
        #pragma unroll
        for (int ti = 0; ti < 8; ++ti) {
            float cc = c[ti], ss = s[ti];
            acc[ti][0] = fmaf(r0.x, cc, fmaf(-i0.x, ss, acc[ti][0]));
            acc[ti][1] = fmaf(r0.y, cc, fmaf(-i0.y, ss, acc[ti][1]));
            acc[ti][2] = fmaf(r0.z, cc, fmaf(-i0.z, ss, acc[ti][2]));
            acc[ti][3] = fmaf(r0.w, cc, fmaf(-i0.w, ss, acc[ti][3]));
            acc[ti][4] = fmaf(r1.x, cc, fmaf(-i1.x, ss, acc[ti][4]));
            acc[ti][5] = fmaf(r1.y, cc, fmaf(-i1.y, ss, acc[ti][5]));
            acc[ti][6] = fmaf(r1.z, cc, fmaf(-i1.z, ss, acc[ti][6]));
            acc[ti][7] = fmaf(r1.w, cc, fmaf(-i1.w, ss, acc[ti][7]));
            float nc = fmaf(cc, cst[ti], -(ss * sst[ti]));
            float ns = fmaf(cc, sst[ti],   ss * cst[ti]);
            c[ti] = nc; s[ti] = ns;
        }
    }

    const float gate = 1.f / (1.f + __expf(-fg[0]));
    const float sc = gate * (2.f / 256.f);
    #pragma unroll
    for (int ti = 0; ti < 8; ++ti) {
        int t = ty + 32*ti;
        unsigned short* yp = y + (((size_t)b*TT + t)*JJ + j)*CC + h*HD + d0;
        i16x8 cur = *(const i16x8*)yp;
        i16x8 nv;
        #pragma unroll
        for (int i = 0; i < 8; ++i)
            nv[i] = (short)f2h(fmaf(sc, acc[ti][i], h2f((unsigned short)cur[i])));
        *(i16x8*)yp = nv;
    }
}

// ---------------------------------------------------------------------------
// Workspace (f16 planes, 71.3MB each; ~357MB used of 570MB):
//  [0]: q f16 -> qf f32 in place (32KB/tile)    [1]: k f16 -> kf
//  [2]: v f16 -> vf                             [3]: x f16 (dead after gemm)
//  [4]: y f16 (attn writes, irfft RMW, proj A)  [+]: wp f16
//  d_out: wq f16 + W hi/lo staging (dead before proj writes)
extern "C" void kernel_launch(void* const* d_in, const int* in_sizes, int n_in,
                              void* d_out, int out_size, void* d_ws, size_t ws_size,
                              hipStream_t stream) {
    const float* x      = (const float*)d_in[0];
    const float* w_qkv  = (const float*)d_in[1];
    const float* w_proj = (const float*)d_in[2];
    const float* b_proj = (const float*)d_in[3];
    const float* fg     = (const float*)d_in[4];
    float* out = (float*)d_out;

    unsigned short* qp = (unsigned short*)d_ws;
    unsigned short* kp = qp + NQKV;
    unsigned short* vp = kp + NQKV;
    unsigned short* xh = vp + NQKV;
    unsigned short* y  = xh + NQKV;
    unsigned short* wph = y + NQKV;
    unsigned short* wqh = (unsigned short*)d_out;
    unsigned short* Whi = wqh + 1536*512;
    unsigned short* Wlo = Whi + 128*256;

    (void)hipFuncSetAttribute((const void*)afxf_k,
                              hipFuncAttributeMaxDynamicSharedMemorySize, 4*FHALF*4);

    conv16_k<<<2048, 256, 0, stream>>>(x, xh, NQKV/8);
    conv16_k<<<384, 256, 0, stream>>>(w_qkv, wqh, 1536*512/8);
    conv16_k<<<128, 256, 0, stream>>>(w_proj, wph, 512*512/8);
    winit_k<<<128, 256, 0, stream>>>(Whi, Wlo);

    gemm_qkv_k<<<6528, 256, 0, stream>>>(xh, wqh, qp, kp, vp);
    attn_time_k<<<NTILES, 256, 0, stream>>>(qp, kp, vp, fg, y);
    dft_k<<<dim3(NTILES, 3), 256, 0, stream>>>(qp, Whi, Wlo);
    afxf_k<<<NTILES, 256, 4*FHALF*4, stream>>>(
        (float*)qp, (const float*)kp, (const float*)vp);
    irfft_k<<<NTILES, 256, 0, stream>>>((const float*)qp, fg, y);

    gemm_proj_k<<<2176, 256, 0, stream>>>(y, wph, b_proj, out);
}

// Round 11
// 735.449 us; speedup vs baseline: 1.7399x; 1.0986x over previous
//
#include <hip/hip_runtime.h>
#include <hip/hip_fp16.h>
#include <math.h>

#define NB 16
#define TT 256
#define JJ 17
#define CC 512
#define HH 8
#define HD 64
#define MROWS (NB*TT*JJ)        // 69632
#define QTILE 16384             // u16 elems per (b,h,j) tile
#define NTILES (NB*HH*JJ)       // 2176
#define NQKV 35651584           // elements per plane (MROWS*512)

#define FP 68            // LDS pitch for 64-wide freq matrices (f32)
#define FHALF 4352       // 64*68
#define W0 0.0245436926061702596f   // 2*pi/256

typedef __attribute__((ext_vector_type(8))) short i16x8;
typedef __attribute__((ext_vector_type(8))) _Float16 f16x8;
typedef __attribute__((ext_vector_type(4))) float f32x4;

__device__ __forceinline__ unsigned short f2h(float f) {
    return (unsigned short)__half_as_ushort(__float2half(f));
}
__device__ __forceinline__ float h2f(unsigned short u) {
    return __half2float(__ushort_as_half(u));
}

#define GLD16(gp, lp) __builtin_amdgcn_global_load_lds( \
    (__attribute__((address_space(1))) void*)(gp), \
    (__attribute__((address_space(3))) void*)(lp), 16, 0, 0)

// ---------------- f32 -> f16 conversion (8-wide) ----------------------------
__global__ __launch_bounds__(256) void conv16_k(
    const float* __restrict__ s, unsigned short* __restrict__ d, int n8)
{
    for (int i = blockIdx.x*256 + threadIdx.x; i < n8; i += gridDim.x*256) {
        float4 a = ((const float4*)s)[i*2];
        float4 b = ((const float4*)s)[i*2+1];
        i16x8 h;
        h[0] = (short)f2h(a.x); h[1] = (short)f2h(a.y);
        h[2] = (short)f2h(a.z); h[3] = (short)f2h(a.w);
        h[4] = (short)f2h(b.x); h[5] = (short)f2h(b.y);
        h[6] = (short)f2h(b.z); h[7] = (short)f2h(b.w);
        ((i16x8*)d)[i] = h;
    }
}

// ---------------- forward twiddle W[128][256] (split f16): cos / -sin -------
__global__ __launch_bounds__(256) void winit_k(
    unsigned short* __restrict__ Whi, unsigned short* __restrict__ Wlo)
{
    const int r = blockIdx.x;
    const int t = threadIdx.x;
    int idx = ((r & 63) * t) & 255;
    float sv, cv;
    sincosf(W0 * (float)idx, &sv, &cv);
    float val = (r < 64) ? cv : -sv;
    unsigned short h = f2h(val);
    Whi[r*256 + t] = h;
    Wlo[r*256 + t] = f2h(val - h2f(h));
}

// ---------------- inverse twiddle WI[256][128] (split f16) ------------------
// WI[t][f<64] = cf*cos(2pi t f/256)*(2/256), cf=0.5 for f=0
// WI[t][64+f'] = -sin(2pi t f'/256)*(2/256)   (f'=0 col is 0: DC imag drops)
__global__ __launch_bounds__(128) void winit2_k(
    unsigned short* __restrict__ WIhi, unsigned short* __restrict__ WIlo)
{
    const int t = blockIdx.x;       // 0..255
    const int f = threadIdx.x;      // 0..127
    int fr = f & 63;
    int idx = (t * fr) & 255;
    float sv, cv;
    sincosf(W0 * (float)idx, &sv, &cv);
    float cf = (fr == 0 && f < 64) ? 0.5f : 1.f;
    float val = ((f < 64) ? cv : -sv) * cf * (2.f / 256.f);
    unsigned short h = f2h(val);
    WIhi[t*128 + f] = h;
    WIlo[t*128 + f] = f2h(val - h2f(h));
}

// ---------------- GEMM 1 (f16 MFMA, BK=64): qkv = x @ w_qkv^T ---------------
__global__ __launch_bounds__(256) void gemm_qkv_k(
    const unsigned short* __restrict__ A, const unsigned short* __restrict__ B,
    unsigned short* __restrict__ qp, unsigned short* __restrict__ kp,
    unsigned short* __restrict__ vp)
{
    __shared__ unsigned short Ah[128*64];
    __shared__ unsigned short Bh[128*64];
    const int tid = threadIdx.x;
    const int lane = tid & 63;
    const int lo = lane & 15, hi = lane >> 4;
    const int wv = tid >> 6;
    const int wr = wv >> 1, wc = wv & 1;
    const int bid = blockIdx.x;
    const int wrk = (bid & 7) * 816 + (bid >> 3);   // 6528 = 8*816, bijective
    const int col0 = (wrk % 12) * 128;
    const int row0 = (wrk / 12) * 128;

    f32x4 acc[4][4];
    #pragma unroll
    for (int rb = 0; rb < 4; ++rb)
        #pragma unroll
        for (int cb = 0; cb < 4; ++cb) acc[rb][cb] = (f32x4){0.f,0.f,0.f,0.f};

    for (int k0 = 0; k0 < 512; k0 += 64) {
        #pragma unroll
        for (int c = 0; c < 4; ++c) {
            int e = c*2048 + tid*8;
            int r = e >> 6, cc = e & 63;
            int ccs = cc ^ ((r & 7) << 3);
            size_t offA = (size_t)(row0 + r)*512 + k0 + ccs;
            size_t offB = (size_t)(col0 + r)*512 + k0 + ccs;
            GLD16(A + offA, (char*)Ah + c*4096 + tid*16);
            GLD16(B + offB, (char*)Bh + c*4096 + tid*16);
        }
        __syncthreads();
        #pragma unroll
        for (int ks = 0; ks < 2; ++ks) {
            f16x8 af[4], bf[4];
            #pragma unroll
            for (int rb = 0; rb < 4; ++rb) {
                int row = wr*64 + rb*16 + lo;
                int col = (ks*32 + hi*8) ^ ((row & 7) << 3);
                af[rb] = *(const f16x8*)&Ah[row*64 + col];
            }
            #pragma unroll
            for (int cb = 0; cb < 4; ++cb) {
                int row = wc*64 + cb*16 + lo;
                int col = (ks*32 + hi*8) ^ ((row & 7) << 3);
                bf[cb] = *(const f16x8*)&Bh[row*64 + col];
            }
            #pragma unroll
            for (int rb = 0; rb < 4; ++rb)
                #pragma unroll
                for (int cb = 0; cb < 4; ++cb)
                    acc[rb][cb] = __builtin_amdgcn_mfma_f32_16x16x32_f16(
                        af[rb], bf[cb], acc[rb][cb], 0, 0, 0);
        }
        __syncthreads();
    }

    // hoisted m -> (bb, t, j) decomposition (independent of cb)
    int bbA[4][4], ttA[4][4], jjA[4][4];
    #pragma unroll
    for (int rb = 0; rb < 4; ++rb)
        #pragma unroll
        for (int r = 0; r < 4; ++r) {
            int m = row0 + wr*64 + rb*16 + hi*4 + r;
            int bb = m / (TT*JJ);
            int rem = m - bb*(TT*JJ);
            int t = rem / JJ;
            bbA[rb][r] = bb; ttA[rb][r] = t; jjA[rb][r] = rem - t*JJ;
        }

    #pragma unroll
    for (int cb = 0; cb < 4; ++cb) {
        int n0 = col0 + wc*64 + cb*16;
        int g = n0 >> 9;
        unsigned short* dst0 = (g == 0) ? qp : (g == 1) ? kp : vp;
        int h = (n0 >> 6) & 7;
        int d = (n0 & 63) + lo;
        #pragma unroll
        for (int rb = 0; rb < 4; ++rb)
            #pragma unroll
            for (int r = 0; r < 4; ++r) {
                size_t off = ((((size_t)bbA[rb][r]*HH + h)*JJ + jjA[rb][r])*TT
                              + ttA[rb][r])*HD + d;
                dst0[off] = f2h(acc[rb][cb][r]);
            }
    }
}

// ---------------- GEMM 2 (f16 MFMA, BK=64): out = y @ w_proj^T + b ----------
__global__ __launch_bounds__(256) void gemm_proj_k(
    const unsigned short* __restrict__ A, const unsigned short* __restrict__ B,
    const float* __restrict__ bias, float* __restrict__ out)
{
    __shared__ unsigned short Ah[128*64];
    __shared__ unsigned short Bh[128*64];
    const int tid = threadIdx.x;
    const int lane = tid & 63;
    const int lo = lane & 15, hi = lane >> 4;
    const int wv = tid >> 6;
    const int wr = wv >> 1, wc = wv & 1;
    const int bid = blockIdx.x;
    const int wrk = (bid & 7) * 272 + (bid >> 3);   // 2176 = 8*272, bijective
    const int col0 = (wrk % 4) * 128;
    const int row0 = (wrk / 4) * 128;

    f32x4 acc[4][4];
    #pragma unroll
    for (int rb = 0; rb < 4; ++rb)
        #pragma unroll
        for (int cb = 0; cb < 4; ++cb) acc[rb][cb] = (f32x4){0.f,0.f,0.f,0.f};

    for (int k0 = 0; k0 < 512; k0 += 64) {
        #pragma unroll
        for (int c = 0; c < 4; ++c) {
            int e = c*2048 + tid*8;
            int r = e >> 6, cc = e & 63;
            int ccs = cc ^ ((r & 7) << 3);
            size_t offA = (size_t)(row0 + r)*512 + k0 + ccs;
            size_t offB = (size_t)(col0 + r)*512 + k0 + ccs;
            GLD16(A + offA, (char*)Ah + c*4096 + tid*16);
            GLD16(B + offB, (char*)Bh + c*4096 + tid*16);
        }
        __syncthreads();
        #pragma unroll
        for (int ks = 0; ks < 2; ++ks) {
            f16x8 af[4], bf[4];
            #pragma unroll
            for (int rb = 0; rb < 4; ++rb) {
                int row = wr*64 + rb*16 + lo;
                int col = (ks*32 + hi*8) ^ ((row & 7) << 3);
                af[rb] = *(const f16x8*)&Ah[row*64 + col];
            }
            #pragma unroll
            for (int cb = 0; cb < 4; ++cb) {
                int row = wc*64 + cb*16 + lo;
                int col = (ks*32 + hi*8) ^ ((row & 7) << 3);
                bf[cb] = *(const f16x8*)&Bh[row*64 + col];
            }
            #pragma unroll
            for (int rb = 0; rb < 4; ++rb)
                #pragma unroll
                for (int cb = 0; cb < 4; ++cb)
                    acc[rb][cb] = __builtin_amdgcn_mfma_f32_16x16x32_f16(
                        af[rb], bf[cb], acc[rb][cb], 0, 0, 0);
        }
        __syncthreads();
    }

    #pragma unroll
    for (int cb = 0; cb < 4; ++cb) {
        int n = col0 + wc*64 + cb*16 + lo;
        float bv = bias[n];
        #pragma unroll
        for (int rb = 0; rb < 4; ++rb)
            #pragma unroll
            for (int r = 0; r < 4; ++r) {
                int m = row0 + wr*64 + rb*16 + hi*4 + r;
                out[(size_t)m*512 + n] = acc[rb][cb][r] + bv;
            }
    }
}

// ---------------- time attention via f16 MFMA (f16 plane inputs) ------------
#define VTP 264
#define PPW 40

__global__ __launch_bounds__(256, 2) void attn_time_k(
    const unsigned short* __restrict__ q, const unsigned short* __restrict__ k,
    const unsigned short* __restrict__ v, const float* __restrict__ fg,
    unsigned short* __restrict__ y)
{
    __shared__ unsigned short VT[64 * VTP];
    __shared__ unsigned short PL[4 * 64 * PPW];

    const int bid = blockIdx.x;
    const int b = bid / (HH*JJ);
    const int h = (bid / JJ) % HH;
    const int j = bid % JJ;
    const size_t base = (size_t)bid * QTILE;

    const int tid = threadIdx.x;
    const int w = tid >> 6;
    const int lane = tid & 63;
    const int lo = lane & 15;
    const int hi = lane >> 4;

    {
        const unsigned short* vptr = v + base + (size_t)tid * HD;
        #pragma unroll
        for (int d0 = 0; d0 < 64; d0 += 8) {
            i16x8 vv = *(const i16x8*)(vptr + d0);
            #pragma unroll
            for (int e = 0; e < 8; ++e)
                VT[(d0+e)*VTP + tid] = (unsigned short)vv[e];
        }
    }
    __syncthreads();

    f16x8 qf[4][2];
    #pragma unroll
    for (int rb = 0; rb < 4; ++rb)
        #pragma unroll
        for (int dc = 0; dc < 2; ++dc)
            qf[rb][dc] = *(const f16x8*)(q + base + (size_t)(w*64 + rb*16 + lo)*HD + dc*32 + hi*8);

    f32x4 o[4][4];
    #pragma unroll
    for (int rb = 0; rb < 4; ++rb)
        #pragma unroll
        for (int cd = 0; cd < 4; ++cd) o[rb][cd] = (f32x4){0.f,0.f,0.f,0.f};
    float rs[4][4];
    #pragma unroll
    for (int rb = 0; rb < 4; ++rb)
        #pragma unroll
        for (int r = 0; r < 4; ++r) rs[rb][r] = 0.f;

    unsigned short* Pw = PL + w * 64 * PPW;

    for (int st = 0; st < 8; ++st) {
        const int s0 = st * 32;
        f16x8 kf[2][2];
        #pragma unroll
        for (int cb = 0; cb < 2; ++cb)
            #pragma unroll
            for (int dc = 0; dc < 2; ++dc)
                kf[cb][dc] = *(const f16x8*)(k + base + (size_t)(s0 + cb*16 + lo)*HD + dc*32 + hi*8);

        #pragma unroll
        for (int rb = 0; rb < 4; ++rb) {
            #pragma unroll
            for (int cb = 0; cb < 2; ++cb) {
                f32x4 acc = (f32x4){0.f,0.f,0.f,0.f};
                acc = __builtin_amdgcn_mfma_f32_16x16x32_f16(qf[rb][0], kf[cb][0], acc, 0, 0, 0);
                acc = __builtin_amdgcn_mfma_f32_16x16x32_f16(qf[rb][1], kf[cb][1], acc, 0, 0, 0);
                #pragma unroll
                for (int r = 0; r < 4; ++r) {
                    float p = __expf(acc[r] * 0.125f);
                    rs[rb][r] += p;
                    Pw[(rb*16 + hi*4 + r)*PPW + cb*16 + lo] = f2h(p);
                }
            }
        }

        f16x8 pa[4];
        #pragma unroll
        for (int rb = 0; rb < 4; ++rb)
            pa[rb] = *(const f16x8*)&Pw[(rb*16 + lo)*PPW + hi*8];
        f16x8 bv[4];
        #pragma unroll
        for (int cd = 0; cd < 4; ++cd)
            bv[cd] = *(const f16x8*)&VT[(cd*16 + lo)*VTP + s0 + hi*8];
        #pragma unroll
        for (int rb = 0; rb < 4; ++rb)
            #pragma unroll
            for (int cd = 0; cd < 4; ++cd)
                o[rb][cd] = __builtin_amdgcn_mfma_f32_16x16x32_f16(pa[rb], bv[cd], o[rb][cd], 0, 0, 0);
    }

    #pragma unroll
    for (int off = 1; off < 16; off <<= 1)
        #pragma unroll
        for (int rb = 0; rb < 4; ++rb)
            #pragma unroll
            for (int r = 0; r < 4; ++r)
                rs[rb][r] += __shfl_xor(rs[rb][r], off, 64);

    const float gate = 1.f / (1.f + __expf(-fg[0]));
    const float wt = 1.f - gate;
    #pragma unroll
    for (int rb = 0; rb < 4; ++rb) {
        #pragma unroll
        for (int r = 0; r < 4; ++r) {
            const int t = w*64 + rb*16 + hi*4 + r;
            const float sc = wt / rs[rb][r];
            unsigned short* yp = y + (((size_t)b*TT + t)*JJ + j)*CC + h*HD;
            #pragma unroll
            for (int cd = 0; cd < 4; ++cd)
                yp[cd*16 + lo] = f2h(o[rb][cd][r] * sc);
        }
    }
}

// ---------------- F1: DFT MFMA GEMM, f16 in -> f16 freq out in place --------
#define XP 280

__global__ __launch_bounds__(256) void dft_k(
    unsigned short* __restrict__ planes, const unsigned short* __restrict__ Whi,
    const unsigned short* __restrict__ Wlo)
{
    __shared__ unsigned short Xh[64*XP];
    unsigned short* src = planes + (size_t)blockIdx.y*NQKV + (size_t)blockIdx.x*QTILE;
    const int tid = threadIdx.x;
    const int w = tid >> 6;
    const int lane = tid & 63;
    const int qd = (tid >> 4) & 3;
    const int rr = tid & 15;
    const int lo = lane & 15, hi = lane >> 4;

    #pragma unroll
    for (int p = 0; p < 16; ++p) {
        const int t = p*16 + 4*w + qd;
        ushort4 x4 = *(const ushort4*)&src[t*64 + 4*rr];
        unsigned int a0 = x4.x, a1 = x4.y, a2 = x4.z, a3 = x4.w;
        unsigned int t01 = (unsigned)__shfl_xor((int)((qd&1) ? a0 : a1), 16, 64);
        unsigned int t23 = (unsigned)__shfl_xor((int)((qd&1) ? a2 : a3), 16, 64);
        if (qd&1) { a0 = t01; a2 = t23; } else { a1 = t01; a3 = t23; }
        unsigned int u01 = (unsigned)__shfl_xor((int)((qd&2) ? a0 : a2), 32, 64);
        unsigned int u23 = (unsigned)__shfl_xor((int)((qd&2) ? a1 : a3), 32, 64);
        if (qd&2) { a0 = u01; a1 = u23; } else { a2 = u01; a3 = u23; }
        const int dd = 4*rr + qd;
        const int tb = p*16 + 4*w;
        ushort4 hv;
        hv.x = (unsigned short)a0; hv.y = (unsigned short)a1;
        hv.z = (unsigned short)a2; hv.w = (unsigned short)a3;
        *(ushort4*)&Xh[dd*XP + tb] = hv;
    }
    __syncthreads();

    f32x4 acc[2][4];
    #pragma unroll
    for (int rb = 0; rb < 2; ++rb)
        #pragma unroll
        for (int cd = 0; cd < 4; ++cd) acc[rb][cd] = (f32x4){0.f,0.f,0.f,0.f};

    for (int ks = 0; ks < 8; ++ks) {
        const int k0 = ks*32;
        f16x8 ah[2], al[2];
        #pragma unroll
        for (int rb = 0; rb < 2; ++rb) {
            int r = w*32 + rb*16 + lo;
            ah[rb] = *(const f16x8*)&Whi[r*256 + k0 + hi*8];
            al[rb] = *(const f16x8*)&Wlo[r*256 + k0 + hi*8];
        }
        f16x8 bh[4];
        #pragma unroll
        for (int cd = 0; cd < 4; ++cd) {
            int d = cd*16 + lo;
            bh[cd] = *(const f16x8*)&Xh[d*XP + k0 + hi*8];
        }
        #pragma unroll
        for (int rb = 0; rb < 2; ++rb)
            #pragma unroll
            for (int cd = 0; cd < 4; ++cd) {
                acc[rb][cd] = __builtin_amdgcn_mfma_f32_16x16x32_f16(
                    ah[rb], bh[cd], acc[rb][cd], 0, 0, 0);
                acc[rb][cd] = __builtin_amdgcn_mfma_f32_16x16x32_f16(
                    al[rb], bh[cd], acc[rb][cd], 0, 0, 0);
            }
    }

    // f16 in-place: [re 64x64][im 64x64] over first 8192 u16 of the tile
    #pragma unroll
    for (int rb = 0; rb < 2; ++rb) {
        #pragma unroll
        for (int r = 0; r < 4; ++r) {
            int row = w*32 + rb*16 + hi*4 + r;
            unsigned short* dst = (row < 64) ? (src + row*64)
                                             : (src + 4096 + (row-64)*64);
            #pragma unroll
            for (int cd = 0; cd < 4; ++cd)
                dst[cd*16 + lo] = f2h(acc[rb][cd][r]);
        }
    }
}

// ---------------- F2: af = scale*qf kf^H, dual softmax, xf = af vf ----------
// f16 in ([re][im] 64x64 each), f32 LDS compute, f16 xf out over q tile.
__global__ __launch_bounds__(256) void afxf_k(
    unsigned short* __restrict__ qfp, const unsigned short* __restrict__ kfp,
    const unsigned short* __restrict__ vfp)
{
    extern __shared__ float lds[];
    float* A = lds;
    float* B = lds + 2*FHALF;

    const int tid = threadIdx.x;
    unsigned short* qf = qfp + (size_t)blockIdx.x * QTILE;
    const unsigned short* kf = kfp + (size_t)blockIdx.x * QTILE;
    const unsigned short* vf = vfp + (size_t)blockIdx.x * QTILE;

    // stage f16 -> f32 LDS (8192 elems each)
    #pragma unroll
    for (int p = 0; p < 4; ++p) {
        int idx = p*256 + tid;
        int e8 = idx*8;
        int part = e8 >> 12;
        int row = (e8 >> 6) & 63;
        int col = e8 & 63;
        i16x8 qv = *(const i16x8*)(qf + e8);
        i16x8 kv = *(const i16x8*)(kf + e8);
        float* ap = A + part*FHALF + row*FP + col;
        float* bp = B + part*FHALF + row*FP + col;
        #pragma unroll
        for (int e = 0; e < 8; ++e) {
            ap[e] = h2f((unsigned short)qv[e]);
            bp[e] = h2f((unsigned short)kv[e]);
        }
    }
    __syncthreads();

    const int fy = tid >> 4;
    const int gl = tid & 15;

    float cR[4][4], cI[4][4];
    #pragma unroll
    for (int i = 0; i < 4; ++i)
        #pragma unroll
        for (int gi = 0; gi < 4; ++gi) { cR[i][gi] = 0.f; cI[i][gi] = 0.f; }

    for (int d4 = 0; d4 < 16; ++d4) {
        float4 qr[4], qi[4], kr[4], ki[4];
        #pragma unroll
        for (int i = 0; i < 4; ++i) {
            int f = fy + 16*i;
            qr[i] = *(const float4*)(A + f*FP + d4*4);
            qi[i] = *(const float4*)(A + FHALF + f*FP + d4*4);
            int g = gl + 16*i;
            kr[i] = *(const float4*)(B + g*FP + d4*4);
            ki[i] = *(const float4*)(B + FHALF + g*FP + d4*4);
        }
        #pragma unroll
        for (int i = 0; i < 4; ++i)
            #pragma unroll
            for (int gi = 0; gi < 4; ++gi) {
                float r = cR[i][gi], m = cI[i][gi];
                r = fmaf(qr[i].x, kr[gi].x, r); r = fmaf(qi[i].x, ki[gi].x, r);
                r = fmaf(qr[i].y, kr[gi].y, r); r = fmaf(qi[i].y, ki[gi].y, r);
                r = fmaf(qr[i].z, kr[gi].z, r); r = fmaf(qi[i].z, ki[gi].z, r);
                r = fmaf(qr[i].w, kr[gi].w, r); r = fmaf(qi[i].w, ki[gi].w, r);
                m = fmaf(qi[i].x, kr[gi].x, m); m = fmaf(-qr[i].x, ki[gi].x, m);
                m = fmaf(qi[i].y, kr[gi].y, m); m = fmaf(-qr[i].y, ki[gi].y, m);
                m = fmaf(qi[i].z, kr[gi].z, m); m = fmaf(-qr[i].z, ki[gi].z, m);
                m = fmaf(qi[i].w, kr[gi].w, m); m = fmaf(-qr[i].w, ki[gi].w, m);
                cR[i][gi] = r; cI[i][gi] = m;
            }
    }
    __syncthreads();

    #pragma unroll
    for (int i = 0; i < 4; ++i)
        #pragma unroll
        for (int gi = 0; gi < 4; ++gi) {
            A[(fy + 16*i)*FP + gl + 16*gi]         = 0.125f * cR[i][gi];
            A[FHALF + (fy + 16*i)*FP + gl + 16*gi] = 0.125f * cI[i][gi];
        }
    #pragma unroll
    for (int p = 0; p < 4; ++p) {
        int idx = p*256 + tid;
        int e8 = idx*8;
        int part = e8 >> 12;
        int row = (e8 >> 6) & 63;
        int col = e8 & 63;
        i16x8 vv = *(const i16x8*)(vf + e8);
        float* bp = B + part*FHALF + row*FP + col;
        #pragma unroll
        for (int e = 0; e < 8; ++e) bp[e] = h2f((unsigned short)vv[e]);
    }
    __syncthreads();

    if (tid < 128) {
        float* row = A + (tid >> 6)*FHALF + (tid & 63)*FP;
        float mx = row[0];
        for (int g2 = 1; g2 < 64; ++g2) mx = fmaxf(mx, row[g2]);
        float sum = 0.f;
        for (int g2 = 0; g2 < 64; ++g2) { float e = __expf(row[g2]-mx); row[g2] = e; sum += e; }
        float inv = 1.f / sum;
        for (int g2 = 0; g2 < 64; ++g2) row[g2] *= inv;
    }
    __syncthreads();

    float xR[4][4], xI[4][4];
    #pragma unroll
    for (int i = 0; i < 4; ++i)
        #pragma unroll
        for (int cmp = 0; cmp < 4; ++cmp) { xR[i][cmp] = 0.f; xI[i][cmp] = 0.f; }

    for (int g2 = 0; g2 < 64; ++g2) {
        float4 vr = *(const float4*)(B + g2*FP + gl*4);
        float4 vi = *(const float4*)(B + FHALF + g2*FP + gl*4);
        #pragma unroll
        for (int i = 0; i < 4; ++i) {
            float sr = A[(fy + 16*i)*FP + g2];
            float si = A[FHALF + (fy + 16*i)*FP + g2];
            xR[i][0] = fmaf(sr, vr.x, fmaf(-si, vi.x, xR[i][0]));
            xI[i][0] = fmaf(sr, vi.x, fmaf( si, vr.x, xI[i][0]));
            xR[i][1] = fmaf(sr, vr.y, fmaf(-si, vi.y, xR[i][1]));
            xI[i][1] = fmaf(sr, vi.y, fmaf( si, vr.y, xI[i][1]));
            xR[i][2] = fmaf(sr, vr.z, fmaf(-si, vi.z, xR[i][2]));
            xI[i][2] = fmaf(sr, vi.z, fmaf( si, vr.z, xI[i][2]));
            xR[i][3] = fmaf(sr, vr.w, fmaf(-si, vi.w, xR[i][3]));
            xI[i][3] = fmaf(sr, vi.w, fmaf( si, vr.w, xI[i][3]));
        }
    }
    // write xf f16 over the qf tile: [re 64x64][im 64x64]
    #pragma unroll
    for (int i = 0; i < 4; ++i) {
        int f = fy + 16*i;
        ushort4 rv, iv;
        rv.x = f2h(xR[i][0]); rv.y = f2h(xR[i][1]);
        rv.z = f2h(xR[i][2]); rv.w = f2h(xR[i][3]);
        iv.x = f2h(xI[i][0]); iv.y = f2h(xI[i][1]);
        iv.z = f2h(xI[i][2]); iv.w = f2h(xI[i][3]);
        *(ushort4*)&qf[f*64 + gl*4]        = rv;
        *(ushort4*)&qf[4096 + f*64 + gl*4] = iv;
    }
}

// ---------------- F3: irfft as split-f16 MFMA GEMM + gated f16 RMW ----------
// C[256 t][64 d] = WI[256][128] @ XF^T; XF = [re 64x64][im 64x64] f16.
#define XFP 136

__global__ __launch_bounds__(256) void irfft_k(
    const unsigned short* __restrict__ xfp, const unsigned short* __restrict__ WIhi,
    const unsigned short* __restrict__ WIlo, const float* __restrict__ fg,
    unsigned short* __restrict__ y)
{
    __shared__ unsigned short XT[64*XFP];
    const int tile = blockIdx.x;
    const int b = tile / (HH*JJ);
    const int h = (tile / JJ) % HH;
    const int j = tile % JJ;
    const unsigned short* src = xfp + (size_t)tile * QTILE;   // [128][64] f16
    const int tid = threadIdx.x;
    const int w = tid >> 6;
    const int lane = tid & 63;
    const int qd = (tid >> 4) & 3;
    const int rr = tid & 15;
    const int lo = lane & 15, hi = lane >> 4;

    // stage XF transposed: XT[d][f], 128 rows -> 8 p-iters
    #pragma unroll
    for (int p = 0; p < 8; ++p) {
        const int fr = p*16 + 4*w + qd;
        ushort4 x4 = *(const ushort4*)&src[fr*64 + 4*rr];
        unsigned int a0 = x4.x, a1 = x4.y, a2 = x4.z, a3 = x4.w;
        unsigned int t01 = (unsigned)__shfl_xor((int)((qd&1) ? a0 : a1), 16, 64);
        unsigned int t23 = (unsigned)__shfl_xor((int)((qd&1) ? a2 : a3), 16, 64);
        if (qd&1) { a0 = t01; a2 = t23; } else { a1 = t01; a3 = t23; }
        unsigned int u01 = (unsigned)__shfl_xor((int)((qd&2) ? a0 : a2), 32, 64);
        unsigned int u23 = (unsigned)__shfl_xor((int)((qd&2) ? a1 : a3), 32, 64);
        if (qd&2) { a0 = u01; a1 = u23; } else { a2 = u01; a3 = u23; }
        const int dd = 4*rr + qd;
        const int fb = p*16 + 4*w;
        ushort4 hv;
        hv.x = (unsigned short)a0; hv.y = (unsigned short)a1;
        hv.z = (unsigned short)a2; hv.w = (unsigned short)a3;
        *(ushort4*)&XT[dd*XFP + fb] = hv;
    }
    __syncthreads();

    f32x4 acc[4][4];
    #pragma unroll
    for (int rb = 0; rb < 4; ++rb)
        #pragma unroll
        for (int cd = 0; cd < 4; ++cd) acc[rb][cd] = (f32x4){0.f,0.f,0.f,0.f};

    #pragma unroll
    for (int ks = 0; ks < 4; ++ks) {
        const int k0 = ks*32;
        f16x8 ah[4], al[4];
        #pragma unroll
        for (int rb = 0; rb < 4; ++rb) {
            int row = w*64 + rb*16 + lo;     // t
            ah[rb] = *(const f16x8*)&WIhi[row*128 + k0 + hi*8];
            al[rb] = *(const f16x8*)&WIlo[row*128 + k0 + hi*8];
        }
        f16x8 bt[4];
        #pragma unroll
        for (int cd = 0; cd < 4; ++cd) {
            int d = cd*16 + lo;
            bt[cd] = *(const f16x8*)&XT[d*XFP + k0 + hi*8];
        }
        #pragma unroll
        for (int rb = 0; rb < 4; ++rb)
            #pragma unroll
            for (int cd = 0; cd < 4; ++cd) {
                acc[rb][cd] = __builtin_amdgcn_mfma_f32_16x16x32_f16(
                    ah[rb], bt[cd], acc[rb][cd], 0, 0, 0);
                acc[rb][cd] = __builtin_amdgcn_mfma_f32_16x16x32_f16(
                    al[rb], bt[cd], acc[rb][cd], 0, 0, 0);
            }
    }

    const float gate = 1.f / (1.f + __expf(-fg[0]));
    #pragma unroll
    for (int rb = 0; rb < 4; ++rb) {
        #pragma unroll
        for (int r = 0; r < 4; ++r) {
            int t = w*64 + rb*16 + hi*4 + r;
            unsigned short* yp = y + (((size_t)b*TT + t)*JJ + j)*CC + h*HD;
            #pragma unroll
            for (int cd = 0; cd < 4; ++cd) {
                int d = cd*16 + lo;
                yp[d] = f2h(fmaf(gate, acc[rb][cd][r], h2f(yp[d])));
            }
        }
    }
}

// ---------------------------------------------------------------------------
// Workspace (f16 planes, 71.3MB each):
//  [0]: q f16 -> qf f16 in place -> xf f16     [1]: k f16 -> kf f16
//  [2]: v f16 -> vf f16                        [3]: x f16 (dead after gemm)
//  [4]: y f16 (attn write, irfft RMW, proj A)  [+]: wp f16
//  d_out: wq + W/WI twiddle staging (dead before proj writes)
extern "C" void kernel_launch(void* const* d_in, const int* in_sizes, int n_in,
                              void* d_out, int out_size, void* d_ws, size_t ws_size,
                              hipStream_t stream) {
    const float* x      = (const float*)d_in[0];
    const float* w_qkv  = (const float*)d_in[1];
    const float* w_proj = (const float*)d_in[2];
    const float* b_proj = (const float*)d_in[3];
    const float* fg     = (const float*)d_in[4];
    float* out = (float*)d_out;

    unsigned short* qp = (unsigned short*)d_ws;
    unsigned short* kp = qp + NQKV;
    unsigned short* vp = kp + NQKV;
    unsigned short* xh = vp + NQKV;
    unsigned short* y  = xh + NQKV;
    unsigned short* wph = y + NQKV;
    unsigned short* wqh = (unsigned short*)d_out;
    unsigned short* Whi  = wqh + 1536*512;   // 128*256
    unsigned short* Wlo  = Whi + 128*256;
    unsigned short* WIhi = Wlo + 128*256;    // 256*128
    unsigned short* WIlo = WIhi + 256*128;

    (void)hipFuncSetAttribute((const void*)afxf_k,
                              hipFuncAttributeMaxDynamicSharedMemorySize, 4*FHALF*4);

    conv16_k<<<2048, 256, 0, stream>>>(x, xh, NQKV/8);
    conv16_k<<<384, 256, 0, stream>>>(w_qkv, wqh, 1536*512/8);
    conv16_k<<<128, 256, 0, stream>>>(w_proj, wph, 512*512/8);
    winit_k<<<128, 256, 0, stream>>>(Whi, Wlo);
    winit2_k<<<256, 128, 0, stream>>>(WIhi, WIlo);

    gemm_qkv_k<<<6528, 256, 0, stream>>>(xh, wqh, qp, kp, vp);
    attn_time_k<<<NTILES, 256, 0, stream>>>(qp, kp, vp, fg, y);
    dft_k<<<dim3(NTILES, 3), 256, 0, stream>>>(qp, Whi, Wlo);
    afxf_k<<<NTILES, 256, 4*FHALF*4, stream>>>(qp, kp, vp);
    irfft_k<<<NTILES, 256, 0, stream>>>(qp, WIhi, WIlo, fg, y);

    gemm_proj_k<<<2176, 256, 0, stream>>>(y, wph, b_proj, out);
}

// Round 12
// 702.421 us; speedup vs baseline: 1.8217x; 1.0470x over previous
//
#include <hip/hip_runtime.h>
#include <hip/hip_fp16.h>
#include <math.h>

#define NB 16
#define TT 256
#define JJ 17
#define CC 512
#define HH 8
#define HD 64
#define MROWS (NB*TT*JJ)        // 69632
#define QTILE 16384             // u16 elems per (b,h,j) tile
#define NTILES (NB*HH*JJ)       // 2176
#define NQKV 35651584           // elements per plane (MROWS*512)

#define FP 68            // LDS pitch for 64-wide freq matrices (f32)
#define FHALF 4352       // 64*68
#define W0 0.0245436926061702596f   // 2*pi/256

typedef __attribute__((ext_vector_type(8))) short i16x8;
typedef __attribute__((ext_vector_type(8))) _Float16 f16x8;
typedef __attribute__((ext_vector_type(4))) float f32x4;

__device__ __forceinline__ unsigned short f2h(float f) {
    return (unsigned short)__half_as_ushort(__float2half(f));
}
__device__ __forceinline__ float h2f(unsigned short u) {
    return __half2float(__ushort_as_half(u));
}

#define GLD16(gp, lp) __builtin_amdgcn_global_load_lds( \
    (__attribute__((address_space(1))) void*)(gp), \
    (__attribute__((address_space(3))) void*)(lp), 16, 0, 0)

// ---------------- f32 -> f16 conversion (8-wide) ----------------------------
__global__ __launch_bounds__(256) void conv16_k(
    const float* __restrict__ s, unsigned short* __restrict__ d, int n8)
{
    for (int i = blockIdx.x*256 + threadIdx.x; i < n8; i += gridDim.x*256) {
        float4 a = ((const float4*)s)[i*2];
        float4 b = ((const float4*)s)[i*2+1];
        i16x8 h;
        h[0] = (short)f2h(a.x); h[1] = (short)f2h(a.y);
        h[2] = (short)f2h(a.z); h[3] = (short)f2h(a.w);
        h[4] = (short)f2h(b.x); h[5] = (short)f2h(b.y);
        h[6] = (short)f2h(b.z); h[7] = (short)f2h(b.w);
        ((i16x8*)d)[i] = h;
    }
}

// ---------------- forward twiddle W[128][256] (split f16): cos / -sin -------
__global__ __launch_bounds__(256) void winit_k(
    unsigned short* __restrict__ Whi, unsigned short* __restrict__ Wlo)
{
    const int r = blockIdx.x;
    const int t = threadIdx.x;
    int idx = ((r & 63) * t) & 255;
    float sv, cv;
    sincosf(W0 * (float)idx, &sv, &cv);
    float val = (r < 64) ? cv : -sv;
    unsigned short h = f2h(val);
    Whi[r*256 + t] = h;
    Wlo[r*256 + t] = f2h(val - h2f(h));
}

// ---------------- inverse twiddle WI[256][128] (f16) ------------------------
// WI[t][f<64] = cf*cos(2pi t f/256)*(2/256), cf=0.5 for f=0
// WI[t][64+f'] = -sin(2pi t f'/256)*(2/256)   (f'=0 col is 0: DC imag drops)
__global__ __launch_bounds__(128) void winit2_k(unsigned short* __restrict__ WIhi)
{
    const int t = blockIdx.x;       // 0..255
    const int f = threadIdx.x;      // 0..127
    int fr = f & 63;
    int idx = (t * fr) & 255;
    float sv, cv;
    sincosf(W0 * (float)idx, &sv, &cv);
    float cf = (fr == 0 && f < 64) ? 0.5f : 1.f;
    float val = ((f < 64) ? cv : -sv) * cf * (2.f / 256.f);
    WIhi[t*128 + f] = f2h(val);
}

// ---------------- GEMM 1 (f16 MFMA, BK=64): qkv = x @ w_qkv^T ---------------
// q plane is pre-scaled by 0.125 (folded softmax scale, inherited by qf too).
__global__ __launch_bounds__(256) void gemm_qkv_k(
    const unsigned short* __restrict__ A, const unsigned short* __restrict__ B,
    unsigned short* __restrict__ qp, unsigned short* __restrict__ kp,
    unsigned short* __restrict__ vp)
{
    __shared__ unsigned short Ah[128*64];
    __shared__ unsigned short Bh[128*64];
    const int tid = threadIdx.x;
    const int lane = tid & 63;
    const int lo = lane & 15, hi = lane >> 4;
    const int wv = tid >> 6;
    const int wr = wv >> 1, wc = wv & 1;
    const int bid = blockIdx.x;
    const int wrk = (bid & 7) * 816 + (bid >> 3);   // 6528 = 8*816, bijective
    const int col0 = (wrk % 12) * 128;
    const int row0 = (wrk / 12) * 128;

    f32x4 acc[4][4];
    #pragma unroll
    for (int rb = 0; rb < 4; ++rb)
        #pragma unroll
        for (int cb = 0; cb < 4; ++cb) acc[rb][cb] = (f32x4){0.f,0.f,0.f,0.f};

    for (int k0 = 0; k0 < 512; k0 += 64) {
        #pragma unroll
        for (int c = 0; c < 4; ++c) {
            int e = c*2048 + tid*8;
            int r = e >> 6, cc = e & 63;
            int ccs = cc ^ ((r & 7) << 3);
            size_t offA = (size_t)(row0 + r)*512 + k0 + ccs;
            size_t offB = (size_t)(col0 + r)*512 + k0 + ccs;
            GLD16(A + offA, (char*)Ah + c*4096 + tid*16);
            GLD16(B + offB, (char*)Bh + c*4096 + tid*16);
        }
        __syncthreads();
        #pragma unroll
        for (int ks = 0; ks < 2; ++ks) {
            f16x8 af[4], bf[4];
            #pragma unroll
            for (int rb = 0; rb < 4; ++rb) {
                int row = wr*64 + rb*16 + lo;
                int col = (ks*32 + hi*8) ^ ((row & 7) << 3);
                af[rb] = *(const f16x8*)&Ah[row*64 + col];
            }
            #pragma unroll
            for (int cb = 0; cb < 4; ++cb) {
                int row = wc*64 + cb*16 + lo;
                int col = (ks*32 + hi*8) ^ ((row & 7) << 3);
                bf[cb] = *(const f16x8*)&Bh[row*64 + col];
            }
            #pragma unroll
            for (int rb = 0; rb < 4; ++rb)
                #pragma unroll
                for (int cb = 0; cb < 4; ++cb)
                    acc[rb][cb] = __builtin_amdgcn_mfma_f32_16x16x32_f16(
                        af[rb], bf[cb], acc[rb][cb], 0, 0, 0);
        }
        __syncthreads();
    }

    // hoisted m -> (bb, t, j) decomposition (independent of cb)
    int bbA[4][4], ttA[4][4], jjA[4][4];
    #pragma unroll
    for (int rb = 0; rb < 4; ++rb)
        #pragma unroll
        for (int r = 0; r < 4; ++r) {
            int m = row0 + wr*64 + rb*16 + hi*4 + r;
            int bb = m / (TT*JJ);
            int rem = m - bb*(TT*JJ);
            int t = rem / JJ;
            bbA[rb][r] = bb; ttA[rb][r] = t; jjA[rb][r] = rem - t*JJ;
        }

    #pragma unroll
    for (int cb = 0; cb < 4; ++cb) {
        int n0 = col0 + wc*64 + cb*16;
        int g = n0 >> 9;
        unsigned short* dst0 = (g == 0) ? qp : (g == 1) ? kp : vp;
        float scl = (g == 0) ? 0.125f : 1.f;
        int h = (n0 >> 6) & 7;
        int d = (n0 & 63) + lo;
        #pragma unroll
        for (int rb = 0; rb < 4; ++rb)
            #pragma unroll
            for (int r = 0; r < 4; ++r) {
                size_t off = ((((size_t)bbA[rb][r]*HH + h)*JJ + jjA[rb][r])*TT
                              + ttA[rb][r])*HD + d;
                dst0[off] = f2h(acc[rb][cb][r] * scl);
            }
    }
}

// ---------------- GEMM 2 (f16 MFMA, BK=64): out = y @ w_proj^T + b ----------
__global__ __launch_bounds__(256) void gemm_proj_k(
    const unsigned short* __restrict__ A, const unsigned short* __restrict__ B,
    const float* __restrict__ bias, float* __restrict__ out)
{
    __shared__ unsigned short Ah[128*64];
    __shared__ unsigned short Bh[128*64];
    const int tid = threadIdx.x;
    const int lane = tid & 63;
    const int lo = lane & 15, hi = lane >> 4;
    const int wv = tid >> 6;
    const int wr = wv >> 1, wc = wv & 1;
    const int bid = blockIdx.x;
    const int wrk = (bid & 7) * 272 + (bid >> 3);   // 2176 = 8*272, bijective
    const int col0 = (wrk % 4) * 128;
    const int row0 = (wrk / 4) * 128;

    f32x4 acc[4][4];
    #pragma unroll
    for (int rb = 0; rb < 4; ++rb)
        #pragma unroll
        for (int cb = 0; cb < 4; ++cb) acc[rb][cb] = (f32x4){0.f,0.f,0.f,0.f};

    for (int k0 = 0; k0 < 512; k0 += 64) {
        #pragma unroll
        for (int c = 0; c < 4; ++c) {
            int e = c*2048 + tid*8;
            int r = e >> 6, cc = e & 63;
            int ccs = cc ^ ((r & 7) << 3);
            size_t offA = (size_t)(row0 + r)*512 + k0 + ccs;
            size_t offB = (size_t)(col0 + r)*512 + k0 + ccs;
            GLD16(A + offA, (char*)Ah + c*4096 + tid*16);
            GLD16(B + offB, (char*)Bh + c*4096 + tid*16);
        }
        __syncthreads();
        #pragma unroll
        for (int ks = 0; ks < 2; ++ks) {
            f16x8 af[4], bf[4];
            #pragma unroll
            for (int rb = 0; rb < 4; ++rb) {
                int row = wr*64 + rb*16 + lo;
                int col = (ks*32 + hi*8) ^ ((row & 7) << 3);
                af[rb] = *(const f16x8*)&Ah[row*64 + col];
            }
            #pragma unroll
            for (int cb = 0; cb < 4; ++cb) {
                int row = wc*64 + cb*16 + lo;
                int col = (ks*32 + hi*8) ^ ((row & 7) << 3);
                bf[cb] = *(const f16x8*)&Bh[row*64 + col];
            }
            #pragma unroll
            for (int rb = 0; rb < 4; ++rb)
                #pragma unroll
                for (int cb = 0; cb < 4; ++cb)
                    acc[rb][cb] = __builtin_amdgcn_mfma_f32_16x16x32_f16(
                        af[rb], bf[cb], acc[rb][cb], 0, 0, 0);
        }
        __syncthreads();
    }

    #pragma unroll
    for (int cb = 0; cb < 4; ++cb) {
        int n = col0 + wc*64 + cb*16 + lo;
        float bv = bias[n];
        #pragma unroll
        for (int rb = 0; rb < 4; ++rb)
            #pragma unroll
            for (int r = 0; r < 4; ++r) {
                int m = row0 + wr*64 + rb*16 + hi*4 + r;
                out[(size_t)m*512 + n] = acc[rb][cb][r] + bv;
            }
    }
}

// ---------------- time attention via f16 MFMA (q pre-scaled) ----------------
#define VTP 264
#define PPW 40

__global__ __launch_bounds__(256, 2) void attn_time_k(
    const unsigned short* __restrict__ q, const unsigned short* __restrict__ k,
    const unsigned short* __restrict__ v, const float* __restrict__ fg,
    unsigned short* __restrict__ y)
{
    __shared__ unsigned short VT[64 * VTP];
    __shared__ unsigned short PL[4 * 64 * PPW];

    const int bid = blockIdx.x;
    const int b = bid / (HH*JJ);
    const int h = (bid / JJ) % HH;
    const int j = bid % JJ;
    const size_t base = (size_t)bid * QTILE;

    const int tid = threadIdx.x;
    const int w = tid >> 6;
    const int lane = tid & 63;
    const int lo = lane & 15;
    const int hi = lane >> 4;

    {
        const unsigned short* vptr = v + base + (size_t)tid * HD;
        #pragma unroll
        for (int d0 = 0; d0 < 64; d0 += 8) {
            i16x8 vv = *(const i16x8*)(vptr + d0);
            #pragma unroll
            for (int e = 0; e < 8; ++e)
                VT[(d0+e)*VTP + tid] = (unsigned short)vv[e];
        }
    }
    __syncthreads();

    f16x8 qf[4][2];
    #pragma unroll
    for (int rb = 0; rb < 4; ++rb)
        #pragma unroll
        for (int dc = 0; dc < 2; ++dc)
            qf[rb][dc] = *(const f16x8*)(q + base + (size_t)(w*64 + rb*16 + lo)*HD + dc*32 + hi*8);

    f32x4 o[4][4];
    #pragma unroll
    for (int rb = 0; rb < 4; ++rb)
        #pragma unroll
        for (int cd = 0; cd < 4; ++cd) o[rb][cd] = (f32x4){0.f,0.f,0.f,0.f};
    float rs[4][4];
    #pragma unroll
    for (int rb = 0; rb < 4; ++rb)
        #pragma unroll
        for (int r = 0; r < 4; ++r) rs[rb][r] = 0.f;

    unsigned short* Pw = PL + w * 64 * PPW;

    for (int st = 0; st < 8; ++st) {
        const int s0 = st * 32;
        f16x8 kf[2][2];
        #pragma unroll
        for (int cb = 0; cb < 2; ++cb)
            #pragma unroll
            for (int dc = 0; dc < 2; ++dc)
                kf[cb][dc] = *(const f16x8*)(k + base + (size_t)(s0 + cb*16 + lo)*HD + dc*32 + hi*8);

        #pragma unroll
        for (int rb = 0; rb < 4; ++rb) {
            #pragma unroll
            for (int cb = 0; cb < 2; ++cb) {
                f32x4 acc = (f32x4){0.f,0.f,0.f,0.f};
                acc = __builtin_amdgcn_mfma_f32_16x16x32_f16(qf[rb][0], kf[cb][0], acc, 0, 0, 0);
                acc = __builtin_amdgcn_mfma_f32_16x16x32_f16(qf[rb][1], kf[cb][1], acc, 0, 0, 0);
                #pragma unroll
                for (int r = 0; r < 4; ++r) {
                    float p = __expf(acc[r]);     // scale folded into q
                    rs[rb][r] += p;
                    Pw[(rb*16 + hi*4 + r)*PPW + cb*16 + lo] = f2h(p);
                }
            }
        }

        f16x8 pa[4];
        #pragma unroll
        for (int rb = 0; rb < 4; ++rb)
            pa[rb] = *(const f16x8*)&Pw[(rb*16 + lo)*PPW + hi*8];
        f16x8 bv[4];
        #pragma unroll
        for (int cd = 0; cd < 4; ++cd)
            bv[cd] = *(const f16x8*)&VT[(cd*16 + lo)*VTP + s0 + hi*8];
        #pragma unroll
        for (int rb = 0; rb < 4; ++rb)
            #pragma unroll
            for (int cd = 0; cd < 4; ++cd)
                o[rb][cd] = __builtin_amdgcn_mfma_f32_16x16x32_f16(pa[rb], bv[cd], o[rb][cd], 0, 0, 0);
    }

    #pragma unroll
    for (int off = 1; off < 16; off <<= 1)
        #pragma unroll
        for (int rb = 0; rb < 4; ++rb)
            #pragma unroll
            for (int r = 0; r < 4; ++r)
                rs[rb][r] += __shfl_xor(rs[rb][r], off, 64);

    const float gate = 1.f / (1.f + __expf(-fg[0]));
    const float wt = 1.f - gate;
    #pragma unroll
    for (int rb = 0; rb < 4; ++rb) {
        #pragma unroll
        for (int r = 0; r < 4; ++r) {
            const int t = w*64 + rb*16 + hi*4 + r;
            const float sc = wt / rs[rb][r];
            unsigned short* yp = y + (((size_t)b*TT + t)*JJ + j)*CC + h*HD;
            #pragma unroll
            for (int cd = 0; cd < 4; ++cd)
                yp[cd*16 + lo] = f2h(o[rb][cd][r] * sc);
        }
    }
}

// ---------------- F1: DFT MFMA GEMM, f16 in -> f16 freq out in place --------
#define XP 280

__global__ __launch_bounds__(256) void dft_k(
    unsigned short* __restrict__ planes, const unsigned short* __restrict__ Whi,
    const unsigned short* __restrict__ Wlo)
{
    __shared__ unsigned short Xh[64*XP];
    unsigned short* src = planes + (size_t)blockIdx.y*NQKV + (size_t)blockIdx.x*QTILE;
    const int tid = threadIdx.x;
    const int w = tid >> 6;
    const int lane = tid & 63;
    const int qd = (tid >> 4) & 3;
    const int rr = tid & 15;
    const int lo = lane & 15, hi = lane >> 4;

    #pragma unroll
    for (int p = 0; p < 16; ++p) {
        const int t = p*16 + 4*w + qd;
        ushort4 x4 = *(const ushort4*)&src[t*64 + 4*rr];
        unsigned int a0 = x4.x, a1 = x4.y, a2 = x4.z, a3 = x4.w;
        unsigned int t01 = (unsigned)__shfl_xor((int)((qd&1) ? a0 : a1), 16, 64);
        unsigned int t23 = (unsigned)__shfl_xor((int)((qd&1) ? a2 : a3), 16, 64);
        if (qd&1) { a0 = t01; a2 = t23; } else { a1 = t01; a3 = t23; }
        unsigned int u01 = (unsigned)__shfl_xor((int)((qd&2) ? a0 : a2), 32, 64);
        unsigned int u23 = (unsigned)__shfl_xor((int)((qd&2) ? a1 : a3), 32, 64);
        if (qd&2) { a0 = u01; a1 = u23; } else { a2 = u01; a3 = u23; }
        const int dd = 4*rr + qd;
        const int tb = p*16 + 4*w;
        ushort4 hv;
        hv.x = (unsigned short)a0; hv.y = (unsigned short)a1;
        hv.z = (unsigned short)a2; hv.w = (unsigned short)a3;
        *(ushort4*)&Xh[dd*XP + tb] = hv;
    }
    __syncthreads();

    f32x4 acc[2][4];
    #pragma unroll
    for (int rb = 0; rb < 2; ++rb)
        #pragma unroll
        for (int cd = 0; cd < 4; ++cd) acc[rb][cd] = (f32x4){0.f,0.f,0.f,0.f};

    for (int ks = 0; ks < 8; ++ks) {
        const int k0 = ks*32;
        f16x8 ah[2], al[2];
        #pragma unroll
        for (int rb = 0; rb < 2; ++rb) {
            int r = w*32 + rb*16 + lo;
            ah[rb] = *(const f16x8*)&Whi[r*256 + k0 + hi*8];
            al[rb] = *(const f16x8*)&Wlo[r*256 + k0 + hi*8];
        }
        f16x8 bh[4];
        #pragma unroll
        for (int cd = 0; cd < 4; ++cd) {
            int d = cd*16 + lo;
            bh[cd] = *(const f16x8*)&Xh[d*XP + k0 + hi*8];
        }
        #pragma unroll
        for (int rb = 0; rb < 2; ++rb)
            #pragma unroll
            for (int cd = 0; cd < 4; ++cd) {
                acc[rb][cd] = __builtin_amdgcn_mfma_f32_16x16x32_f16(
                    ah[rb], bh[cd], acc[rb][cd], 0, 0, 0);
                acc[rb][cd] = __builtin_amdgcn_mfma_f32_16x16x32_f16(
                    al[rb], bh[cd], acc[rb][cd], 0, 0, 0);
            }
    }

    // f16 in-place: [re 64x64][im 64x64] over first 8192 u16 of the tile
    #pragma unroll
    for (int rb = 0; rb < 2; ++rb) {
        #pragma unroll
        for (int r = 0; r < 4; ++r) {
            int row = w*32 + rb*16 + hi*4 + r;
            unsigned short* dst = (row < 64) ? (src + row*64)
                                             : (src + 4096 + (row-64)*64);
            #pragma unroll
            for (int cd = 0; cd < 4; ++cd)
                dst[cd*16 + lo] = f2h(acc[rb][cd][r]);
        }
    }
}

// ---------------- F2+F3 fused: af -> dual softmax -> xf -> irfft -> y -------
// qf pre-scaled by 0.125 (folded). xf never leaves the block: written as
// transposed f16 XT into LDS (aliased over the dead vf region), then the
// irfft MFMA tail (single-product WI) RMWs y.
#define XFP 136

__global__ __launch_bounds__(256) void freqtail_k(
    unsigned short* __restrict__ qfp, const unsigned short* __restrict__ kfp,
    const unsigned short* __restrict__ vfp, const unsigned short* __restrict__ WIhi,
    const float* __restrict__ fg, unsigned short* __restrict__ y)
{
    extern __shared__ float lds[];
    float* A = lds;
    float* B = lds + 2*FHALF;

    const int tid = threadIdx.x;
    const int tile = blockIdx.x;
    const int b = tile / (HH*JJ);
    const int h = (tile / JJ) % HH;
    const int j = tile % JJ;
    const unsigned short* qf = qfp + (size_t)tile * QTILE;
    const unsigned short* kf = kfp + (size_t)tile * QTILE;
    const unsigned short* vf = vfp + (size_t)tile * QTILE;

    // stage qf/kf f16 -> f32 LDS
    #pragma unroll
    for (int p = 0; p < 4; ++p) {
        int idx = p*256 + tid;
        int e8 = idx*8;
        int part = e8 >> 12;
        int row = (e8 >> 6) & 63;
        int col = e8 & 63;
        i16x8 qv = *(const i16x8*)(qf + e8);
        i16x8 kv = *(const i16x8*)(kf + e8);
        float* ap = A + part*FHALF + row*FP + col;
        float* bp = B + part*FHALF + row*FP + col;
        #pragma unroll
        for (int e = 0; e < 8; ++e) {
            ap[e] = h2f((unsigned short)qv[e]);
            bp[e] = h2f((unsigned short)kv[e]);
        }
    }
    __syncthreads();

    const int fy = tid >> 4;
    const int gl = tid & 15;

    float cR[4][4], cI[4][4];
    #pragma unroll
    for (int i = 0; i < 4; ++i)
        #pragma unroll
        for (int gi = 0; gi < 4; ++gi) { cR[i][gi] = 0.f; cI[i][gi] = 0.f; }

    for (int d4 = 0; d4 < 16; ++d4) {
        float4 qr[4], qi[4], kr[4], ki[4];
        #pragma unroll
        for (int i = 0; i < 4; ++i) {
            int f = fy + 16*i;
            qr[i] = *(const float4*)(A + f*FP + d4*4);
            qi[i] = *(const float4*)(A + FHALF + f*FP + d4*4);
            int g = gl + 16*i;
            kr[i] = *(const float4*)(B + g*FP + d4*4);
            ki[i] = *(const float4*)(B + FHALF + g*FP + d4*4);
        }
        #pragma unroll
        for (int i = 0; i < 4; ++i)
            #pragma unroll
            for (int gi = 0; gi < 4; ++gi) {
                float r = cR[i][gi], m = cI[i][gi];
                r = fmaf(qr[i].x, kr[gi].x, r); r = fmaf(qi[i].x, ki[gi].x, r);
                r = fmaf(qr[i].y, kr[gi].y, r); r = fmaf(qi[i].y, ki[gi].y, r);
                r = fmaf(qr[i].z, kr[gi].z, r); r = fmaf(qi[i].z, ki[gi].z, r);
                r = fmaf(qr[i].w, kr[gi].w, r); r = fmaf(qi[i].w, ki[gi].w, r);
                m = fmaf(qi[i].x, kr[gi].x, m); m = fmaf(-qr[i].x, ki[gi].x, m);
                m = fmaf(qi[i].y, kr[gi].y, m); m = fmaf(-qr[i].y, ki[gi].y, m);
                m = fmaf(qi[i].z, kr[gi].z, m); m = fmaf(-qr[i].z, ki[gi].z, m);
                m = fmaf(qi[i].w, kr[gi].w, m); m = fmaf(-qr[i].w, ki[gi].w, m);
                cR[i][gi] = r; cI[i][gi] = m;
            }
    }
    __syncthreads();

    // af -> A (scale already folded into qf); vf -> B
    #pragma unroll
    for (int i = 0; i < 4; ++i)
        #pragma unroll
        for (int gi = 0; gi < 4; ++gi) {
            A[(fy + 16*i)*FP + gl + 16*gi]         = cR[i][gi];
            A[FHALF + (fy + 16*i)*FP + gl + 16*gi] = cI[i][gi];
        }
    #pragma unroll
    for (int p = 0; p < 4; ++p) {
        int idx = p*256 + tid;
        int e8 = idx*8;
        int part = e8 >> 12;
        int row = (e8 >> 6) & 63;
        int col = e8 & 63;
        i16x8 vv = *(const i16x8*)(vf + e8);
        float* bp = B + part*FHALF + row*FP + col;
        #pragma unroll
        for (int e = 0; e < 8; ++e) bp[e] = h2f((unsigned short)vv[e]);
    }
    __syncthreads();

    if (tid < 128) {
        float* row = A + (tid >> 6)*FHALF + (tid & 63)*FP;
        float mx = row[0];
        for (int g2 = 1; g2 < 64; ++g2) mx = fmaxf(mx, row[g2]);
        float sum = 0.f;
        for (int g2 = 0; g2 < 64; ++g2) { float e = __expf(row[g2]-mx); row[g2] = e; sum += e; }
        float inv = 1.f / sum;
        for (int g2 = 0; g2 < 64; ++g2) row[g2] *= inv;
    }
    __syncthreads();

    float xR[4][4], xI[4][4];
    #pragma unroll
    for (int i = 0; i < 4; ++i)
        #pragma unroll
        for (int cmp = 0; cmp < 4; ++cmp) { xR[i][cmp] = 0.f; xI[i][cmp] = 0.f; }

    for (int g2 = 0; g2 < 64; ++g2) {
        float4 vr = *(const float4*)(B + g2*FP + gl*4);
        float4 vi = *(const float4*)(B + FHALF + g2*FP + gl*4);
        #pragma unroll
        for (int i = 0; i < 4; ++i) {
            float sr = A[(fy + 16*i)*FP + g2];
            float si = A[FHALF + (fy + 16*i)*FP + g2];
            xR[i][0] = fmaf(sr, vr.x, fmaf(-si, vi.x, xR[i][0]));
            xI[i][0] = fmaf(sr, vi.x, fmaf( si, vr.x, xI[i][0]));
            xR[i][1] = fmaf(sr, vr.y, fmaf(-si, vi.y, xR[i][1]));
            xI[i][1] = fmaf(sr, vi.y, fmaf( si, vr.y, xI[i][1]));
            xR[i][2] = fmaf(sr, vr.z, fmaf(-si, vi.z, xR[i][2]));
            xI[i][2] = fmaf(sr, vi.z, fmaf( si, vr.z, xI[i][2]));
            xR[i][3] = fmaf(sr, vr.w, fmaf(-si, vi.w, xR[i][3]));
            xI[i][3] = fmaf(sr, vi.w, fmaf( si, vr.w, xI[i][3]));
        }
    }
    __syncthreads();   // all vf reads done -> safe to overwrite B with XT

    // write xf transposed f16 into XT (aliased over B): XT[d][f | 64+f]
    unsigned short* XT = (unsigned short*)B;
    #pragma unroll
    for (int i = 0; i < 4; ++i) {
        int f = fy + 16*i;
        #pragma unroll
        for (int e = 0; e < 4; ++e) {
            XT[(gl*4+e)*XFP + f]      = f2h(xR[i][e]);
            XT[(gl*4+e)*XFP + 64 + f] = f2h(xI[i][e]);
        }
    }
    __syncthreads();

    // irfft MFMA tail: C[256 t][64 d] = WI[256][128] @ XT^T
    const int w = tid >> 6;
    const int lane = tid & 63;
    const int lo = lane & 15, hi = lane >> 4;

    f32x4 acc[4][4];
    #pragma unroll
    for (int rb = 0; rb < 4; ++rb)
        #pragma unroll
        for (int cd = 0; cd < 4; ++cd) acc[rb][cd] = (f32x4){0.f,0.f,0.f,0.f};

    #pragma unroll
    for (int ks = 0; ks < 4; ++ks) {
        const int k0 = ks*32;
        f16x8 ah[4];
        #pragma unroll
        for (int rb = 0; rb < 4; ++rb) {
            int row = w*64 + rb*16 + lo;     // t
            ah[rb] = *(const f16x8*)&WIhi[row*128 + k0 + hi*8];
        }
        f16x8 bt[4];
        #pragma unroll
        for (int cd = 0; cd < 4; ++cd) {
            int d = cd*16 + lo;
            bt[cd] = *(const f16x8*)&XT[d*XFP + k0 + hi*8];
        }
        #pragma unroll
        for (int rb = 0; rb < 4; ++rb)
            #pragma unroll
            for (int cd = 0; cd < 4; ++cd)
                acc[rb][cd] = __builtin_amdgcn_mfma_f32_16x16x32_f16(
                    ah[rb], bt[cd], acc[rb][cd], 0, 0, 0);
    }

    const float gate = 1.f / (1.f + __expf(-fg[0]));
    #pragma unroll
    for (int rb = 0; rb < 4; ++rb) {
        #pragma unroll
        for (int r = 0; r < 4; ++r) {
            int t = w*64 + rb*16 + hi*4 + r;
            unsigned short* yp = y + (((size_t)b*TT + t)*JJ + j)*CC + h*HD;
            #pragma unroll
            for (int cd = 0; cd < 4; ++cd) {
                int d = cd*16 + lo;
                yp[d] = f2h(fmaf(gate, acc[rb][cd][r], h2f(yp[d])));
            }
        }
    }
}

// ---------------------------------------------------------------------------
// Workspace (f16 planes, 71.3MB each):
//  [0]: q f16 (x0.125) -> qf f16 in place     [1]: k f16 -> kf f16
//  [2]: v f16 -> vf f16                       [3]: x f16 (dead after gemm)
//  [4]: y f16 (attn write, freqtail RMW, proj A)  [+]: wp f16
//  d_out: wq + W/WI twiddle staging (dead before proj writes)
extern "C" void kernel_launch(void* const* d_in, const int* in_sizes, int n_in,
                              void* d_out, int out_size, void* d_ws, size_t ws_size,
                              hipStream_t stream) {
    const float* x      = (const float*)d_in[0];
    const float* w_qkv  = (const float*)d_in[1];
    const float* w_proj = (const float*)d_in[2];
    const float* b_proj = (const float*)d_in[3];
    const float* fg     = (const float*)d_in[4];
    float* out = (float*)d_out;

    unsigned short* qp = (unsigned short*)d_ws;
    unsigned short* kp = qp + NQKV;
    unsigned short* vp = kp + NQKV;
    unsigned short* xh = vp + NQKV;
    unsigned short* y  = xh + NQKV;
    unsigned short* wph = y + NQKV;
    unsigned short* wqh = (unsigned short*)d_out;
    unsigned short* Whi  = wqh + 1536*512;   // 128*256
    unsigned short* Wlo  = Whi + 128*256;
    unsigned short* WIhi = Wlo + 128*256;    // 256*128
    unsigned short* Wend = WIhi + 256*128;
    (void)Wend;

    (void)hipFuncSetAttribute((const void*)freqtail_k,
                              hipFuncAttributeMaxDynamicSharedMemorySize, 4*FHALF*4);

    conv16_k<<<2048, 256, 0, stream>>>(x, xh, NQKV/8);
    conv16_k<<<384, 256, 0, stream>>>(w_qkv, wqh, 1536*512/8);
    conv16_k<<<128, 256, 0, stream>>>(w_proj, wph, 512*512/8);
    winit_k<<<128, 256, 0, stream>>>(Whi, Wlo);
    winit2_k<<<256, 128, 0, stream>>>(WIhi);

    gemm_qkv_k<<<6528, 256, 0, stream>>>(xh, wqh, qp, kp, vp);
    attn_time_k<<<NTILES, 256, 0, stream>>>(qp, kp, vp, fg, y);
    dft_k<<<dim3(NTILES, 3), 256, 0, stream>>>(qp, Whi, Wlo);
    freqtail_k<<<NTILES, 256, 4*FHALF*4, stream>>>(qp, kp, vp, WIhi, fg, y);

    gemm_proj_k<<<2176, 256, 0, stream>>>(y, wph, b_proj, out);
}

// Round 13
// 687.956 us; speedup vs baseline: 1.8601x; 1.0210x over previous
//
#include <hip/hip_runtime.h>
#include <hip/hip_fp16.h>
#include <math.h>

#define NB 16
#define TT 256
#define JJ 17
#define CC 512
#define HH 8
#define HD 64
#define MROWS (NB*TT*JJ)        // 69632
#define QTILE 16384             // u16 elems per (b,h,j) tile
#define NTILES (NB*HH*JJ)       // 2176
#define NQKV 35651584           // elements per plane (MROWS*512)

#define FP 68            // LDS pitch for 64-wide freq matrices (f32)
#define FHALF 4352       // 64*68
#define W0 0.0245436926061702596f   // 2*pi/256

typedef __attribute__((ext_vector_type(8))) short i16x8;
typedef __attribute__((ext_vector_type(8))) _Float16 f16x8;
typedef __attribute__((ext_vector_type(4))) float f32x4;

__device__ __forceinline__ unsigned short f2h(float f) {
    return (unsigned short)__half_as_ushort(__float2half(f));
}
__device__ __forceinline__ float h2f(unsigned short u) {
    return __half2float(__ushort_as_half(u));
}

#define GLD16(gp, lp) __builtin_amdgcn_global_load_lds( \
    (__attribute__((address_space(1))) void*)(gp), \
    (__attribute__((address_space(3))) void*)(lp), 16, 0, 0)

// ---------------- f32 -> f16 conversion (8-wide) ----------------------------
__global__ __launch_bounds__(256) void conv16_k(
    const float* __restrict__ s, unsigned short* __restrict__ d, int n8)
{
    for (int i = blockIdx.x*256 + threadIdx.x; i < n8; i += gridDim.x*256) {
        float4 a = ((const float4*)s)[i*2];
        float4 b = ((const float4*)s)[i*2+1];
        i16x8 h;
        h[0] = (short)f2h(a.x); h[1] = (short)f2h(a.y);
        h[2] = (short)f2h(a.z); h[3] = (short)f2h(a.w);
        h[4] = (short)f2h(b.x); h[5] = (short)f2h(b.y);
        h[6] = (short)f2h(b.z); h[7] = (short)f2h(b.w);
        ((i16x8*)d)[i] = h;
    }
}

// ---------------- fused prep: wq/wp conv + W + WI twiddle init --------------
// blocks [0,384): wq conv; [384,512): wp conv; [512,640): W; [640,768): WI
__global__ __launch_bounds__(256) void prep_k(
    const float* __restrict__ wq, const float* __restrict__ wp,
    unsigned short* __restrict__ wqh, unsigned short* __restrict__ wph,
    unsigned short* __restrict__ Whi, unsigned short* __restrict__ Wlo,
    unsigned short* __restrict__ WIhi)
{
    const int b = blockIdx.x;
    const int tid = threadIdx.x;
    if (b < 512) {
        const float* s = (b < 384) ? wq : wp;
        unsigned short* d = (b < 384) ? wqh : wph;
        int i = (b < 384 ? b : b - 384)*256 + tid;
        float4 a = ((const float4*)s)[i*2];
        float4 bb = ((const float4*)s)[i*2+1];
        i16x8 h;
        h[0] = (short)f2h(a.x); h[1] = (short)f2h(a.y);
        h[2] = (short)f2h(a.z); h[3] = (short)f2h(a.w);
        h[4] = (short)f2h(bb.x); h[5] = (short)f2h(bb.y);
        h[6] = (short)f2h(bb.z); h[7] = (short)f2h(bb.w);
        ((i16x8*)d)[i] = h;
    } else if (b < 640) {
        // forward twiddle W[128][256] (split f16): rows 0-63 cos, 64-127 -sin
        const int r = b - 512;
        const int t = tid;
        int idx = ((r & 63) * t) & 255;
        float sv, cv;
        sincosf(W0 * (float)idx, &sv, &cv);
        float val = (r < 64) ? cv : -sv;
        unsigned short h = f2h(val);
        Whi[r*256 + t] = h;
        Wlo[r*256 + t] = f2h(val - h2f(h));
    } else {
        // inverse twiddle WI[256][128] (f16), DC-halving folded into col 0
        int idx = (b - 640)*256 + tid;
        int t = idx >> 7;
        int f = idx & 127;
        int fr = f & 63;
        int ii = (t * fr) & 255;
        float sv, cv;
        sincosf(W0 * (float)ii, &sv, &cv);
        float cf = (fr == 0 && f < 64) ? 0.5f : 1.f;
        float val = ((f < 64) ? cv : -sv) * cf * (2.f / 256.f);
        WIhi[t*128 + f] = f2h(val);
    }
}

// ---------------- GEMM 1 (f16 MFMA, BK=64): qkv = x @ w_qkv^T ---------------
// q plane pre-scaled by 0.125. LDS-bounce epilogue: f16 output tile staged in
// LDS (XOR-swizzled), re-read 8-lane-group-per-row -> 16B coalesced stores.
__global__ __launch_bounds__(256) void gemm_qkv_k(
    const unsigned short* __restrict__ A, const unsigned short* __restrict__ B,
    unsigned short* __restrict__ qp, unsigned short* __restrict__ kp,
    unsigned short* __restrict__ vp)
{
    __shared__ unsigned short Sh[128*128];   // Ah | Bh during loop; OT after
    unsigned short* Ah = Sh;
    unsigned short* Bh = Sh + 128*64;
    const int tid = threadIdx.x;
    const int lane = tid & 63;
    const int lo = lane & 15, hi = lane >> 4;
    const int wv = tid >> 6;
    const int wr = wv >> 1, wc = wv & 1;
    const int bid = blockIdx.x;
    const int wrk = (bid & 7) * 816 + (bid >> 3);   // 6528 = 8*816, bijective
    const int col0 = (wrk % 12) * 128;
    const int row0 = (wrk / 12) * 128;

    f32x4 acc[4][4];
    #pragma unroll
    for (int rb = 0; rb < 4; ++rb)
        #pragma unroll
        for (int cb = 0; cb < 4; ++cb) acc[rb][cb] = (f32x4){0.f,0.f,0.f,0.f};

    for (int k0 = 0; k0 < 512; k0 += 64) {
        #pragma unroll
        for (int c = 0; c < 4; ++c) {
            int e = c*2048 + tid*8;
            int r = e >> 6, cc = e & 63;
            int ccs = cc ^ ((r & 7) << 3);
            size_t offA = (size_t)(row0 + r)*512 + k0 + ccs;
            size_t offB = (size_t)(col0 + r)*512 + k0 + ccs;
            GLD16(A + offA, (char*)Ah + c*4096 + tid*16);
            GLD16(B + offB, (char*)Bh + c*4096 + tid*16);
        }
        __syncthreads();
        #pragma unroll
        for (int ks = 0; ks < 2; ++ks) {
            f16x8 af[4], bf[4];
            #pragma unroll
            for (int rb = 0; rb < 4; ++rb) {
                int row = wr*64 + rb*16 + lo;
                int col = (ks*32 + hi*8) ^ ((row & 7) << 3);
                af[rb] = *(const f16x8*)&Ah[row*64 + col];
            }
            #pragma unroll
            for (int cb = 0; cb < 4; ++cb) {
                int row = wc*64 + cb*16 + lo;
                int col = (ks*32 + hi*8) ^ ((row & 7) << 3);
                bf[cb] = *(const f16x8*)&Bh[row*64 + col];
            }
            #pragma unroll
            for (int rb = 0; rb < 4; ++rb)
                #pragma unroll
                for (int cb = 0; cb < 4; ++cb)
                    acc[rb][cb] = __builtin_amdgcn_mfma_f32_16x16x32_f16(
                        af[rb], bf[cb], acc[rb][cb], 0, 0, 0);
        }
        __syncthreads();
    }

    // ---- stage output tile in LDS (f16, XOR-swizzled), conflict-free b16 ----
    #pragma unroll
    for (int cb = 0; cb < 4; ++cb) {
        int n0 = col0 + wc*64 + cb*16;
        float scl = ((n0 >> 9) == 0) ? 0.125f : 1.f;   // fold softmax scale into q
        #pragma unroll
        for (int rb = 0; rb < 4; ++rb)
            #pragma unroll
            for (int r = 0; r < 4; ++r) {
                int row = wr*64 + rb*16 + hi*4 + r;
                int col = wc*64 + cb*16 + lo;
                Sh[row*128 + (col ^ ((row & 7) << 3))] = f2h(acc[rb][cb][r]*scl);
            }
    }
    __syncthreads();

    // ---- coalesced read-out: 8-lane group owns one (row, h-half) -----------
    {
        const int grp = lane >> 3;          // 0..7
        const int d0 = (lane & 7) * 8;      // 8 u16 = 16B per lane
        #pragma unroll
        for (int it = 0; it < 8; ++it) {
            int p = it*32 + wv*8 + grp;     // 0..255 (row, half) pairs
            int row = p >> 1;
            int half = p & 1;
            int m = row0 + row;
            int bb = m / (TT*JJ);
            int rem = m - bb*(TT*JJ);
            int t = rem / JJ;
            int j = rem - t*JJ;
            int n0 = col0 + half*64;
            int g = n0 >> 9;
            unsigned short* dst0 = (g == 0) ? qp : (g == 1) ? kp : vp;
            int h = (n0 >> 6) & 7;
            unsigned short* dst = dst0 +
                ((((size_t)bb*HH + h)*JJ + j)*TT + t)*HD + d0;
            i16x8 vls = *(const i16x8*)&Sh[row*128 + ((half*64 + d0) ^ ((row & 7) << 3))];
            *(i16x8*)dst = vls;
        }
    }
}

// ---------------- GEMM 2 (f16 MFMA, BK=64): out = y @ w_proj^T + b ----------
__global__ __launch_bounds__(256) void gemm_proj_k(
    const unsigned short* __restrict__ A, const unsigned short* __restrict__ B,
    const float* __restrict__ bias, float* __restrict__ out)
{
    __shared__ unsigned short Ah[128*64];
    __shared__ unsigned short Bh[128*64];
    const int tid = threadIdx.x;
    const int lane = tid & 63;
    const int lo = lane & 15, hi = lane >> 4;
    const int wv = tid >> 6;
    const int wr = wv >> 1, wc = wv & 1;
    const int bid = blockIdx.x;
    const int wrk = (bid & 7) * 272 + (bid >> 3);   // 2176 = 8*272, bijective
    const int col0 = (wrk % 4) * 128;
    const int row0 = (wrk / 4) * 128;

    f32x4 acc[4][4];
    #pragma unroll
    for (int rb = 0; rb < 4; ++rb)
        #pragma unroll
        for (int cb = 0; cb < 4; ++cb) acc[rb][cb] = (f32x4){0.f,0.f,0.f,0.f};

    for (int k0 = 0; k0 < 512; k0 += 64) {
        #pragma unroll
        for (int c = 0; c < 4; ++c) {
            int e = c*2048 + tid*8;
            int r = e >> 6, cc = e & 63;
            int ccs = cc ^ ((r & 7) << 3);
            size_t offA = (size_t)(row0 + r)*512 + k0 + ccs;
            size_t offB = (size_t)(col0 + r)*512 + k0 + ccs;
            GLD16(A + offA, (char*)Ah + c*4096 + tid*16);
            GLD16(B + offB, (char*)Bh + c*4096 + tid*16);
        }
        __syncthreads();
        #pragma unroll
        for (int ks = 0; ks < 2; ++ks) {
            f16x8 af[4], bf[4];
            #pragma unroll
            for (int rb = 0; rb < 4; ++rb) {
                int row = wr*64 + rb*16 + lo;
                int col = (ks*32 + hi*8) ^ ((row & 7) << 3);
                af[rb] = *(const f16x8*)&Ah[row*64 + col];
            }
            #pragma unroll
            for (int cb = 0; cb < 4; ++cb) {
                int row = wc*64 + cb*16 + lo;
                int col = (ks*32 + hi*8) ^ ((row & 7) << 3);
                bf[cb] = *(const f16x8*)&Bh[row*64 + col];
            }
            #pragma unroll
            for (int rb = 0; rb < 4; ++rb)
                #pragma unroll
                for (int cb = 0; cb < 4; ++cb)
                    acc[rb][cb] = __builtin_amdgcn_mfma_f32_16x16x32_f16(
                        af[rb], bf[cb], acc[rb][cb], 0, 0, 0);
        }
        __syncthreads();
    }

    #pragma unroll
    for (int cb = 0; cb < 4; ++cb) {
        int n = col0 + wc*64 + cb*16 + lo;
        float bv = bias[n];
        #pragma unroll
        for (int rb = 0; rb < 4; ++rb)
            #pragma unroll
            for (int r = 0; r < 4; ++r) {
                int m = row0 + wr*64 + rb*16 + hi*4 + r;
                out[(size_t)m*512 + n] = acc[rb][cb][r] + bv;
            }
    }
}

// ---------------- time attention via f16 MFMA (q pre-scaled) ----------------
#define VTP 264
#define PPW 40

__global__ __launch_bounds__(256, 2) void attn_time_k(
    const unsigned short* __restrict__ q, const unsigned short* __restrict__ k,
    const unsigned short* __restrict__ v, const float* __restrict__ fg,
    unsigned short* __restrict__ y)
{
    __shared__ unsigned short VT[64 * VTP];
    __shared__ unsigned short PL[4 * 64 * PPW];

    const int bid = blockIdx.x;
    const int b = bid / (HH*JJ);
    const int h = (bid / JJ) % HH;
    const int j = bid % JJ;
    const size_t base = (size_t)bid * QTILE;

    const int tid = threadIdx.x;
    const int w = tid >> 6;
    const int lane = tid & 63;
    const int lo = lane & 15;
    const int hi = lane >> 4;

    {
        const unsigned short* vptr = v + base + (size_t)tid * HD;
        #pragma unroll
        for (int d0 = 0; d0 < 64; d0 += 8) {
            i16x8 vv = *(const i16x8*)(vptr + d0);
            #pragma unroll
            for (int e = 0; e < 8; ++e)
                VT[(d0+e)*VTP + tid] = (unsigned short)vv[e];
        }
    }
    __syncthreads();

    f16x8 qf[4][2];
    #pragma unroll
    for (int rb = 0; rb < 4; ++rb)
        #pragma unroll
        for (int dc = 0; dc < 2; ++dc)
            qf[rb][dc] = *(const f16x8*)(q + base + (size_t)(w*64 + rb*16 + lo)*HD + dc*32 + hi*8);

    f32x4 o[4][4];
    #pragma unroll
    for (int rb = 0; rb < 4; ++rb)
        #pragma unroll
        for (int cd = 0; cd < 4; ++cd) o[rb][cd] = (f32x4){0.f,0.f,0.f,0.f};
    float rs[4][4];
    #pragma unroll
    for (int rb = 0; rb < 4; ++rb)
        #pragma unroll
        for (int r = 0; r < 4; ++r) rs[rb][r] = 0.f;

    unsigned short* Pw = PL + w * 64 * PPW;

    for (int st = 0; st < 8; ++st) {
        const int s0 = st * 32;
        f16x8 kf[2][2];
        #pragma unroll
        for (int cb = 0; cb < 2; ++cb)
            #pragma unroll
            for (int dc = 0; dc < 2; ++dc)
                kf[cb][dc] = *(const f16x8*)(k + base + (size_t)(s0 + cb*16 + lo)*HD + dc*32 + hi*8);

        #pragma unroll
        for (int rb = 0; rb < 4; ++rb) {
            #pragma unroll
            for (int cb = 0; cb < 2; ++cb) {
                f32x4 acc = (f32x4){0.f,0.f,0.f,0.f};
                acc = __builtin_amdgcn_mfma_f32_16x16x32_f16(qf[rb][0], kf[cb][0], acc, 0, 0, 0);
                acc = __builtin_amdgcn_mfma_f32_16x16x32_f16(qf[rb][1], kf[cb][1], acc, 0, 0, 0);
                #pragma unroll
                for (int r = 0; r < 4; ++r) {
                    float p = __expf(acc[r]);     // scale folded into q
                    rs[rb][r] += p;
                    Pw[(rb*16 + hi*4 + r)*PPW + cb*16 + lo] = f2h(p);
                }
            }
        }

        f16x8 pa[4];
        #pragma unroll
        for (int rb = 0; rb < 4; ++rb)
            pa[rb] = *(const f16x8*)&Pw[(rb*16 + lo)*PPW + hi*8];
        f16x8 bv[4];
        #pragma unroll
        for (int cd = 0; cd < 4; ++cd)
            bv[cd] = *(const f16x8*)&VT[(cd*16 + lo)*VTP + s0 + hi*8];
        #pragma unroll
        for (int rb = 0; rb < 4; ++rb)
            #pragma unroll
            for (int cd = 0; cd < 4; ++cd)
                o[rb][cd] = __builtin_amdgcn_mfma_f32_16x16x32_f16(pa[rb], bv[cd], o[rb][cd], 0, 0, 0);
    }

    #pragma unroll
    for (int off = 1; off < 16; off <<= 1)
        #pragma unroll
        for (int rb = 0; rb < 4; ++rb)
            #pragma unroll
            for (int r = 0; r < 4; ++r)
                rs[rb][r] += __shfl_xor(rs[rb][r], off, 64);

    const float gate = 1.f / (1.f + __expf(-fg[0]));
    const float wt = 1.f - gate;
    #pragma unroll
    for (int rb = 0; rb < 4; ++rb) {
        #pragma unroll
        for (int r = 0; r < 4; ++r) {
            const int t = w*64 + rb*16 + hi*4 + r;
            const float sc = wt / rs[rb][r];
            unsigned short* yp = y + (((size_t)b*TT + t)*JJ + j)*CC + h*HD;
            #pragma unroll
            for (int cd = 0; cd < 4; ++cd)
                yp[cd*16 + lo] = f2h(o[rb][cd][r] * sc);
        }
    }
}

// ---------------- F1: DFT MFMA GEMM, f16 in -> f16 freq out in place --------
#define XP 280

__global__ __launch_bounds__(256) void dft_k(
    unsigned short* __restrict__ planes, const unsigned short* __restrict__ Whi,
    const unsigned short* __restrict__ Wlo)
{
    __shared__ unsigned short Xh[64*XP];
    unsigned short* src = planes + (size_t)blockIdx.y*NQKV + (size_t)blockIdx.x*QTILE;
    const int tid = threadIdx.x;
    const int w = tid >> 6;
    const int lane = tid & 63;
    const int qd = (tid >> 4) & 3;
    const int rr = tid & 15;
    const int lo = lane & 15, hi = lane >> 4;

    #pragma unroll
    for (int p = 0; p < 16; ++p) {
        const int t = p*16 + 4*w + qd;
        ushort4 x4 = *(const ushort4*)&src[t*64 + 4*rr];
        unsigned int a0 = x4.x, a1 = x4.y, a2 = x4.z, a3 = x4.w;
        unsigned int t01 = (unsigned)__shfl_xor((int)((qd&1) ? a0 : a1), 16, 64);
        unsigned int t23 = (unsigned)__shfl_xor((int)((qd&1) ? a2 : a3), 16, 64);
        if (qd&1) { a0 = t01; a2 = t23; } else { a1 = t01; a3 = t23; }
        unsigned int u01 = (unsigned)__shfl_xor((int)((qd&2) ? a0 : a2), 32, 64);
        unsigned int u23 = (unsigned)__shfl_xor((int)((qd&2) ? a1 : a3), 32, 64);
        if (qd&2) { a0 = u01; a1 = u23; } else { a2 = u01; a3 = u23; }
        const int dd = 4*rr + qd;
        const int tb = p*16 + 4*w;
        ushort4 hv;
        hv.x = (unsigned short)a0; hv.y = (unsigned short)a1;
        hv.z = (unsigned short)a2; hv.w = (unsigned short)a3;
        *(ushort4*)&Xh[dd*XP + tb] = hv;
    }
    __syncthreads();

    f32x4 acc[2][4];
    #pragma unroll
    for (int rb = 0; rb < 2; ++rb)
        #pragma unroll
        for (int cd = 0; cd < 4; ++cd) acc[rb][cd] = (f32x4){0.f,0.f,0.f,0.f};

    for (int ks = 0; ks < 8; ++ks) {
        const int k0 = ks*32;
        f16x8 ah[2], al[2];
        #pragma unroll
        for (int rb = 0; rb < 2; ++rb) {
            int r = w*32 + rb*16 + lo;
            ah[rb] = *(const f16x8*)&Whi[r*256 + k0 + hi*8];
            al[rb] = *(const f16x8*)&Wlo[r*256 + k0 + hi*8];
        }
        f16x8 bh[4];
        #pragma unroll
        for (int cd = 0; cd < 4; ++cd) {
            int d = cd*16 + lo;
            bh[cd] = *(const f16x8*)&Xh[d*XP + k0 + hi*8];
        }
        #pragma unroll
        for (int rb = 0; rb < 2; ++rb)
            #pragma unroll
            for (int cd = 0; cd < 4; ++cd) {
                acc[rb][cd] = __builtin_amdgcn_mfma_f32_16x16x32_f16(
                    ah[rb], bh[cd], acc[rb][cd], 0, 0, 0);
                acc[rb][cd] = __builtin_amdgcn_mfma_f32_16x16x32_f16(
                    al[rb], bh[cd], acc[rb][cd], 0, 0, 0);
            }
    }

    #pragma unroll
    for (int rb = 0; rb < 2; ++rb) {
        #pragma unroll
        for (int r = 0; r < 4; ++r) {
            int row = w*32 + rb*16 + hi*4 + r;
            unsigned short* dst = (row < 64) ? (src + row*64)
                                             : (src + 4096 + (row-64)*64);
            #pragma unroll
            for (int cd = 0; cd < 4; ++cd)
                dst[cd*16 + lo] = f2h(acc[rb][cd][r]);
        }
    }
}

// ---------------- F2+F3 fused: af -> dual softmax -> xf -> irfft -> y -------
#define XFP 136

__global__ __launch_bounds__(256) void freqtail_k(
    unsigned short* __restrict__ qfp, const unsigned short* __restrict__ kfp,
    const unsigned short* __restrict__ vfp, const unsigned short* __restrict__ WIhi,
    const float* __restrict__ fg, unsigned short* __restrict__ y)
{
    extern __shared__ float lds[];
    float* A = lds;
    float* B = lds + 2*FHALF;

    const int tid = threadIdx.x;
    const int tile = blockIdx.x;
    const int b = tile / (HH*JJ);
    const int h = (tile / JJ) % HH;
    const int j = tile % JJ;
    const unsigned short* qf = qfp + (size_t)tile * QTILE;
    const unsigned short* kf = kfp + (size_t)tile * QTILE;
    const unsigned short* vf = vfp + (size_t)tile * QTILE;

    #pragma unroll
    for (int p = 0; p < 4; ++p) {
        int idx = p*256 + tid;
        int e8 = idx*8;
        int part = e8 >> 12;
        int row = (e8 >> 6) & 63;
        int col = e8 & 63;
        i16x8 qv = *(const i16x8*)(qf + e8);
        i16x8 kv = *(const i16x8*)(kf + e8);
        float* ap = A + part*FHALF + row*FP + col;
        float* bp = B + part*FHALF + row*FP + col;
        #pragma unroll
        for (int e = 0; e < 8; ++e) {
            ap[e] = h2f((unsigned short)qv[e]);
            bp[e] = h2f((unsigned short)kv[e]);
        }
    }
    __syncthreads();

    const int fy = tid >> 4;
    const int gl = tid & 15;

    float cR[4][4], cI[4][4];
    #pragma unroll
    for (int i = 0; i < 4; ++i)
        #pragma unroll
        for (int gi = 0; gi < 4; ++gi) { cR[i][gi] = 0.f; cI[i][gi] = 0.f; }

    for (int d4 = 0; d4 < 16; ++d4) {
        float4 qr[4], qi[4], kr[4], ki[4];
        #pragma unroll
        for (int i = 0; i < 4; ++i) {
            int f = fy + 16*i;
            qr[i] = *(const float4*)(A + f*FP + d4*4);
            qi[i] = *(const float4*)(A + FHALF + f*FP + d4*4);
            int g = gl + 16*i;
            kr[i] = *(const float4*)(B + g*FP + d4*4);
            ki[i] = *(const float4*)(B + FHALF + g*FP + d4*4);
        }
        #pragma unroll
        for (int i = 0; i < 4; ++i)
            #pragma unroll
            for (int gi = 0; gi < 4; ++gi) {
                float r = cR[i][gi], m = cI[i][gi];
                r = fmaf(qr[i].x, kr[gi].x, r); r = fmaf(qi[i].x, ki[gi].x, r);
                r = fmaf(qr[i].y, kr[gi].y, r); r = fmaf(qi[i].y, ki[gi].y, r);
                r = fmaf(qr[i].z, kr[gi].z, r); r = fmaf(qi[i].z, ki[gi].z, r);
                r = fmaf(qr[i].w, kr[gi].w, r); r = fmaf(qi[i].w, ki[gi].w, r);
                m = fmaf(qi[i].x, kr[gi].x, m); m = fmaf(-qr[i].x, ki[gi].x, m);
                m = fmaf(qi[i].y, kr[gi].y, m); m = fmaf(-qr[i].y, ki[gi].y, m);
                m = fmaf(qi[i].z, kr[gi].z, m); m = fmaf(-qr[i].z, ki[gi].z, m);
                m = fmaf(qi[i].w, kr[gi].w, m); m = fmaf(-qr[i].w, ki[gi].w, m);
                cR[i][gi] = r; cI[i][gi] = m;
            }
    }
    __syncthreads();

    #pragma unroll
    for (int i = 0; i < 4; ++i)
        #pragma unroll
        for (int gi = 0; gi < 4; ++gi) {
            A[(fy + 16*i)*FP + gl + 16*gi]         = cR[i][gi];
            A[FHALF + (fy + 16*i)*FP + gl + 16*gi] = cI[i][gi];
        }
    #pragma unroll
    for (int p = 0; p < 4; ++p) {
        int idx = p*256 + tid;
        int e8 = idx*8;
        int part = e8 >> 12;
        int row = (e8 >> 6) & 63;
        int col = e8 & 63;
        i16x8 vv = *(const i16x8*)(vf + e8);
        float* bp = B + part*FHALF + row*FP + col;
        #pragma unroll
        for (int e = 0; e < 8; ++e) bp[e] = h2f((unsigned short)vv[e]);
    }
    __syncthreads();

    if (tid < 128) {
        float* row = A + (tid >> 6)*FHALF + (tid & 63)*FP;
        float mx = row[0];
        for (int g2 = 1; g2 < 64; ++g2) mx = fmaxf(mx, row[g2]);
        float sum = 0.f;
        for (int g2 = 0; g2 < 64; ++g2) { float e = __expf(row[g2]-mx); row[g2] = e; sum += e; }
        float inv = 1.f / sum;
        for (int g2 = 0; g2 < 64; ++g2) row[g2] *= inv;
    }
    __syncthreads();

    float xR[4][4], xI[4][4];
    #pragma unroll
    for (int i = 0; i < 4; ++i)
        #pragma unroll
        for (int cmp = 0; cmp < 4; ++cmp) { xR[i][cmp] = 0.f; xI[i][cmp] = 0.f; }

    for (int g2 = 0; g2 < 64; ++g2) {
        float4 vr = *(const float4*)(B + g2*FP + gl*4);
        float4 vi = *(const float4*)(B + FHALF + g2*FP + gl*4);
        #pragma unroll
        for (int i = 0; i < 4; ++i) {
            float sr = A[(fy + 16*i)*FP + g2];
            float si = A[FHALF + (fy + 16*i)*FP + g2];
            xR[i][0] = fmaf(sr, vr.x, fmaf(-si, vi.x, xR[i][0]));
            xI[i][0] = fmaf(sr, vi.x, fmaf( si, vr.x, xI[i][0]));
            xR[i][1] = fmaf(sr, vr.y, fmaf(-si, vi.y, xR[i][1]));
            xI[i][1] = fmaf(sr, vi.y, fmaf( si, vr.y, xI[i][1]));
            xR[i][2] = fmaf(sr, vr.z, fmaf(-si, vi.z, xR[i][2]));
            xI[i][2] = fmaf(sr, vi.z, fmaf( si, vr.z, xI[i][2]));
            xR[i][3] = fmaf(sr, vr.w, fmaf(-si, vi.w, xR[i][3]));
            xI[i][3] = fmaf(sr, vi.w, fmaf( si, vr.w, xI[i][3]));
        }
    }
    __syncthreads();   // all vf reads done -> safe to overwrite B with XT

    unsigned short* XT = (unsigned short*)B;
    #pragma unroll
    for (int i = 0; i < 4; ++i) {
        int f = fy + 16*i;
        #pragma unroll
        for (int e = 0; e < 4; ++e) {
            XT[(gl*4+e)*XFP + f]      = f2h(xR[i][e]);
            XT[(gl*4+e)*XFP + 64 + f] = f2h(xI[i][e]);
        }
    }
    __syncthreads();

    const int w = tid >> 6;
    const int lane = tid & 63;
    const int lo = lane & 15, hi = lane >> 4;

    f32x4 acc[4][4];
    #pragma unroll
    for (int rb = 0; rb < 4; ++rb)
        #pragma unroll
        for (int cd = 0; cd < 4; ++cd) acc[rb][cd] = (f32x4){0.f,0.f,0.f,0.f};

    #pragma unroll
    for (int ks = 0; ks < 4; ++ks) {
        const int k0 = ks*32;
        f16x8 ah[4];
        #pragma unroll
        for (int rb = 0; rb < 4; ++rb) {
            int row = w*64 + rb*16 + lo;
            ah[rb] = *(const f16x8*)&WIhi[row*128 + k0 + hi*8];
        }
        f16x8 bt[4];
        #pragma unroll
        for (int cd = 0; cd < 4; ++cd) {
            int d = cd*16 + lo;
            bt[cd] = *(const f16x8*)&XT[d*XFP + k0 + hi*8];
        }
        #pragma unroll
        for (int rb = 0; rb < 4; ++rb)
            #pragma unroll
            for (int cd = 0; cd < 4; ++cd)
                acc[rb][cd] = __builtin_amdgcn_mfma_f32_16x16x32_f16(
                    ah[rb], bt[cd], acc[rb][cd], 0, 0, 0);
    }

    const float gate = 1.f / (1.f + __expf(-fg[0]));
    #pragma unroll
    for (int rb = 0; rb < 4; ++rb) {
        #pragma unroll
        for (int r = 0; r < 4; ++r) {
            int t = w*64 + rb*16 + hi*4 + r;
            unsigned short* yp = y + (((size_t)b*TT + t)*JJ + j)*CC + h*HD;
            #pragma unroll
            for (int cd = 0; cd < 4; ++cd) {
                int d = cd*16 + lo;
                yp[d] = f2h(fmaf(gate, acc[rb][cd][r], h2f(yp[d])));
            }
        }
    }
}

// ---------------------------------------------------------------------------
extern "C" void kernel_launch(void* const* d_in, const int* in_sizes, int n_in,
                              void* d_out, int out_size, void* d_ws, size_t ws_size,
                              hipStream_t stream) {
    const float* x      = (const float*)d_in[0];
    const float* w_qkv  = (const float*)d_in[1];
    const float* w_proj = (const float*)d_in[2];
    const float* b_proj = (const float*)d_in[3];
    const float* fg     = (const float*)d_in[4];
    float* out = (float*)d_out;

    unsigned short* qp = (unsigned short*)d_ws;
    unsigned short* kp = qp + NQKV;
    unsigned short* vp = kp + NQKV;
    unsigned short* xh = vp + NQKV;
    unsigned short* y  = xh + NQKV;
    unsigned short* wph = y + NQKV;
    unsigned short* wqh = (unsigned short*)d_out;
    unsigned short* Whi  = wqh + 1536*512;   // 128*256
    unsigned short* Wlo  = Whi + 128*256;
    unsigned short* WIhi = Wlo + 128*256;    // 256*128

    (void)hipFuncSetAttribute((const void*)freqtail_k,
                              hipFuncAttributeMaxDynamicSharedMemorySize, 4*FHALF*4);

    conv16_k<<<2048, 256, 0, stream>>>(x, xh, NQKV/8);
    prep_k<<<768, 256, 0, stream>>>(w_qkv, w_proj, wqh, wph, Whi, Wlo, WIhi);

    gemm_qkv_k<<<6528, 256, 0, stream>>>(xh, wqh, qp, kp, vp);
    attn_time_k<<<NTILES, 256, 0, stream>>>(qp, kp, vp, fg, y);
    dft_k<<<dim3(NTILES, 3), 256, 0, stream>>>(qp, Whi, Wlo);
    freqtail_k<<<NTILES, 256, 4*FHALF*4, stream>>>(qp, kp, vp, WIhi, fg, y);

    gemm_proj_k<<<2176, 256, 0, stream>>>(y, wph, b_proj, out);
}

// Round 14
// 586.134 us; speedup vs baseline: 2.1832x; 1.1737x over previous
//
#include <hip/hip_runtime.h>
#include <hip/hip_fp16.h>
#include <math.h>

#define NB 16
#define TT 256
#define JJ 17
#define CC 512
#define HH 8
#define HD 64
#define MROWS (NB*TT*JJ)        // 69632
#define QTILE 16384             // u16 elems per (b,h,j) tile
#define NTILES (NB*HH*JJ)       // 2176
#define NQKV 35651584           // elements per plane (MROWS*512)

#define W0 0.0245436926061702596f   // 2*pi/256

typedef __attribute__((ext_vector_type(8))) short i16x8;
typedef __attribute__((ext_vector_type(8))) _Float16 f16x8;
typedef __attribute__((ext_vector_type(4))) float f32x4;

__device__ __forceinline__ unsigned short f2h(float f) {
    return (unsigned short)__half_as_ushort(__float2half(f));
}
__device__ __forceinline__ float h2f(unsigned short u) {
    return __half2float(__ushort_as_half(u));
}

#define GLD16(gp, lp) __builtin_amdgcn_global_load_lds( \
    (__attribute__((address_space(1))) void*)(gp), \
    (__attribute__((address_space(3))) void*)(lp), 16, 0, 0)

// ---------------- f32 -> f16 conversion (8-wide) ----------------------------
__global__ __launch_bounds__(256) void conv16_k(
    const float* __restrict__ s, unsigned short* __restrict__ d, int n8)
{
    for (int i = blockIdx.x*256 + threadIdx.x; i < n8; i += gridDim.x*256) {
        float4 a = ((const float4*)s)[i*2];
        float4 b = ((const float4*)s)[i*2+1];
        i16x8 h;
        h[0] = (short)f2h(a.x); h[1] = (short)f2h(a.y);
        h[2] = (short)f2h(a.z); h[3] = (short)f2h(a.w);
        h[4] = (short)f2h(b.x); h[5] = (short)f2h(b.y);
        h[6] = (short)f2h(b.z); h[7] = (short)f2h(b.w);
        ((i16x8*)d)[i] = h;
    }
}

// ---------------- fused prep: wq/wp conv + W + WI twiddle init --------------
__global__ __launch_bounds__(256) void prep_k(
    const float* __restrict__ wq, const float* __restrict__ wp,
    unsigned short* __restrict__ wqh, unsigned short* __restrict__ wph,
    unsigned short* __restrict__ Whi, unsigned short* __restrict__ Wlo,
    unsigned short* __restrict__ WIhi)
{
    const int b = blockIdx.x;
    const int tid = threadIdx.x;
    if (b < 512) {
        const float* s = (b < 384) ? wq : wp;
        unsigned short* d = (b < 384) ? wqh : wph;
        int i = (b < 384 ? b : b - 384)*256 + tid;
        float4 a = ((const float4*)s)[i*2];
        float4 bb = ((const float4*)s)[i*2+1];
        i16x8 h;
        h[0] = (short)f2h(a.x); h[1] = (short)f2h(a.y);
        h[2] = (short)f2h(a.z); h[3] = (short)f2h(a.w);
        h[4] = (short)f2h(bb.x); h[5] = (short)f2h(bb.y);
        h[6] = (short)f2h(bb.z); h[7] = (short)f2h(bb.w);
        ((i16x8*)d)[i] = h;
    } else if (b < 640) {
        const int r = b - 512;
        const int t = tid;
        int idx = ((r & 63) * t) & 255;
        float sv, cv;
        sincosf(W0 * (float)idx, &sv, &cv);
        float val = (r < 64) ? cv : -sv;
        unsigned short h = f2h(val);
        Whi[r*256 + t] = h;
        Wlo[r*256 + t] = f2h(val - h2f(h));
    } else {
        int idx = (b - 640)*256 + tid;
        int t = idx >> 7;
        int f = idx & 127;
        int fr = f & 63;
        int ii = (t * fr) & 255;
        float sv, cv;
        sincosf(W0 * (float)ii, &sv, &cv);
        float cf = (fr == 0 && f < 64) ? 0.5f : 1.f;
        float val = ((f < 64) ? cv : -sv) * cf * (2.f / 256.f);
        WIhi[t*128 + f] = f2h(val);
    }
}

// ---------------- GEMM 1 (f16 MFMA, BK=64): qkv = x @ w_qkv^T ---------------
__global__ __launch_bounds__(256) void gemm_qkv_k(
    const unsigned short* __restrict__ A, const unsigned short* __restrict__ B,
    unsigned short* __restrict__ qp, unsigned short* __restrict__ kp,
    unsigned short* __restrict__ vp)
{
    __shared__ unsigned short Sh[128*128];
    unsigned short* Ah = Sh;
    unsigned short* Bh = Sh + 128*64;
    const int tid = threadIdx.x;
    const int lane = tid & 63;
    const int lo = lane & 15, hi = lane >> 4;
    const int wv = tid >> 6;
    const int wr = wv >> 1, wc = wv & 1;
    const int bid = blockIdx.x;
    const int wrk = (bid & 7) * 816 + (bid >> 3);
    const int col0 = (wrk % 12) * 128;
    const int row0 = (wrk / 12) * 128;

    f32x4 acc[4][4];
    #pragma unroll
    for (int rb = 0; rb < 4; ++rb)
        #pragma unroll
        for (int cb = 0; cb < 4; ++cb) acc[rb][cb] = (f32x4){0.f,0.f,0.f,0.f};

    for (int k0 = 0; k0 < 512; k0 += 64) {
        #pragma unroll
        for (int c = 0; c < 4; ++c) {
            int e = c*2048 + tid*8;
            int r = e >> 6, cc = e & 63;
            int ccs = cc ^ ((r & 7) << 3);
            size_t offA = (size_t)(row0 + r)*512 + k0 + ccs;
            size_t offB = (size_t)(col0 + r)*512 + k0 + ccs;
            GLD16(A + offA, (char*)Ah + c*4096 + tid*16);
            GLD16(B + offB, (char*)Bh + c*4096 + tid*16);
        }
        __syncthreads();
        #pragma unroll
        for (int ks = 0; ks < 2; ++ks) {
            f16x8 af[4], bf[4];
            #pragma unroll
            for (int rb = 0; rb < 4; ++rb) {
                int row = wr*64 + rb*16 + lo;
                int col = (ks*32 + hi*8) ^ ((row & 7) << 3);
                af[rb] = *(const f16x8*)&Ah[row*64 + col];
            }
            #pragma unroll
            for (int cb = 0; cb < 4; ++cb) {
                int row = wc*64 + cb*16 + lo;
                int col = (ks*32 + hi*8) ^ ((row & 7) << 3);
                bf[cb] = *(const f16x8*)&Bh[row*64 + col];
            }
            #pragma unroll
            for (int rb = 0; rb < 4; ++rb)
                #pragma unroll
                for (int cb = 0; cb < 4; ++cb)
                    acc[rb][cb] = __builtin_amdgcn_mfma_f32_16x16x32_f16(
                        af[rb], bf[cb], acc[rb][cb], 0, 0, 0);
        }
        __syncthreads();
    }

    #pragma unroll
    for (int cb = 0; cb < 4; ++cb) {
        int n0 = col0 + wc*64 + cb*16;
        float scl = ((n0 >> 9) == 0) ? 0.125f : 1.f;
        #pragma unroll
        for (int rb = 0; rb < 4; ++rb)
            #pragma unroll
            for (int r = 0; r < 4; ++r) {
                int row = wr*64 + rb*16 + hi*4 + r;
                int col = wc*64 + cb*16 + lo;
                Sh[row*128 + (col ^ ((row & 7) << 3))] = f2h(acc[rb][cb][r]*scl);
            }
    }
    __syncthreads();

    {
        const int grp = lane >> 3;
        const int d0 = (lane & 7) * 8;
        #pragma unroll
        for (int it = 0; it < 8; ++it) {
            int p = it*32 + wv*8 + grp;
            int row = p >> 1;
            int half = p & 1;
            int m = row0 + row;
            int bb = m / (TT*JJ);
            int rem = m - bb*(TT*JJ);
            int t = rem / JJ;
            int j = rem - t*JJ;
            int n0 = col0 + half*64;
            int g = n0 >> 9;
            unsigned short* dst0 = (g == 0) ? qp : (g == 1) ? kp : vp;
            int h = (n0 >> 6) & 7;
            unsigned short* dst = dst0 +
                ((((size_t)bb*HH + h)*JJ + j)*TT + t)*HD + d0;
            i16x8 vls = *(const i16x8*)&Sh[row*128 + ((half*64 + d0) ^ ((row & 7) << 3))];
            *(i16x8*)dst = vls;
        }
    }
}

// ---------------- GEMM 2 (f16 MFMA, BK=64): out = y @ w_proj^T + b ----------
__global__ __launch_bounds__(256) void gemm_proj_k(
    const unsigned short* __restrict__ A, const unsigned short* __restrict__ B,
    const float* __restrict__ bias, float* __restrict__ out)
{
    __shared__ unsigned short Ah[128*64];
    __shared__ unsigned short Bh[128*64];
    const int tid = threadIdx.x;
    const int lane = tid & 63;
    const int lo = lane & 15, hi = lane >> 4;
    const int wv = tid >> 6;
    const int wr = wv >> 1, wc = wv & 1;
    const int bid = blockIdx.x;
    const int wrk = (bid & 7) * 272 + (bid >> 3);
    const int col0 = (wrk % 4) * 128;
    const int row0 = (wrk / 4) * 128;

    f32x4 acc[4][4];
    #pragma unroll
    for (int rb = 0; rb < 4; ++rb)
        #pragma unroll
        for (int cb = 0; cb < 4; ++cb) acc[rb][cb] = (f32x4){0.f,0.f,0.f,0.f};

    for (int k0 = 0; k0 < 512; k0 += 64) {
        #pragma unroll
        for (int c = 0; c < 4; ++c) {
            int e = c*2048 + tid*8;
            int r = e >> 6, cc = e & 63;
            int ccs = cc ^ ((r & 7) << 3);
            size_t offA = (size_t)(row0 + r)*512 + k0 + ccs;
            size_t offB = (size_t)(col0 + r)*512 + k0 + ccs;
            GLD16(A + offA, (char*)Ah + c*4096 + tid*16);
            GLD16(B + offB, (char*)Bh + c*4096 + tid*16);
        }
        __syncthreads();
        #pragma unroll
        for (int ks = 0; ks < 2; ++ks) {
            f16x8 af[4], bf[4];
            #pragma unroll
            for (int rb = 0; rb < 4; ++rb) {
                int row = wr*64 + rb*16 + lo;
                int col = (ks*32 + hi*8) ^ ((row & 7) << 3);
                af[rb] = *(const f16x8*)&Ah[row*64 + col];
            }
            #pragma unroll
            for (int cb = 0; cb < 4; ++cb) {
                int row = wc*64 + cb*16 + lo;
                int col = (ks*32 + hi*8) ^ ((row & 7) << 3);
                bf[cb] = *(const f16x8*)&Bh[row*64 + col];
            }
            #pragma unroll
            for (int rb = 0; rb < 4; ++rb)
                #pragma unroll
                for (int cb = 0; cb < 4; ++cb)
                    acc[rb][cb] = __builtin_amdgcn_mfma_f32_16x16x32_f16(
                        af[rb], bf[cb], acc[rb][cb], 0, 0, 0);
        }
        __syncthreads();
    }

    #pragma unroll
    for (int cb = 0; cb < 4; ++cb) {
        int n = col0 + wc*64 + cb*16 + lo;
        float bv = bias[n];
        #pragma unroll
        for (int rb = 0; rb < 4; ++rb)
            #pragma unroll
            for (int r = 0; r < 4; ++r) {
                int m = row0 + wr*64 + rb*16 + hi*4 + r;
                out[(size_t)m*512 + n] = acc[rb][cb][r] + bv;
            }
    }
}

// ---------------- time attention via f16 MFMA (q pre-scaled) ----------------
// VT: pitch 256 + both-sides XOR swizzle -> 52KB total LDS -> 3 blocks/CU.
#define PPW 40

__global__ __launch_bounds__(256, 3) void attn_time_k(
    const unsigned short* __restrict__ q, const unsigned short* __restrict__ k,
    const unsigned short* __restrict__ v, const float* __restrict__ fg,
    unsigned short* __restrict__ y)
{
    __shared__ unsigned short VT[64 * 256];
    __shared__ unsigned short PL[4 * 64 * PPW];

    const int bid = blockIdx.x;
    const int b = bid / (HH*JJ);
    const int h = (bid / JJ) % HH;
    const int j = bid % JJ;
    const size_t base = (size_t)bid * QTILE;

    const int tid = threadIdx.x;
    const int w = tid >> 6;
    const int lane = tid & 63;
    const int lo = lane & 15;
    const int hi = lane >> 4;

    {
        const unsigned short* vptr = v + base + (size_t)tid * HD;
        #pragma unroll
        for (int d0 = 0; d0 < 64; d0 += 8) {
            i16x8 vv = *(const i16x8*)(vptr + d0);
            #pragma unroll
            for (int e = 0; e < 8; ++e) {
                int row = d0 + e;
                VT[row*256 + (tid ^ ((row & 7) << 3))] = (unsigned short)vv[e];
            }
        }
    }
    __syncthreads();

    f16x8 qf[4][2];
    #pragma unroll
    for (int rb = 0; rb < 4; ++rb)
        #pragma unroll
        for (int dc = 0; dc < 2; ++dc)
            qf[rb][dc] = *(const f16x8*)(q + base + (size_t)(w*64 + rb*16 + lo)*HD + dc*32 + hi*8);

    f32x4 o[4][4];
    #pragma unroll
    for (int rb = 0; rb < 4; ++rb)
        #pragma unroll
        for (int cd = 0; cd < 4; ++cd) o[rb][cd] = (f32x4){0.f,0.f,0.f,0.f};
    float rs[4][4];
    #pragma unroll
    for (int rb = 0; rb < 4; ++rb)
        #pragma unroll
        for (int r = 0; r < 4; ++r) rs[rb][r] = 0.f;

    unsigned short* Pw = PL + w * 64 * PPW;

    for (int st = 0; st < 8; ++st) {
        const int s0 = st * 32;
        f16x8 kf[2][2];
        #pragma unroll
        for (int cb = 0; cb < 2; ++cb)
            #pragma unroll
            for (int dc = 0; dc < 2; ++dc)
                kf[cb][dc] = *(const f16x8*)(k + base + (size_t)(s0 + cb*16 + lo)*HD + dc*32 + hi*8);

        #pragma unroll
        for (int rb = 0; rb < 4; ++rb) {
            #pragma unroll
            for (int cb = 0; cb < 2; ++cb) {
                f32x4 acc = (f32x4){0.f,0.f,0.f,0.f};
                acc = __builtin_amdgcn_mfma_f32_16x16x32_f16(qf[rb][0], kf[cb][0], acc, 0, 0, 0);
                acc = __builtin_amdgcn_mfma_f32_16x16x32_f16(qf[rb][1], kf[cb][1], acc, 0, 0, 0);
                #pragma unroll
                for (int r = 0; r < 4; ++r) {
                    float p = __expf(acc[r]);
                    rs[rb][r] += p;
                    Pw[(rb*16 + hi*4 + r)*PPW + cb*16 + lo] = f2h(p);
                }
            }
        }

        f16x8 pa[4];
        #pragma unroll
        for (int rb = 0; rb < 4; ++rb)
            pa[rb] = *(const f16x8*)&Pw[(rb*16 + lo)*PPW + hi*8];
        f16x8 bv[4];
        #pragma unroll
        for (int cd = 0; cd < 4; ++cd) {
            int row = cd*16 + lo;
            bv[cd] = *(const f16x8*)&VT[row*256 + ((s0 + hi*8) ^ ((row & 7) << 3))];
        }
        #pragma unroll
        for (int rb = 0; rb < 4; ++rb)
            #pragma unroll
            for (int cd = 0; cd < 4; ++cd)
                o[rb][cd] = __builtin_amdgcn_mfma_f32_16x16x32_f16(pa[rb], bv[cd], o[rb][cd], 0, 0, 0);
    }

    #pragma unroll
    for (int off = 1; off < 16; off <<= 1)
        #pragma unroll
        for (int rb = 0; rb < 4; ++rb)
            #pragma unroll
            for (int r = 0; r < 4; ++r)
                rs[rb][r] += __shfl_xor(rs[rb][r], off, 64);

    const float gate = 1.f / (1.f + __expf(-fg[0]));
    const float wt = 1.f - gate;
    #pragma unroll
    for (int rb = 0; rb < 4; ++rb) {
        #pragma unroll
        for (int r = 0; r < 4; ++r) {
            const int t = w*64 + rb*16 + hi*4 + r;
            const float sc = wt / rs[rb][r];
            unsigned short* yp = y + (((size_t)b*TT + t)*JJ + j)*CC + h*HD;
            #pragma unroll
            for (int cd = 0; cd < 4; ++cd)
                yp[cd*16 + lo] = f2h(o[rb][cd][r] * sc);
        }
    }
}

// ---------------- F1: DFT MFMA GEMM, f16 in -> f16 freq out in place --------
#define XP 280

__global__ __launch_bounds__(256) void dft_k(
    unsigned short* __restrict__ planes, const unsigned short* __restrict__ Whi,
    const unsigned short* __restrict__ Wlo)
{
    __shared__ unsigned short Xh[64*XP];
    unsigned short* src = planes + (size_t)blockIdx.y*NQKV + (size_t)blockIdx.x*QTILE;
    const int tid = threadIdx.x;
    const int w = tid >> 6;
    const int lane = tid & 63;
    const int qd = (tid >> 4) & 3;
    const int rr = tid & 15;
    const int lo = lane & 15, hi = lane >> 4;

    #pragma unroll
    for (int p = 0; p < 16; ++p) {
        const int t = p*16 + 4*w + qd;
        ushort4 x4 = *(const ushort4*)&src[t*64 + 4*rr];
        unsigned int a0 = x4.x, a1 = x4.y, a2 = x4.z, a3 = x4.w;
        unsigned int t01 = (unsigned)__shfl_xor((int)((qd&1) ? a0 : a1), 16, 64);
        unsigned int t23 = (unsigned)__shfl_xor((int)((qd&1) ? a2 : a3), 16, 64);
        if (qd&1) { a0 = t01; a2 = t23; } else { a1 = t01; a3 = t23; }
        unsigned int u01 = (unsigned)__shfl_xor((int)((qd&2) ? a0 : a2), 32, 64);
        unsigned int u23 = (unsigned)__shfl_xor((int)((qd&2) ? a1 : a3), 32, 64);
        if (qd&2) { a0 = u01; a1 = u23; } else { a2 = u01; a3 = u23; }
        const int dd = 4*rr + qd;
        const int tb = p*16 + 4*w;
        ushort4 hv;
        hv.x = (unsigned short)a0; hv.y = (unsigned short)a1;
        hv.z = (unsigned short)a2; hv.w = (unsigned short)a3;
        *(ushort4*)&Xh[dd*XP + tb] = hv;
    }
    __syncthreads();

    f32x4 acc[2][4];
    #pragma unroll
    for (int rb = 0; rb < 2; ++rb)
        #pragma unroll
        for (int cd = 0; cd < 4; ++cd) acc[rb][cd] = (f32x4){0.f,0.f,0.f,0.f};

    for (int ks = 0; ks < 8; ++ks) {
        const int k0 = ks*32;
        f16x8 ah[2], al[2];
        #pragma unroll
        for (int rb = 0; rb < 2; ++rb) {
            int r = w*32 + rb*16 + lo;
            ah[rb] = *(const f16x8*)&Whi[r*256 + k0 + hi*8];
            al[rb] = *(const f16x8*)&Wlo[r*256 + k0 + hi*8];
        }
        f16x8 bh[4];
        #pragma unroll
        for (int cd = 0; cd < 4; ++cd) {
            int d = cd*16 + lo;
            bh[cd] = *(const f16x8*)&Xh[d*XP + k0 + hi*8];
        }
        #pragma unroll
        for (int rb = 0; rb < 2; ++rb)
            #pragma unroll
            for (int cd = 0; cd < 4; ++cd) {
                acc[rb][cd] = __builtin_amdgcn_mfma_f32_16x16x32_f16(
                    ah[rb], bh[cd], acc[rb][cd], 0, 0, 0);
                acc[rb][cd] = __builtin_amdgcn_mfma_f32_16x16x32_f16(
                    al[rb], bh[cd], acc[rb][cd], 0, 0, 0);
            }
    }

    #pragma unroll
    for (int rb = 0; rb < 2; ++rb) {
        #pragma unroll
        for (int r = 0; r < 4; ++r) {
            int row = w*32 + rb*16 + hi*4 + r;
            unsigned short* dst = (row < 64) ? (src + row*64)
                                             : (src + 4096 + (row-64)*64);
            #pragma unroll
            for (int cd = 0; cd < 4; ++cd)
                dst[cd*16 + lo] = f2h(acc[rb][cd][r]);
        }
    }
}

// ---------------- F2+F3 fused, all-MFMA: af -> in-reg dual softmax ->
// xf -> irfft -> y. Wave w owns rows w*32..w*32+32 of the stacked [re;im].
#define FQP 72    // u16 pitch for 128x64 f16 LDS tiles (144B rows, 16B-aligned)
#define XFP 136

__global__ __launch_bounds__(256) void freqtail_k(
    const unsigned short* __restrict__ qfp, const unsigned short* __restrict__ kfp,
    const unsigned short* __restrict__ vfp, const unsigned short* __restrict__ WIhi,
    const float* __restrict__ fg, unsigned short* __restrict__ y)
{
    __shared__ unsigned short S1[128*FQP];   // qf -> P -> XT
    __shared__ unsigned short S2[128*FQP];   // kf -> VFT

    const int tid = threadIdx.x;
    const int tile = blockIdx.x;
    const int b = tile / (HH*JJ);
    const int h = (tile / JJ) % HH;
    const int j = tile % JJ;
    const unsigned short* qf = qfp + (size_t)tile * QTILE;
    const unsigned short* kf = kfp + (size_t)tile * QTILE;
    const unsigned short* vf = vfp + (size_t)tile * QTILE;

    const int w = tid >> 6;
    const int lane = tid & 63;
    const int lo = lane & 15, hi = lane >> 4;
    const int comp = w >> 1;          // 0: real rows, 1: imag rows
    const int fr0 = (w & 1) * 32;     // f-base within component

    // ---- stage qf -> S1, kf -> S2 (f16, [128][FQP]) ----
    #pragma unroll
    for (int p = 0; p < 4; ++p) {
        int e8 = (p*256 + tid) * 8;
        int row = e8 >> 6, col = e8 & 63;
        *(i16x8*)&S1[row*FQP + col] = *(const i16x8*)(qf + e8);
        *(i16x8*)&S2[row*FQP + col] = *(const i16x8*)(kf + e8);
    }
    __syncthreads();

    // ---- af via MFMA: accA = qA.kr^T, accB = qB.ki^T; val = accA + sgn*accB
    f32x4 accA[2][4], accB[2][4];
    #pragma unroll
    for (int rb = 0; rb < 2; ++rb)
        #pragma unroll
        for (int cb = 0; cb < 4; ++cb) {
            accA[rb][cb] = (f32x4){0.f,0.f,0.f,0.f};
            accB[rb][cb] = (f32x4){0.f,0.f,0.f,0.f};
        }
    #pragma unroll
    for (int ks = 0; ks < 2; ++ks) {
        f16x8 qA[2], qB[2];
        #pragma unroll
        for (int rb = 0; rb < 2; ++rb) {
            int fr = fr0 + rb*16 + lo;
            qA[rb] = *(const f16x8*)&S1[(comp*64 + fr)*FQP + ks*32 + hi*8];
            qB[rb] = *(const f16x8*)&S1[((1-comp)*64 + fr)*FQP + ks*32 + hi*8];
        }
        f16x8 kr[4], ki[4];
        #pragma unroll
        for (int cb = 0; cb < 4; ++cb) {
            int g = cb*16 + lo;
            kr[cb] = *(const f16x8*)&S2[g*FQP + ks*32 + hi*8];
            ki[cb] = *(const f16x8*)&S2[(64 + g)*FQP + ks*32 + hi*8];
        }
        #pragma unroll
        for (int rb = 0; rb < 2; ++rb)
            #pragma unroll
            for (int cb = 0; cb < 4; ++cb) {
                accA[rb][cb] = __builtin_amdgcn_mfma_f32_16x16x32_f16(
                    qA[rb], kr[cb], accA[rb][cb], 0, 0, 0);
                accB[rb][cb] = __builtin_amdgcn_mfma_f32_16x16x32_f16(
                    qB[rb], ki[cb], accB[rb][cb], 0, 0, 0);
            }
    }
    __syncthreads();   // S1/S2 reads done (P and VFT overwrite next)

    // ---- in-register dual softmax (rows of 64 = 4 cb x 16 lanes) ----
    const float sgn = comp ? -1.f : 1.f;
    float pv[2][4][4];
    float inv[2][4];
    #pragma unroll
    for (int rb = 0; rb < 2; ++rb) {
        #pragma unroll
        for (int r = 0; r < 4; ++r) {
            float m = -3.0e38f;
            #pragma unroll
            for (int cb = 0; cb < 4; ++cb) {
                float vv = accA[rb][cb][r] + sgn*accB[rb][cb][r];
                pv[rb][cb][r] = vv;
                m = fmaxf(m, vv);
            }
            #pragma unroll
            for (int off = 1; off < 16; off <<= 1)
                m = fmaxf(m, __shfl_xor(m, off, 64));
            float s = 0.f;
            #pragma unroll
            for (int cb = 0; cb < 4; ++cb) {
                float e = __expf(pv[rb][cb][r] - m);
                pv[rb][cb][r] = e;
                s += e;
            }
            #pragma unroll
            for (int off = 1; off < 16; off <<= 1)
                s += __shfl_xor(s, off, 64);
            inv[rb][r] = 1.f / s;
        }
    }
    // write P (f16) over S1: row = w*32 + rb*16 + hi*4 + r, col = cb*16+lo
    #pragma unroll
    for (int rb = 0; rb < 2; ++rb)
        #pragma unroll
        for (int r = 0; r < 4; ++r)
            #pragma unroll
            for (int cb = 0; cb < 4; ++cb)
                S1[(w*32 + rb*16 + hi*4 + r)*FQP + cb*16 + lo] =
                    f2h(pv[rb][cb][r] * inv[rb][r]);

    // stage VFT (vf transposed) over S2: VFT[comp*64 + d][g]
    #pragma unroll
    for (int p = 0; p < 4; ++p) {
        int e8 = (p*256 + tid) * 8;
        int srow = e8 >> 6;           // 0..127: [re g | im g]
        int c2 = srow >> 6, g = srow & 63, d0 = e8 & 63;
        i16x8 vv = *(const i16x8*)(vf + e8);
        #pragma unroll
        for (int e = 0; e < 8; ++e)
            S2[(c2*64 + d0 + e)*FQP + g] = (unsigned short)vv[e];
    }
    __syncthreads();

    // ---- xf via MFMA: xA = pA.bA^T, xB = pB.bB^T; val = xA + sgn2*xB ----
    f32x4 xA[2][4], xB[2][4];
    #pragma unroll
    for (int rb = 0; rb < 2; ++rb)
        #pragma unroll
        for (int cd = 0; cd < 4; ++cd) {
            xA[rb][cd] = (f32x4){0.f,0.f,0.f,0.f};
            xB[rb][cd] = (f32x4){0.f,0.f,0.f,0.f};
        }
    #pragma unroll
    for (int ks = 0; ks < 2; ++ks) {
        f16x8 pA[2], pB[2];
        #pragma unroll
        for (int rb = 0; rb < 2; ++rb) {
            int fr = fr0 + rb*16 + lo;
            pA[rb] = *(const f16x8*)&S1[fr*FQP + ks*32 + hi*8];          // Pr
            pB[rb] = *(const f16x8*)&S1[(64 + fr)*FQP + ks*32 + hi*8];   // Pi
        }
        f16x8 bA[4], bB[4];
        #pragma unroll
        for (int cd = 0; cd < 4; ++cd) {
            int d = cd*16 + lo;
            bA[cd] = *(const f16x8*)&S2[(comp*64 + d)*FQP + ks*32 + hi*8];
            bB[cd] = *(const f16x8*)&S2[((1-comp)*64 + d)*FQP + ks*32 + hi*8];
        }
        #pragma unroll
        for (int rb = 0; rb < 2; ++rb)
            #pragma unroll
            for (int cd = 0; cd < 4; ++cd) {
                xA[rb][cd] = __builtin_amdgcn_mfma_f32_16x16x32_f16(
                    pA[rb], bA[cd], xA[rb][cd], 0, 0, 0);
                xB[rb][cd] = __builtin_amdgcn_mfma_f32_16x16x32_f16(
                    pB[rb], bB[cd], xB[rb][cd], 0, 0, 0);
            }
    }
    __syncthreads();   // P/VFT reads done

    // ---- write xf transposed f16 into XT (over S1): XT[d][comp*64 + f] ----
    const float sgn2 = comp ? 1.f : -1.f;
    unsigned short* XT = S1;
    #pragma unroll
    for (int rb = 0; rb < 2; ++rb)
        #pragma unroll
        for (int cd = 0; cd < 4; ++cd)
            #pragma unroll
            for (int r = 0; r < 4; ++r) {
                int f = fr0 + rb*16 + hi*4 + r;
                int d = cd*16 + lo;
                XT[d*XFP + comp*64 + f] =
                    f2h(xA[rb][cd][r] + sgn2*xB[rb][cd][r]);
            }
    __syncthreads();

    // ---- irfft MFMA tail: C[256 t][64 d] = WI[256][128] @ XT^T ----
    f32x4 acc[4][4];
    #pragma unroll
    for (int rb = 0; rb < 4; ++rb)
        #pragma unroll
        for (int cd = 0; cd < 4; ++cd) acc[rb][cd] = (f32x4){0.f,0.f,0.f,0.f};

    #pragma unroll
    for (int ks = 0; ks < 4; ++ks) {
        const int k0 = ks*32;
        f16x8 ah[4];
        #pragma unroll
        for (int rb = 0; rb < 4; ++rb) {
            int row = w*64 + rb*16 + lo;
            ah[rb] = *(const f16x8*)&WIhi[row*128 + k0 + hi*8];
        }
        f16x8 bt[4];
        #pragma unroll
        for (int cd = 0; cd < 4; ++cd) {
            int d = cd*16 + lo;
            bt[cd] = *(const f16x8*)&XT[d*XFP + k0 + hi*8];
        }
        #pragma unroll
        for (int rb = 0; rb < 4; ++rb)
            #pragma unroll
            for (int cd = 0; cd < 4; ++cd)
                acc[rb][cd] = __builtin_amdgcn_mfma_f32_16x16x32_f16(
                    ah[rb], bt[cd], acc[rb][cd], 0, 0, 0);
    }

    const float gate = 1.f / (1.f + __expf(-fg[0]));
    #pragma unroll
    for (int rb = 0; rb < 4; ++rb) {
        #pragma unroll
        for (int r = 0; r < 4; ++r) {
            int t = w*64 + rb*16 + hi*4 + r;
            unsigned short* yp = y + (((size_t)b*TT + t)*JJ + j)*CC + h*HD;
            #pragma unroll
            for (int cd = 0; cd < 4; ++cd) {
                int d = cd*16 + lo;
                yp[d] = f2h(fmaf(gate, acc[rb][cd][r], h2f(yp[d])));
            }
        }
    }
}

// ---------------------------------------------------------------------------
extern "C" void kernel_launch(void* const* d_in, const int* in_sizes, int n_in,
                              void* d_out, int out_size, void* d_ws, size_t ws_size,
                              hipStream_t stream) {
    const float* x      = (const float*)d_in[0];
    const float* w_qkv  = (const float*)d_in[1];
    const float* w_proj = (const float*)d_in[2];
    const float* b_proj = (const float*)d_in[3];
    const float* fg     = (const float*)d_in[4];
    float* out = (float*)d_out;

    unsigned short* qp = (unsigned short*)d_ws;
    unsigned short* kp = qp + NQKV;
    unsigned short* vp = kp + NQKV;
    unsigned short* xh = vp + NQKV;
    unsigned short* y  = xh + NQKV;
    unsigned short* wph = y + NQKV;
    unsigned short* wqh = (unsigned short*)d_out;
    unsigned short* Whi  = wqh + 1536*512;   // 128*256
    unsigned short* Wlo  = Whi + 128*256;
    unsigned short* WIhi = Wlo + 128*256;    // 256*128

    conv16_k<<<2048, 256, 0, stream>>>(x, xh, NQKV/8);
    prep_k<<<768, 256, 0, stream>>>(w_qkv, w_proj, wqh, wph, Whi, Wlo, WIhi);

    gemm_qkv_k<<<6528, 256, 0, stream>>>(xh, wqh, qp, kp, vp);
    attn_time_k<<<NTILES, 256, 0, stream>>>(qp, kp, vp, fg, y);
    dft_k<<<dim3(NTILES, 3), 256, 0, stream>>>(qp, Whi, Wlo);
    freqtail_k<<<NTILES, 256, 0, stream>>>(qp, kp, vp, WIhi, fg, y);

    gemm_proj_k<<<2176, 256, 0, stream>>>(y, wph, b_proj, out);
}